// Round 14
// baseline (1553.558 us; speedup 1.0000x reference)
//
#include <hip/hip_runtime.h>
#include <hip/hip_bf16.h>

typedef __bf16 bfx8 __attribute__((ext_vector_type(8)));
typedef __bf16 bfx4 __attribute__((ext_vector_type(4)));
typedef float f32x4 __attribute__((ext_vector_type(4)));

#define MFMA16(a, b, c) __builtin_amdgcn_mfma_f32_16x16x32_bf16((a), (b), (c), 0, 0, 0)

__device__ __forceinline__ void gl_lds16(const __bf16* g, __bf16* l) {
  __builtin_amdgcn_global_load_lds(
      (const __attribute__((address_space(1))) unsigned int*)(const void*)g,
      (__attribute__((address_space(3))) unsigned int*)(void*)l, 16, 0, 0);
}

__device__ __forceinline__ unsigned pack_bf2(float a, float b) {
  unsigned short ua = __builtin_bit_cast(unsigned short, (__bf16)a);
  unsigned short ub = __builtin_bit_cast(unsigned short, (__bf16)b);
  return (unsigned)ua | ((unsigned)ub << 16);
}

__device__ __forceinline__ float gelu_tanh_f(float x) {
  float u = 0.7978845608028654f * (x + 0.044715f * x * x * x);
  float t;
  if (u > 10.f) t = 1.f;
  else if (u < -10.f) t = -1.f;
  else { float e = __expf(2.f * u); t = (e - 1.f) / (e + 1.f); }
  return 0.5f * x * (1.f + t);
}

// ---------------- RMSNorm (optionally fused residual add) ----------------
__global__ __launch_bounds__(256)
void rmsnorm_kernel(const float* __restrict__ X, const float* __restrict__ X2,
                    const float* __restrict__ scale, __bf16* __restrict__ out) {
  __shared__ float wsum[4];
  const int row = blockIdx.x, tid = threadIdx.x;
  const size_t base = (size_t)row * 2048;
  f32x4 v[2];
  float ss = 0.f;
#pragma unroll
  for (int i = 0; i < 2; ++i) {
    const int idx = tid * 4 + i * 1024;
    v[i] = *(const f32x4*)(X + base + idx);
    if (X2) { f32x4 u = *(const f32x4*)(X2 + base + idx); v[i] = v[i] + u; }
#pragma unroll
    for (int j = 0; j < 4; ++j) ss += v[i][j] * v[i][j];
  }
#pragma unroll
  for (int o = 32; o > 0; o >>= 1) ss += __shfl_xor(ss, o, 64);
  if ((tid & 63) == 0) wsum[tid >> 6] = ss;
  __syncthreads();
  const float tot = wsum[0] + wsum[1] + wsum[2] + wsum[3];
  const float rs = rsqrtf(tot * (1.f / 2048.f) + 1e-6f);
#pragma unroll
  for (int i = 0; i < 2; ++i) {
    const int idx = tid * 4 + i * 1024;
    f32x4 sc = *(const f32x4*)(scale + idx);
    bfx4 ov;
#pragma unroll
    for (int j = 0; j < 4; ++j) ov[j] = (__bf16)(v[i][j] * rs * (1.f + sc[j]));
    *(bfx4*)(out + base + idx) = ov;
  }
}

// ---------------- RoPE in-place on bf16 (+ optional scale), stride param ----------------
__global__ __launch_bounds__(256)
void rope_bf_kernel(__bf16* __restrict__ buf, const int* __restrict__ pos,
                    int nheads, int rstride, float outscale) {
  const int row = blockIdx.x;
  const float p = (float)pos[row];
  const int total = nheads * 128;
  const size_t rbase = (size_t)row * (size_t)rstride;
  for (int idx = threadIdx.x; idx < total; idx += 256) {
    const int n = idx >> 7, i = idx & 127;
    const float ts = __expf(-(float)i * 0.071955784f);  // 10000^(-i/128)
    float sn, cs;
    __sincosf(p * ts, &sn, &cs);
    __bf16* bp = buf + rbase + n * 256 + i;
    const float x1 = (float)bp[0], x2 = (float)bp[128];
    bp[0]   = (__bf16)((x1 * cs - x2 * sn) * outscale);
    bp[128] = (__bf16)((x2 * cs + x1 * sn) * outscale);
  }
}

// ---------------- RoPE f32 -> bf16 (fallback path) ----------------
__global__ __launch_bounds__(256)
void rope_kernel(const float* __restrict__ in, const int* __restrict__ pos,
                 __bf16* __restrict__ outp, int nheads, float outscale) {
  const int row = blockIdx.x;
  const float p = (float)pos[row];
  const int total = nheads * 128;
  const size_t rbase = (size_t)row * (size_t)(nheads * 256);
  for (int idx = threadIdx.x; idx < total; idx += 256) {
    const int n = idx >> 7, i = idx & 127;
    const float ts = __expf(-(float)i * 0.071955784f);
    float sn, cs;
    __sincosf(p * ts, &sn, &cs);
    const float* bp = in + rbase + n * 256 + i;
    const float x1 = bp[0], x2 = bp[128];
    __bf16* ob = outp + rbase + n * 256 + i;
    ob[0]   = (__bf16)((x1 * cs - x2 * sn) * outscale);
    ob[128] = (__bf16)((x2 * cs + x1 * sn) * outscale);
  }
}

// ---------------- Weight convert: f32 W[k][c] -> bf16 tile-panel layout ----------------
// Panel: (cp*(K/32)+ks)*4096 holds the 128x32 tile pre-swizzled in LDS-linear order:
// element (m=col&127, k): lg=(k%32)/8, p=lg^((m>>1)&3), offset = m*32 + p*8 + (k&7).
__global__ __launch_bounds__(256)
void convw_kernel(const float* __restrict__ in, __bf16* __restrict__ out,
                  int K, int headDim) {
  __shared__ __bf16 tile[64][65];
  const int tc0 = blockIdx.x * 64;
  const int tk0 = blockIdx.y * 64;
  const int tid = threadIdx.x;
  const int cchunk = tid & 15, krow = tid >> 4;
  const int c = tc0 + cchunk * 4;
  const float* colbase = in + (size_t)(c / headDim) * (size_t)K * headDim + (c % headDim);
#pragma unroll
  for (int i = 0; i < 4; ++i) {
    const int k = tk0 + krow + i * 16;
    f32x4 v = *(const f32x4*)(colbase + (size_t)k * headDim);
#pragma unroll
    for (int j = 0; j < 4; ++j) tile[cchunk * 4 + j][krow + i * 16] = (__bf16)v[j];
  }
  __syncthreads();
  const int nks = K >> 5;
#pragma unroll
  for (int s = 0; s < 2; ++s) {
    const int ch = tid + s * 256;
    const int wc = ch >> 3, wk8 = (ch & 7) * 8;
    bfx8 v;
#pragma unroll
    for (int j = 0; j < 8; ++j) v[j] = tile[wc][wk8 + j];
    const int col = tc0 + wc;
    const int kchunk = (tk0 + wk8) >> 3;
    const int cp = col >> 7, m = col & 127;
    const int ks = kchunk >> 2, lg = kchunk & 3;
    const int p = lg ^ ((m >> 1) & 3);
    *(bfx8*)(out + ((size_t)(cp * nks + ks)) * 4096 + m * 32 + p * 8) = v;
  }
}

// ---------------- 2-phase dual-panel GEMM (256 rows x 2 panels, 512 threads) ---------
// Round-11-verified K-loop. Two B panels share one A read (effective BN=256).
// outMode 4: C = gelu(A·W0)*(A·W1), both panels at SAME cols (col0 = by*128).
// outMode 0/2/5: W1 is the NEXT col-panel of one matrix (pass W1 = W0 + nks*4096);
//   cols = col0 + pan*128 + ... with col0 = by*256.
//   0: f32 C; 2: f32 C + Extra residual; 5: QKV scatter (col<2304 bf16 C, else V^T to C2).
__global__ __launch_bounds__(512, 2)
void dual256(const __bf16* __restrict__ A, const __bf16* __restrict__ W0,
             const __bf16* __restrict__ W1, void* __restrict__ C,
             void* __restrict__ C2, const void* __restrict__ Extra,
             int Mpb, int lda, int strideA, int Kd,
             int ldc, int strideC, int mbPerBatch, int outMode) {
  __shared__ __align__(16) __bf16 As[2 * 2 * 8192];  // [buf][half][128x64]
  __shared__ __align__(16) __bf16 Bs[2 * 2 * 8192];  // [buf][pan][128x64]
  const int tid = threadIdx.x;
  const int lane = tid & 63;
  const int wid = tid >> 6;
  const int wr = wid >> 2;
  const int wc = wid & 3;
  const int qi = lane & 15, g = lane >> 4;
  // XCD-chunked swizzle (nwg divisible by 8)
  int bid = blockIdx.y * gridDim.x + blockIdx.x;
  const int nwg = gridDim.x * gridDim.y;
  if ((nwg & 7) == 0) bid = (bid & 7) * (nwg >> 3) + (bid >> 3);
  const int bx = bid % gridDim.x, by = bid / gridDim.x;
  const int b = bx / mbPerBatch;
  const int row0 = (bx % mbPerBatch) * 256;
  const int colw = (outMode == 4) ? 128 : 256;
  const int col0 = by * colw;
  const __bf16* Ab = A + (size_t)b * strideA;
  const size_t nks = (size_t)(Kd >> 5);
  const __bf16* Bgp = W0 + ((size_t)(col0 >> 7)) * nks * 4096;
  const __bf16* Bap = W1 + ((size_t)(col0 >> 7)) * nks * 4096;
  const int NT = Kd >> 6;

  const int sm = tid >> 2, sp = tid & 3;
  const int slg = sp ^ ((sm >> 1) & 3);
  int r0 = row0 + sm;       if (r0 >= Mpb) r0 = Mpb - 1;
  int r1 = row0 + 128 + sm; if (r1 >= Mpb) r1 = Mpb - 1;
  const __bf16* asrc0 = Ab + (size_t)r0 * lda + slg * 8;
  const __bf16* asrc1 = Ab + (size_t)r1 * lda + slg * 8;

  // half order per K-tile t: 0=A0, 1=B0, 2=A1, 3=B1
  auto stage_half = [&](int gh) {
    if (gh >= 4 * NT) return;
    const int t = gh >> 2, which = gh & 3;
    const int bufi = t & 1;
    if ((which & 1) == 0) {
      const int h = which >> 1;
      __bf16* dst = &As[bufi * 16384 + h * 8192];
      const __bf16* src = (h ? asrc1 : asrc0) + t * 64;
      gl_lds16(src, dst + tid * 8);
      gl_lds16(src + 32, dst + 4096 + tid * 8);
    } else {
      const int pan = which >> 1;
      __bf16* dst = &Bs[bufi * 16384 + pan * 8192];
      const __bf16* src = (pan ? Bap : Bgp) + (size_t)(t * 2) * 4096 + tid * 8;
      gl_lds16(src, dst + tid * 8);
      gl_lds16(src + 4096, dst + 4096 + tid * 8);
    }
  };

  f32x4 acc[2][2][4][2];
#pragma unroll
  for (int a0 = 0; a0 < 2; ++a0)
#pragma unroll
    for (int a1 = 0; a1 < 2; ++a1)
#pragma unroll
      for (int a2 = 0; a2 < 4; ++a2)
#pragma unroll
        for (int a3 = 0; a3 < 2; ++a3) acc[a0][a1][a2][a3] = f32x4{0.f, 0.f, 0.f, 0.f};

  for (int gh = 0; gh < 6; ++gh) stage_half(gh);
  asm volatile("s_waitcnt vmcnt(4)" ::: "memory");
  __builtin_amdgcn_s_barrier();
  asm volatile("" ::: "memory");

  for (int t = 0; t < NT; ++t) {
    const int cb = (t & 1) * 16384;
    bfx8 af[4][2], bf[2][2][2];

    // ---- PHASE 0: A-half 0, both panels ----
#pragma unroll
    for (int mi = 0; mi < 4; ++mi) {
      const int m = wr * 64 + mi * 16 + qi;
      const int sl = g ^ ((m >> 1) & 3);
      const int ba = cb + m * 32 + sl * 8;
      af[mi][0] = *(const bfx8*)(&As[ba]);
      af[mi][1] = *(const bfx8*)(&As[ba + 4096]);
    }
#pragma unroll
    for (int pan = 0; pan < 2; ++pan)
#pragma unroll
      for (int ni = 0; ni < 2; ++ni) {
        const int m = wc * 32 + ni * 16 + qi;
        const int sl = g ^ ((m >> 1) & 3);
        const int bb = cb + pan * 8192 + m * 32 + sl * 8;
        bf[pan][ni][0] = *(const bfx8*)(&Bs[bb]);
        bf[pan][ni][1] = *(const bfx8*)(&Bs[bb + 4096]);
      }
    stage_half(4 * t + 6);
    stage_half(4 * t + 7);
    __builtin_amdgcn_s_barrier();
    asm volatile("s_waitcnt lgkmcnt(0)" ::: "memory");
    __builtin_amdgcn_sched_barrier(0);
    __builtin_amdgcn_s_setprio(1);
#pragma unroll
    for (int pan = 0; pan < 2; ++pan)
#pragma unroll
      for (int mi = 0; mi < 4; ++mi)
#pragma unroll
        for (int ni = 0; ni < 2; ++ni) {
          acc[0][pan][mi][ni] = MFMA16(af[mi][0], bf[pan][ni][0], acc[0][pan][mi][ni]);
          acc[0][pan][mi][ni] = MFMA16(af[mi][1], bf[pan][ni][1], acc[0][pan][mi][ni]);
        }
    __builtin_amdgcn_s_setprio(0);
    __builtin_amdgcn_s_barrier();
    asm volatile("" ::: "memory");

    // ---- PHASE 1: A-half 1, reuse bf ----
#pragma unroll
    for (int mi = 0; mi < 4; ++mi) {
      const int m = wr * 64 + mi * 16 + qi;
      const int sl = g ^ ((m >> 1) & 3);
      const int ba = cb + 8192 + m * 32 + sl * 8;
      af[mi][0] = *(const bfx8*)(&As[ba]);
      af[mi][1] = *(const bfx8*)(&As[ba + 4096]);
    }
    stage_half(4 * t + 8);
    stage_half(4 * t + 9);
    if (t + 2 < NT) asm volatile("s_waitcnt vmcnt(4)" ::: "memory");
    else            asm volatile("s_waitcnt vmcnt(0)" ::: "memory");
    __builtin_amdgcn_s_barrier();
    asm volatile("s_waitcnt lgkmcnt(0)" ::: "memory");
    __builtin_amdgcn_sched_barrier(0);
    __builtin_amdgcn_s_setprio(1);
#pragma unroll
    for (int pan = 0; pan < 2; ++pan)
#pragma unroll
      for (int mi = 0; mi < 4; ++mi)
#pragma unroll
        for (int ni = 0; ni < 2; ++ni) {
          acc[1][pan][mi][ni] = MFMA16(af[mi][0], bf[pan][ni][0], acc[1][pan][mi][ni]);
          acc[1][pan][mi][ni] = MFMA16(af[mi][1], bf[pan][ni][1], acc[1][pan][mi][ni]);
        }
    __builtin_amdgcn_s_setprio(0);
    __builtin_amdgcn_s_barrier();
    asm volatile("" ::: "memory");
  }

  if (outMode == 4) {
#pragma unroll
    for (int mh = 0; mh < 2; ++mh)
#pragma unroll
      for (int mi = 0; mi < 4; ++mi)
#pragma unroll
        for (int ni = 0; ni < 2; ++ni) {
          const int col = col0 + wc * 32 + ni * 16 + qi;
#pragma unroll
          for (int r = 0; r < 4; ++r) {
            const int row = row0 + mh * 128 + wr * 64 + mi * 16 + g * 4 + r;
            if (row >= Mpb) continue;
            ((__bf16*)C)[(size_t)b * strideC + (size_t)row * ldc + col] =
                (__bf16)(gelu_tanh_f(acc[mh][0][mi][ni][r]) * acc[mh][1][mi][ni][r]);
          }
        }
  } else {
#pragma unroll
    for (int mh = 0; mh < 2; ++mh)
#pragma unroll
      for (int pan = 0; pan < 2; ++pan)
#pragma unroll
        for (int mi = 0; mi < 4; ++mi)
#pragma unroll
          for (int ni = 0; ni < 2; ++ni) {
            const int col = col0 + pan * 128 + wc * 32 + ni * 16 + qi;
            if (outMode == 5 && col >= 2304) {
              const int vcol = col - 2304;
              const int rowb = row0 + mh * 128 + wr * 64 + mi * 16 + g * 4;
              if (rowb < Mpb) {
                bfx4 ov;
#pragma unroll
                for (int r = 0; r < 4; ++r) ov[r] = (__bf16)acc[mh][pan][mi][ni][r];
                *(bfx4*)((__bf16*)C2 + (size_t)b * (256 * 816) + (size_t)vcol * 816 + rowb) = ov;
              }
              continue;
            }
#pragma unroll
            for (int r = 0; r < 4; ++r) {
              const int row = row0 + mh * 128 + wr * 64 + mi * 16 + g * 4 + r;
              if (row >= Mpb) continue;
              const float v = acc[mh][pan][mi][ni][r];
              if (outMode == 0) {
                ((float*)C)[(size_t)b * strideC + (size_t)row * ldc + col] = v;
              } else if (outMode == 5) {
                ((__bf16*)C)[(size_t)b * strideC + (size_t)row * ldc + col] = (__bf16)v;
              } else {  // mode 2
                const size_t ix = (size_t)b * strideC + (size_t)row * ldc + col;
                ((float*)C)[ix] = v + ((const float*)Extra)[ix];
              }
            }
          }
  }
}

// ---------------- bf16 GEMM, panel weights, BK=64, counted-vmcnt (small-M path) ------
__global__ __launch_bounds__(256, 2)
void gemm_bt2(const __bf16* __restrict__ A, const __bf16* __restrict__ Bt,
              void* __restrict__ C, void* __restrict__ C2, const void* __restrict__ Extra,
              int Mpb, int lda, int strideA, int Kd,
              int ldc, int strideC, int mbPerBatch,
              int outMode, int ldct) {
  __shared__ __align__(16) __bf16 As[2][8192];
  __shared__ __align__(16) __bf16 Bs[2][8192];
  const int tid = threadIdx.x;
  const int lane = tid & 63;
  const int wid = tid >> 6;
  const int b = blockIdx.x / mbPerBatch;
  const int row0 = (blockIdx.x % mbPerBatch) * 128;
  const int col0 = blockIdx.y * 128;
  const __bf16* Ab = A + (size_t)b * strideA;
  const size_t nks = (size_t)(Kd >> 5);
  const __bf16* Bpan0 = Bt + ((size_t)(col0 >> 7)) * nks * 4096;
  const int wm = (wid >> 1) * 64, wn = (wid & 1) * 64;
  const int qi = lane & 15, g = lane >> 4;

  const int m0 = tid >> 2, p0 = tid & 3;
  const int lg0 = p0 ^ ((m0 >> 1) & 3);
  const int m1 = m0 + 64;
  const int lg1 = p0 ^ ((m1 >> 1) & 3);
  int mr0 = row0 + m0; if (mr0 >= Mpb) mr0 = Mpb - 1;
  int mr1 = row0 + m1; if (mr1 >= Mpb) mr1 = Mpb - 1;
  const __bf16* asrc0 = Ab + (size_t)mr0 * lda + lg0 * 8;
  const __bf16* asrc1 = Ab + (size_t)mr1 * lda + lg1 * 8;
  const int nt = Kd >> 6;

  auto stage = [&](int t, int bufi) {
    const int k0 = t * 64;
    gl_lds16(asrc0 + k0, &As[bufi][tid * 8]);
    gl_lds16(asrc1 + k0, &As[bufi][(tid + 256) * 8]);
    gl_lds16(asrc0 + k0 + 32, &As[bufi][4096 + tid * 8]);
    gl_lds16(asrc1 + k0 + 32, &As[bufi][4096 + (tid + 256) * 8]);
    const __bf16* pb = Bpan0 + (size_t)(k0 >> 5) * 4096;
    gl_lds16(pb + tid * 8, &Bs[bufi][tid * 8]);
    gl_lds16(pb + (tid + 256) * 8, &Bs[bufi][(tid + 256) * 8]);
    gl_lds16(pb + 4096 + tid * 8, &Bs[bufi][4096 + tid * 8]);
    gl_lds16(pb + 4096 + (tid + 256) * 8, &Bs[bufi][4096 + (tid + 256) * 8]);
  };

  f32x4 acc[4][4];
#pragma unroll
  for (int i = 0; i < 4; ++i)
#pragma unroll
    for (int j = 0; j < 4; ++j) acc[i][j] = f32x4{0.f, 0.f, 0.f, 0.f};

  stage(0, 0);
  if (nt > 1) stage(1, 1);

  for (int t = 0; t < nt; ++t) {
    const int cur = t & 1;
    if (t + 1 < nt) asm volatile("s_waitcnt vmcnt(8)" ::: "memory");
    else            asm volatile("s_waitcnt vmcnt(0)" ::: "memory");
    __builtin_amdgcn_s_barrier();
    asm volatile("" ::: "memory");
#pragma unroll
    for (int ks = 0; ks < 2; ++ks) {
      bfx8 af[4], bf[4];
#pragma unroll
      for (int mi = 0; mi < 4; ++mi) {
        const int m = wm + mi * 16 + qi;
        const int sl = g ^ ((m >> 1) & 3);
        af[mi] = *(const bfx8*)(&As[cur][ks * 4096 + m * 32 + sl * 8]);
      }
#pragma unroll
      for (int ni = 0; ni < 4; ++ni) {
        const int n = wn + ni * 16 + qi;
        const int sl = g ^ ((n >> 1) & 3);
        bf[ni] = *(const bfx8*)(&Bs[cur][ks * 4096 + n * 32 + sl * 8]);
      }
#pragma unroll
      for (int mi = 0; mi < 4; ++mi)
#pragma unroll
        for (int ni = 0; ni < 4; ++ni)
          acc[mi][ni] = MFMA16(af[mi], bf[ni], acc[mi][ni]);
    }
    asm volatile("s_waitcnt lgkmcnt(0)" ::: "memory");
    __builtin_amdgcn_s_barrier();
    asm volatile("" ::: "memory");
    if (t + 2 < nt) stage(t + 2, cur);
  }

#pragma unroll
  for (int mi = 0; mi < 4; ++mi) {
#pragma unroll
    for (int ni = 0; ni < 4; ++ni) {
      const int col = col0 + wn + ni * 16 + qi;
      if (outMode == 5 && col >= 2304) {
        const int vcol = col - 2304;
        const int rowb = row0 + wm + mi * 16 + g * 4;
        if (rowb < Mpb) {
          bfx4 ov;
#pragma unroll
          for (int r = 0; r < 4; ++r) ov[r] = (__bf16)acc[mi][ni][r];
          *(bfx4*)((__bf16*)C2 + (size_t)b * (256 * 816) + (size_t)vcol * 816 + rowb) = ov;
        }
        continue;
      }
#pragma unroll
      for (int r = 0; r < 4; ++r) {
        const int row = row0 + wm + mi * 16 + g * 4 + r;
        if (row >= Mpb) continue;
        const float v = acc[mi][ni][r];
        if (outMode == 0) {
          ((float*)C)[(size_t)b * strideC + (size_t)row * ldc + col] = v;
        } else if (outMode == 1 || outMode == 5) {
          ((__bf16*)C)[(size_t)b * strideC + (size_t)row * ldc + col] = (__bf16)v;
        } else {  // mode 2
          const size_t ix = (size_t)b * strideC + (size_t)row * ldc + col;
          ((float*)C)[ix] = v + ((const float*)Extra)[ix];
        }
      }
    }
  }
  (void)ldct;
}

// ---------------- Fused GEGLU dual-GEMM (128-tile, small-M path) ----------------
__global__ __launch_bounds__(256, 2)
void ffn_dual(const __bf16* __restrict__ A, const __bf16* __restrict__ Wg,
              const __bf16* __restrict__ Wa, __bf16* __restrict__ C,
              int Mpb, int lda, int strideA, int Kd,
              int ldc, int strideC, int mbPerBatch) {
  __shared__ __align__(16) __bf16 As[2][8192];
  __shared__ __align__(16) __bf16 Bs[2][8192];
  const int tid = threadIdx.x;
  const int lane = tid & 63;
  const int wid = tid >> 6;
  const int b = blockIdx.x / mbPerBatch;
  const int row0 = (blockIdx.x % mbPerBatch) * 128;
  const int col0 = blockIdx.y * 128;
  const __bf16* Ab = A + (size_t)b * strideA;
  const size_t nks = (size_t)(Kd >> 5);
  const int wm = (wid >> 1) * 64, wn = (wid & 1) * 64;
  const int qi = lane & 15, g = lane >> 4;

  const int m0 = tid >> 2, p0 = tid & 3;
  const int lg0 = p0 ^ ((m0 >> 1) & 3);
  const int m1 = m0 + 64;
  const int lg1 = p0 ^ ((m1 >> 1) & 3);
  int mr0 = row0 + m0; if (mr0 >= Mpb) mr0 = Mpb - 1;
  int mr1 = row0 + m1; if (mr1 >= Mpb) mr1 = Mpb - 1;
  const __bf16* asrc0 = Ab + (size_t)mr0 * lda + lg0 * 8;
  const __bf16* asrc1 = Ab + (size_t)mr1 * lda + lg1 * 8;
  const int nt = Kd >> 6;

  f32x4 gval[4][4];
  f32x4 acc[4][4];

#pragma unroll
  for (int pan = 0; pan < 2; ++pan) {
    const __bf16* Bpan0 = (pan ? Wa : Wg) + ((size_t)(col0 >> 7)) * nks * 4096;

    auto stage = [&](int t, int bufi) {
      const int k0 = t * 64;
      gl_lds16(asrc0 + k0, &As[bufi][tid * 8]);
      gl_lds16(asrc1 + k0, &As[bufi][(tid + 256) * 8]);
      gl_lds16(asrc0 + k0 + 32, &As[bufi][4096 + tid * 8]);
      gl_lds16(asrc1 + k0 + 32, &As[bufi][4096 + (tid + 256) * 8]);
      const __bf16* pb = Bpan0 + (size_t)(k0 >> 5) * 4096;
      gl_lds16(pb + tid * 8, &Bs[bufi][tid * 8]);
      gl_lds16(pb + (tid + 256) * 8, &Bs[bufi][(tid + 256) * 8]);
      gl_lds16(pb + 4096 + tid * 8, &Bs[bufi][4096 + tid * 8]);
      gl_lds16(pb + 4096 + (tid + 256) * 8, &Bs[bufi][4096 + (tid + 256) * 8]);
    };

#pragma unroll
    for (int i = 0; i < 4; ++i)
#pragma unroll
      for (int j = 0; j < 4; ++j) acc[i][j] = f32x4{0.f, 0.f, 0.f, 0.f};

    stage(0, 0);
    if (nt > 1) stage(1, 1);

    for (int t = 0; t < nt; ++t) {
      const int cur = t & 1;
      if (t + 1 < nt) asm volatile("s_waitcnt vmcnt(8)" ::: "memory");
      else            asm volatile("s_waitcnt vmcnt(0)" ::: "memory");
      __builtin_amdgcn_s_barrier();
      asm volatile("" ::: "memory");
#pragma unroll
      for (int ks = 0; ks < 2; ++ks) {
        bfx8 af[4], bf[4];
#pragma unroll
        for (int mi = 0; mi < 4; ++mi) {
          const int m = wm + mi * 16 + qi;
          const int sl = g ^ ((m >> 1) & 3);
          af[mi] = *(const bfx8*)(&As[cur][ks * 4096 + m * 32 + sl * 8]);
        }
#pragma unroll
        for (int ni = 0; ni < 4; ++ni) {
          const int n = wn + ni * 16 + qi;
          const int sl = g ^ ((n >> 1) & 3);
          bf[ni] = *(const bfx8*)(&Bs[cur][ks * 4096 + n * 32 + sl * 8]);
        }
#pragma unroll
        for (int mi = 0; mi < 4; ++mi)
#pragma unroll
          for (int ni = 0; ni < 4; ++ni)
            acc[mi][ni] = MFMA16(af[mi], bf[ni], acc[mi][ni]);
      }
      asm volatile("s_waitcnt lgkmcnt(0)" ::: "memory");
      __builtin_amdgcn_s_barrier();
      asm volatile("" ::: "memory");
      if (t + 2 < nt) stage(t + 2, cur);
    }

    if (pan == 0) {
#pragma unroll
      for (int i = 0; i < 4; ++i)
#pragma unroll
        for (int j = 0; j < 4; ++j)
#pragma unroll
          for (int r = 0; r < 4; ++r) gval[i][j][r] = gelu_tanh_f(acc[i][j][r]);
    }
  }

#pragma unroll
  for (int mi = 0; mi < 4; ++mi) {
#pragma unroll
    for (int ni = 0; ni < 4; ++ni) {
      const int col = col0 + wn + ni * 16 + qi;
#pragma unroll
      for (int r = 0; r < 4; ++r) {
        const int row = row0 + wm + mi * 16 + g * 4 + r;
        if (row >= Mpb) continue;
        C[(size_t)b * strideC + (size_t)row * ldc + col] =
            (__bf16)(gval[mi][ni][r] * acc[mi][ni][r]);
      }
    }
  }
}

// ---------------- Old GEMM (f32 weights on the fly) — legacy fallback ----------------
__global__ __launch_bounds__(256, 2)
void gemm_kernel(const __bf16* __restrict__ A, const float* __restrict__ Bw,
                 void* __restrict__ C, const void* __restrict__ Extra,
                 int Mpb, int lda, int strideA,
                 int ldb, int headDim, int Kd,
                 int ldc, int strideC, int mbPerBatch,
                 int outMode, int ldct) {
  __shared__ __align__(16) __bf16 As[128 * 32];
  __shared__ __align__(16) __bf16 Bs[128 * 32];
  const int tid = threadIdx.x;
  const int lane = tid & 63;
  const int wid = tid >> 6;
  const int b = blockIdx.x / mbPerBatch;
  const int row0 = (blockIdx.x % mbPerBatch) * 128;
  const int col0 = blockIdx.y * 128;
  const __bf16* Ab = A + (size_t)b * strideA;
  const float* Bb = (headDim > 0)
      ? (Bw + (size_t)(col0 / headDim) * (size_t)Kd * headDim + (col0 % headDim))
      : (Bw + col0);
  const int wm = (wid >> 1) * 64, wn = (wid & 1) * 64;
  const int qi = lane & 15, g = lane >> 4;

  f32x4 acc[4][4];
#pragma unroll
  for (int i = 0; i < 4; ++i)
#pragma unroll
    for (int j = 0; j < 4; ++j) acc[i][j] = f32x4{0.f, 0.f, 0.f, 0.f};

  const int am = tid >> 2, ap = tid & 3;
  const int bn = tid >> 2, bc = tid & 3;

  for (int k0 = 0; k0 < Kd; k0 += 32) {
    __syncthreads();
#pragma unroll
    for (int s = 0; s < 2; ++s) {
      const int m = am + s * 64;
      int mr = row0 + m;
      if (mr >= Mpb) mr = Mpb - 1;
      const int lg = ap ^ ((m >> 1) & 3);
      bfx8 v = *(const bfx8*)(Ab + (size_t)mr * lda + k0 + lg * 8);
      *(bfx8*)(&As[m * 32 + ap * 8]) = v;
    }
#pragma unroll
    for (int s = 0; s < 2; ++s) {
      const int n = bn + s * 64;
      const float* bp = Bb + (size_t)(k0 + bc * 8) * ldb + n;
      bfx8 v;
#pragma unroll
      for (int i = 0; i < 8; ++i) v[i] = (__bf16)bp[(size_t)i * ldb];
      const int p = bc ^ ((n >> 1) & 3);
      *(bfx8*)(&Bs[n * 32 + p * 8]) = v;
    }
    __syncthreads();
    bfx8 af[4], bf[4];
#pragma unroll
    for (int mi = 0; mi < 4; ++mi) {
      const int m = wm + mi * 16 + qi;
      const int sl = g ^ ((m >> 1) & 3);
      af[mi] = *(const bfx8*)(&As[m * 32 + sl * 8]);
    }
#pragma unroll
    for (int ni = 0; ni < 4; ++ni) {
      const int n = wn + ni * 16 + qi;
      const int sl = g ^ ((n >> 1) & 3);
      bf[ni] = *(const bfx8*)(&Bs[n * 32 + sl * 8]);
    }
#pragma unroll
    for (int mi = 0; mi < 4; ++mi)
#pragma unroll
      for (int ni = 0; ni < 4; ++ni)
        acc[mi][ni] = MFMA16(af[mi], bf[ni], acc[mi][ni]);
  }

#pragma unroll
  for (int mi = 0; mi < 4; ++mi) {
#pragma unroll
    for (int ni = 0; ni < 4; ++ni) {
      const int col = col0 + wn + ni * 16 + qi;
#pragma unroll
      for (int r = 0; r < 4; ++r) {
        const int row = row0 + wm + mi * 16 + g * 4 + r;
        if (row >= Mpb) continue;
        const float v = acc[mi][ni][r];
        if (outMode == 0) {
          ((float*)C)[(size_t)b * strideC + (size_t)row * ldc + col] = v;
        } else if (outMode == 1) {
          ((__bf16*)C)[(size_t)b * strideC + (size_t)row * ldc + col] = (__bf16)v;
        } else if (outMode == 2) {
          const size_t ix = (size_t)b * strideC + (size_t)row * ldc + col;
          ((float*)C)[ix] = v + ((const float*)Extra)[ix];
        } else if (outMode == 3) {
          ((__bf16*)C)[(size_t)b * strideC + (size_t)col * ldct + row] = (__bf16)v;
        } else {
          const size_t ix = (size_t)b * strideC + (size_t)row * ldc + col;
          const float gt = (float)((const __bf16*)Extra)[ix];
          ((__bf16*)C)[ix] = (__bf16)(gelu_tanh_f(gt) * v);
        }
      }
    }
  }
}

// ---------------- Fused attention (q/k strides parameterized) ----------------
__global__ __launch_bounds__(256, 2)
void attn_kernel(const __bf16* __restrict__ qp, const __bf16* __restrict__ kp0,
                 const __bf16* __restrict__ vt, __bf16* __restrict__ ao,
                 int qstride, int kstride) {
  __shared__ __align__(16) __bf16 Ps[4][1024];
  __shared__ float denw[4][16];
  const int tid = threadIdx.x, lane = tid & 63, wid = tid >> 6;
  const int qt = blockIdx.x, hn = blockIdx.y, b = blockIdx.z;
  const int q0 = qt * 64;
  const int qi = lane & 15, g = lane >> 4;

  int qrow = q0 + wid * 16 + qi;
  if (qrow > 815) qrow = 815;
  const int cmq = (qrow >= 768) + (qrow >= 771);
  const __bf16* qrp = qp + (size_t)(b * 816 + qrow) * qstride + hn * 256 + g * 8;
  bfx8 qf[8];
#pragma unroll
  for (int kf = 0; kf < 8; ++kf) qf[kf] = *(const bfx8*)(qrp + kf * 32);

  f32x4 oacc[16];
#pragma unroll
  for (int i = 0; i < 16; ++i) oacc[i] = f32x4{0.f, 0.f, 0.f, 0.f};
  float den = 0.f;

  const int ntiles = (q0 + 63 < 768) ? 12 : 13;
  for (int t = 0; t < ntiles; ++t) {
    const int kv0 = t * 64;
#pragma unroll
    for (int mi = 0; mi < 4; ++mi) {
      f32x4 sac = f32x4{0.f, 0.f, 0.f, 0.f};
      int srow = kv0 + mi * 16 + qi;
      if (srow > 815) srow = 815;
      const __bf16* kp = kp0 + (size_t)(b * 816 + srow) * kstride + g * 8;
#pragma unroll
      for (int kf = 0; kf < 8; ++kf) {
        bfx8 a = *(const bfx8*)(kp + kf * 32);
        sac = MFMA16(a, qf[kf], sac);
      }
      float pv[4];
#pragma unroll
      for (int r = 0; r < 4; ++r) {
        const int s = kv0 + mi * 16 + g * 4 + r;
        const float l = sac[r];
        const float e2 = __expf(l * 0.04f);
        const float capped = 50.f * (e2 - 1.f) / (e2 + 1.f);
        const int cms = (s >= 768) + (s >= 771);
        const bool ok = (s < 816) && (cms <= cmq);
        const float p = ok ? __expf(capped) : 0.f;
        den += p;
        pv[r] = p;
      }
      const unsigned lo = pack_bf2(pv[0], pv[1]);
      const unsigned hi = pack_bf2(pv[2], pv[3]);
      const int slot = 2 * mi + (g >> 1);
      const int phys = slot ^ (qi & 7);
      char* pb = (char*)&Ps[wid][0] + qi * 128 + phys * 16 + (g & 1) * 8;
      *(unsigned*)(pb) = lo;
      *(unsigned*)(pb + 4) = hi;
    }
    asm volatile("s_waitcnt lgkmcnt(0)" ::: "memory");
    bfx8 pa[2];
#pragma unroll
    for (int k2 = 0; k2 < 2; ++k2) {
      const int sl = (k2 * 4 + g) ^ (qi & 7);
      pa[k2] = *(const bfx8*)((const char*)&Ps[wid][0] + qi * 128 + sl * 16);
    }
#pragma unroll
    for (int hf = 0; hf < 16; ++hf) {
      const int h = hf * 16 + qi;
#pragma unroll
      for (int k2 = 0; k2 < 2; ++k2) {
        int s0 = kv0 + k2 * 32 + g * 8;
        if (s0 > 808) s0 = 808;
        bfx8 vb = *(const bfx8*)(vt + ((size_t)(b * 256 + h)) * 816 + s0);
        oacc[hf] = MFMA16(pa[k2], vb, oacc[hf]);
      }
    }
    asm volatile("s_waitcnt lgkmcnt(0)" ::: "memory");
  }

  den += __shfl_xor(den, 16, 64);
  den += __shfl_xor(den, 32, 64);
  if (lane < 16) denw[wid][qi] = den;
  asm volatile("s_waitcnt lgkmcnt(0)" ::: "memory");
#pragma unroll
  for (int r = 0; r < 4; ++r) {
    const int qg = q0 + wid * 16 + g * 4 + r;
    if (qg >= 816) continue;
    const float di = 1.f / denw[wid][g * 4 + r];
#pragma unroll
    for (int hf = 0; hf < 16; ++hf) {
      ao[((size_t)(b * 816 + qg)) * 2048 + hn * 256 + hf * 16 + qi] =
          (__bf16)(oacc[hf][r] * di);
    }
  }
}

// ---------------- Host orchestration ----------------
extern "C" void kernel_launch(void* const* d_in, const int* in_sizes, int n_in,
                              void* d_out, int out_size, void* d_ws, size_t ws_size,
                              hipStream_t stream) {
  (void)in_sizes; (void)n_in; (void)out_size;
  const float* x      = (const float*)d_in[0];
  const int*   pos    = (const int*)d_in[1];
  const float* s_attn = (const float*)d_in[4];
  const float* s_ffw  = (const float*)d_in[5];
  const float* gq     = (const float*)d_in[6];
  const float* gkv    = (const float*)d_in[7];
  const float* go     = (const float*)d_in[8];
  const float* aq     = (const float*)d_in[9];
  const float* akv    = (const float*)d_in[10];
  const float* aow    = (const float*)d_in[11];
  const float* gg     = (const float*)d_in[12];
  const float* gl     = (const float*)d_in[13];
  const float* ag     = (const float*)d_in[14];
  const float* al     = (const float*)d_in[15];
  float* outp = (float*)d_out;
  char* ws = (char*)d_ws;
  dim3 blk(256);

  const size_t NEED_BATCH = 577437696u;
  const size_t NEED_FAST  = 423297024u;

  if (ws_size >= NEED_FAST) {
    const bool batched = (ws_size >= NEED_BATCH);
    // weights (tile-panel bf16); QKV fused: [Q 16 panels][K 2][V 2] contiguous
    __bf16* wQKVg = (__bf16*)(ws + 0);          // 20 panels x 64ks x 4096
    __bf16* wQKVa = (__bf16*)(ws + 10485760);
    __bf16* goT = (__bf16*)(ws + 20971520);
    __bf16* aoT = (__bf16*)(ws + 29360128);
    __bf16* ggT = (__bf16*)(ws + 37748736);     // [2] x [16384 x 2048]
    __bf16* glT = (__bf16*)(ws + 171966464);    // [2048 x 16384]
    __bf16* agT = (__bf16*)(ws + 239075328);    // [2] x [4096 x 2048]
    __bf16* alT = (__bf16*)(ws + 272629760);    // [2048 x 4096]
    // activations
    __bf16* xn   = (__bf16*)(ws + 289406976);   // [3264][2048]
    __bf16* qkb  = (__bf16*)(ws + 302776320);   // [3264][2304]  Q cols 0-2047, K 2048-2303
    __bf16* vt   = (__bf16*)(ws + 317816832);   // [4][256][816]
    __bf16* aob  = (__bf16*)(ws + 319488000);   // [3264][2048]
    float*  ob   = (float*)(ws + 332857344);    // [3264][2048] f32
    __bf16* hb   = (__bf16*)(ws + 359596032);   // [3264][2048]
    __bf16* gate  = (__bf16*)(ws + 372965376);  // per-batch scratch
    __bf16* act   = (__bf16*)(ws + 398131200);  // per-batch [768][16384]
    __bf16* act4  = (__bf16*)(ws + 473628672);  // batched [4][768][16384]
    __bf16* actA4 = (__bf16*)(ws + 575864832);  // batched [4][48][4096]

    // weight conversion (f32 [K][N] -> bf16 panel)
    convw_kernel<<<dim3(32, 32), blk, 0, stream>>>(gq, wQKVg, 2048, 256);
    convw_kernel<<<dim3(4, 32), blk, 0, stream>>>(gkv, wQKVg + 16 * 64 * 4096, 2048, 256);
    convw_kernel<<<dim3(4, 32), blk, 0, stream>>>(gkv + 2048 * 256, wQKVg + 18 * 64 * 4096, 2048, 256);
    convw_kernel<<<dim3(32, 32), blk, 0, stream>>>(aq, wQKVa, 2048, 256);
    convw_kernel<<<dim3(4, 32), blk, 0, stream>>>(akv, wQKVa + 16 * 64 * 4096, 2048, 256);
    convw_kernel<<<dim3(4, 32), blk, 0, stream>>>(akv + 2048 * 256, wQKVa + 18 * 64 * 4096, 2048, 256);
    convw_kernel<<<dim3(32, 32), blk, 0, stream>>>(go, goT, 2048, 2048);
    convw_kernel<<<dim3(32, 32), blk, 0, stream>>>(aow, aoT, 2048, 2048);
    convw_kernel<<<dim3(256, 32), blk, 0, stream>>>(gg, ggT, 2048, 16384);
    convw_kernel<<<dim3(256, 32), blk, 0, stream>>>(gg + (size_t)2048 * 16384, ggT + (size_t)16384 * 2048, 2048, 16384);
    convw_kernel<<<dim3(32, 256), blk, 0, stream>>>(gl, glT, 16384, 2048);
    convw_kernel<<<dim3(64, 32), blk, 0, stream>>>(ag, agT, 2048, 4096);
    convw_kernel<<<dim3(64, 32), blk, 0, stream>>>(ag + (size_t)2048 * 4096, agT + (size_t)4096 * 2048, 2048, 4096);
    convw_kernel<<<dim3(32, 64), blk, 0, stream>>>(al, alT, 4096, 2048);

    // 1. pre-attention rmsnorm
    rmsnorm_kernel<<<3264, blk, 0, stream>>>(x, nullptr, s_attn, xn);

    // 2. fused QKV projection (Q,K -> qkb; V -> vt transposed), wide 256-col blocks
    dual256<<<dim3(12, 10), dim3(512), 0, stream>>>(xn, wQKVg, wQKVg + 64 * 4096, qkb, vt, nullptr,
        768, 2048, 816 * 2048, 2048, 2304, 816 * 2304, 3, 5);
    gemm_bt2<<<dim3(4, 20), blk, 0, stream>>>(xn + 768 * 2048, wQKVa, qkb + 768 * 2304, vt + 768, nullptr,
        48, 2048, 816 * 2048, 2048, 2304, 816 * 2304, 1, 5, 0);

    // 3. RoPE in place (q scaled by H^-0.5)
    rope_bf_kernel<<<3264, blk, 0, stream>>>(qkb, pos, 8, 2304, 0.0625f);
    rope_bf_kernel<<<3264, blk, 0, stream>>>(qkb + 2048, pos, 1, 2304, 1.0f);

    // 4. attention
    attn_kernel<<<dim3(13, 8, 4), blk, 0, stream>>>(qkb, qkb + 2048, vt, aob, 2304, 2304);

    // 5. output projection (wide 256-col blocks)
    dual256<<<dim3(12, 8), dim3(512), 0, stream>>>(aob, goT, goT + 64 * 4096, ob, nullptr, nullptr,
        768, 2048, 816 * 2048, 2048, 2048, 816 * 2048, 3, 0);
    gemm_bt2<<<dim3(4, 16), blk, 0, stream>>>(aob + 768 * 2048, aoT, ob + 768 * 2048, nullptr, nullptr,
        48, 2048, 816 * 2048, 2048, 2048, 816 * 2048, 1, 0, 0);

    // 6. pre-FFW rmsnorm of (o + x)
    rmsnorm_kernel<<<3264, blk, 0, stream>>>(ob, x, s_ffw, hb);

    // 7. FFN (fused gate+act dual GEMM, then wide down-proj with residual)
    if (batched) {
      dual256<<<dim3(12, 128), dim3(512), 0, stream>>>(hb, ggT, ggT + (size_t)16384 * 2048, act4, nullptr, nullptr,
          768, 2048, 816 * 2048, 2048, 16384, 768 * 16384, 3, 4);
      dual256<<<dim3(12, 8), dim3(512), 0, stream>>>(act4, glT, glT + 512 * 4096, outp, nullptr, x,
          768, 16384, 768 * 16384, 16384, 2048, 816 * 2048, 3, 2);
      ffn_dual<<<dim3(4, 32), blk, 0, stream>>>(hb + 768 * 2048, agT, agT + (size_t)4096 * 2048, actA4,
          48, 2048, 816 * 2048, 2048, 4096, 48 * 4096, 1);
      gemm_bt2<<<dim3(4, 16), blk, 0, stream>>>(actA4, alT, outp + 768 * 2048, nullptr, x + 768 * 2048,
          48, 4096, 48 * 4096, 4096, 2048, 816 * 2048, 1, 2, 0);
    } else {
      for (int bb = 0; bb < 4; ++bb) {
        const __bf16* hg = hb + (size_t)bb * 816 * 2048;
        float* og = outp + (size_t)bb * 816 * 2048;
        const float* xg = x + (size_t)bb * 816 * 2048;
        ffn_dual<<<dim3(6, 128), blk, 0, stream>>>(hg, ggT, ggT + (size_t)16384 * 2048, act,
            768, 2048, 0, 2048, 16384, 0, 6);
        gemm_bt2<<<dim3(6, 16), blk, 0, stream>>>(act, glT, og, nullptr, xg,
            768, 16384, 0, 16384, 2048, 0, 6, 2, 0);
        const __bf16* ha = hg + 768 * 2048;
        ffn_dual<<<dim3(1, 32), blk, 0, stream>>>(ha, agT, agT + (size_t)4096 * 2048, gate,
            48, 2048, 0, 2048, 4096, 0, 1);
        gemm_bt2<<<dim3(1, 16), blk, 0, stream>>>(gate, alT, og + 768 * 2048, nullptr, xg + 768 * 2048,
            48, 4096, 0, 4096, 2048, 0, 1, 2, 0);
      }
    }
    return;
  }

  // ---- legacy fallback path (round-0, on-the-fly f32 weights) ----
  if (ws_size < 164000000u) return;
  __bf16* xn   = (__bf16*)(ws + 0);
  float*  qf   = (float*)(ws + 13369344);
  __bf16* qbb  = (__bf16*)(ws + 40108032);
  float*  kf   = (float*)(ws + 53477376);
  __bf16* kbb  = (__bf16*)(ws + 56819712);
  __bf16* vt   = (__bf16*)(ws + 58490880);
  __bf16* aob  = (__bf16*)(ws + 60162048);
  float*  ob   = (float*)(ws + 73531392);
  __bf16* hb   = (__bf16*)(ws + 100270080);
  __bf16* gate = (__bf16*)(ws + 113639424);
  __bf16* act  = (__bf16*)(ws + 138805248);

  rmsnorm_kernel<<<3264, blk, 0, stream>>>(x, nullptr, s_attn, xn);
  gemm_kernel<<<dim3(24, 16), blk, 0, stream>>>(xn, gq, qf, nullptr,
      768, 2048, 816 * 2048, 256, 256, 2048, 2048, 816 * 2048, 6, 0, 0);
  gemm_kernel<<<dim3(4, 16), blk, 0, stream>>>(xn + 768 * 2048, aq, qf + 768 * 2048, nullptr,
      48, 2048, 816 * 2048, 256, 256, 2048, 2048, 816 * 2048, 1, 0, 0);
  gemm_kernel<<<dim3(24, 2), blk, 0, stream>>>(xn, gkv, kf, nullptr,
      768, 2048, 816 * 2048, 256, 256, 2048, 256, 816 * 256, 6, 0, 0);
  gemm_kernel<<<dim3(4, 2), blk, 0, stream>>>(xn + 768 * 2048, akv, kf + 768 * 256, nullptr,
      48, 2048, 816 * 2048, 256, 256, 2048, 256, 816 * 256, 1, 0, 0);
  gemm_kernel<<<dim3(24, 2), blk, 0, stream>>>(xn, gkv + 2048 * 256, vt, nullptr,
      768, 2048, 816 * 2048, 256, 256, 2048, 0, 256 * 816, 6, 3, 816);
  gemm_kernel<<<dim3(4, 2), blk, 0, stream>>>(xn + 768 * 2048, akv + 2048 * 256, vt + 768, nullptr,
      48, 2048, 816 * 2048, 256, 256, 2048, 0, 256 * 816, 1, 3, 816);
  rope_kernel<<<3264, blk, 0, stream>>>(qf, pos, qbb, 8, 0.0625f);
  rope_kernel<<<3264, blk, 0, stream>>>(kf, pos, kbb, 1, 1.0f);
  attn_kernel<<<dim3(13, 8, 4), blk, 0, stream>>>(qbb, kbb, vt, aob, 2048, 256);
  gemm_kernel<<<dim3(24, 16), blk, 0, stream>>>(aob, go, ob, nullptr,
      768, 2048, 816 * 2048, 2048, 0, 2048, 2048, 816 * 2048, 6, 0, 0);
  gemm_kernel<<<dim3(4, 16), blk, 0, stream>>>(aob + 768 * 2048, aow, ob + 768 * 2048, nullptr,
      48, 2048, 816 * 2048, 2048, 0, 2048, 2048, 816 * 2048, 1, 0, 0);
  rmsnorm_kernel<<<3264, blk, 0, stream>>>(ob, x, s_ffw, hb);
  for (int bb = 0; bb < 4; ++bb) {
    const __bf16* hg = hb + (size_t)bb * 816 * 2048;
    float* og = outp + (size_t)bb * 816 * 2048;
    const float* xg = x + (size_t)bb * 816 * 2048;
    gemm_kernel<<<dim3(6, 128), blk, 0, stream>>>(hg, gg, gate, nullptr,
        768, 2048, 0, 16384, 0, 2048, 16384, 0, 6, 1, 0);
    gemm_kernel<<<dim3(6, 128), blk, 0, stream>>>(hg, gg + 2048 * 16384, act, gate,
        768, 2048, 0, 16384, 0, 2048, 16384, 0, 6, 4, 0);
    gemm_kernel<<<dim3(6, 16), blk, 0, stream>>>(act, gl, og, xg,
        768, 16384, 0, 2048, 0, 16384, 2048, 0, 6, 2, 0);
    const __bf16* ha = hg + 768 * 2048;
    gemm_kernel<<<dim3(1, 32), blk, 0, stream>>>(ha, ag, gate, nullptr,
        48, 2048, 0, 4096, 0, 2048, 4096, 0, 1, 1, 0);
    gemm_kernel<<<dim3(1, 32), blk, 0, stream>>>(ha, ag + 2048 * 4096, act, gate,
        48, 2048, 0, 4096, 0, 2048, 4096, 0, 1, 4, 0);
    gemm_kernel<<<dim3(1, 16), blk, 0, stream>>>(act, al, og + 768 * 2048, xg + 768 * 2048,
        48, 4096, 0, 2048, 0, 4096, 2048, 0, 1, 2, 0);
  }
}

// Round 15
// 1409.546 us; speedup vs baseline: 1.1022x; 1.1022x over previous
//
#include <hip/hip_runtime.h>
#include <hip/hip_bf16.h>

typedef __bf16 bfx8 __attribute__((ext_vector_type(8)));
typedef __bf16 bfx4 __attribute__((ext_vector_type(4)));
typedef float f32x4 __attribute__((ext_vector_type(4)));

#define MFMA16(a, b, c) __builtin_amdgcn_mfma_f32_16x16x32_bf16((a), (b), (c), 0, 0, 0)

__device__ __forceinline__ void gl_lds16(const __bf16* g, __bf16* l) {
  __builtin_amdgcn_global_load_lds(
      (const __attribute__((address_space(1))) unsigned int*)(const void*)g,
      (__attribute__((address_space(3))) unsigned int*)(void*)l, 16, 0, 0);
}

__device__ __forceinline__ unsigned pack_bf2(float a, float b) {
  unsigned short ua = __builtin_bit_cast(unsigned short, (__bf16)a);
  unsigned short ub = __builtin_bit_cast(unsigned short, (__bf16)b);
  return (unsigned)ua | ((unsigned)ub << 16);
}

__device__ __forceinline__ float gelu_tanh_f(float x) {
  float u = 0.7978845608028654f * (x + 0.044715f * x * x * x);
  float t;
  if (u > 10.f) t = 1.f;
  else if (u < -10.f) t = -1.f;
  else { float e = __expf(2.f * u); t = (e - 1.f) / (e + 1.f); }
  return 0.5f * x * (1.f + t);
}

// ---------------- RMSNorm (optionally fused residual add) ----------------
__global__ __launch_bounds__(256)
void rmsnorm_kernel(const float* __restrict__ X, const float* __restrict__ X2,
                    const float* __restrict__ scale, __bf16* __restrict__ out) {
  __shared__ float wsum[4];
  const int row = blockIdx.x, tid = threadIdx.x;
  const size_t base = (size_t)row * 2048;
  f32x4 v[2];
  float ss = 0.f;
#pragma unroll
  for (int i = 0; i < 2; ++i) {
    const int idx = tid * 4 + i * 1024;
    v[i] = *(const f32x4*)(X + base + idx);
    if (X2) { f32x4 u = *(const f32x4*)(X2 + base + idx); v[i] = v[i] + u; }
#pragma unroll
    for (int j = 0; j < 4; ++j) ss += v[i][j] * v[i][j];
  }
#pragma unroll
  for (int o = 32; o > 0; o >>= 1) ss += __shfl_xor(ss, o, 64);
  if ((tid & 63) == 0) wsum[tid >> 6] = ss;
  __syncthreads();
  const float tot = wsum[0] + wsum[1] + wsum[2] + wsum[3];
  const float rs = rsqrtf(tot * (1.f / 2048.f) + 1e-6f);
#pragma unroll
  for (int i = 0; i < 2; ++i) {
    const int idx = tid * 4 + i * 1024;
    f32x4 sc = *(const f32x4*)(scale + idx);
    bfx4 ov;
#pragma unroll
    for (int j = 0; j < 4; ++j) ov[j] = (__bf16)(v[i][j] * rs * (1.f + sc[j]));
    *(bfx4*)(out + base + idx) = ov;
  }
}

// ---------------- RoPE in-place on bf16 (+ optional scale), stride param ----------------
__global__ __launch_bounds__(256)
void rope_bf_kernel(__bf16* __restrict__ buf, const int* __restrict__ pos,
                    int nheads, int rstride, float outscale) {
  const int row = blockIdx.x;
  const float p = (float)pos[row];
  const int total = nheads * 128;
  const size_t rbase = (size_t)row * (size_t)rstride;
  for (int idx = threadIdx.x; idx < total; idx += 256) {
    const int n = idx >> 7, i = idx & 127;
    const float ts = __expf(-(float)i * 0.071955784f);  // 10000^(-i/128)
    float sn, cs;
    __sincosf(p * ts, &sn, &cs);
    __bf16* bp = buf + rbase + n * 256 + i;
    const float x1 = (float)bp[0], x2 = (float)bp[128];
    bp[0]   = (__bf16)((x1 * cs - x2 * sn) * outscale);
    bp[128] = (__bf16)((x2 * cs + x1 * sn) * outscale);
  }
}

// ---------------- RoPE f32 -> bf16 (fallback path) ----------------
__global__ __launch_bounds__(256)
void rope_kernel(const float* __restrict__ in, const int* __restrict__ pos,
                 __bf16* __restrict__ outp, int nheads, float outscale) {
  const int row = blockIdx.x;
  const float p = (float)pos[row];
  const int total = nheads * 128;
  const size_t rbase = (size_t)row * (size_t)(nheads * 256);
  for (int idx = threadIdx.x; idx < total; idx += 256) {
    const int n = idx >> 7, i = idx & 127;
    const float ts = __expf(-(float)i * 0.071955784f);
    float sn, cs;
    __sincosf(p * ts, &sn, &cs);
    const float* bp = in + rbase + n * 256 + i;
    const float x1 = bp[0], x2 = bp[128];
    __bf16* ob = outp + rbase + n * 256 + i;
    ob[0]   = (__bf16)((x1 * cs - x2 * sn) * outscale);
    ob[128] = (__bf16)((x2 * cs + x1 * sn) * outscale);
  }
}

// ---------------- Weight convert: f32 W[k][c] -> bf16 tile-panel layout ----------------
// Panel: (cp*(K/32)+ks)*4096 holds the 128x32 tile pre-swizzled in LDS-linear order:
// element (m=col&127, k): lg=(k%32)/8, p=lg^((m>>1)&3), offset = m*32 + p*8 + (k&7).
__global__ __launch_bounds__(256)
void convw_kernel(const float* __restrict__ in, __bf16* __restrict__ out,
                  int K, int headDim) {
  __shared__ __bf16 tile[64][65];
  const int tc0 = blockIdx.x * 64;
  const int tk0 = blockIdx.y * 64;
  const int tid = threadIdx.x;
  const int cchunk = tid & 15, krow = tid >> 4;
  const int c = tc0 + cchunk * 4;
  const float* colbase = in + (size_t)(c / headDim) * (size_t)K * headDim + (c % headDim);
#pragma unroll
  for (int i = 0; i < 4; ++i) {
    const int k = tk0 + krow + i * 16;
    f32x4 v = *(const f32x4*)(colbase + (size_t)k * headDim);
#pragma unroll
    for (int j = 0; j < 4; ++j) tile[cchunk * 4 + j][krow + i * 16] = (__bf16)v[j];
  }
  __syncthreads();
  const int nks = K >> 5;
#pragma unroll
  for (int s = 0; s < 2; ++s) {
    const int ch = tid + s * 256;
    const int wc = ch >> 3, wk8 = (ch & 7) * 8;
    bfx8 v;
#pragma unroll
    for (int j = 0; j < 8; ++j) v[j] = tile[wc][wk8 + j];
    const int col = tc0 + wc;
    const int kchunk = (tk0 + wk8) >> 3;
    const int cp = col >> 7, m = col & 127;
    const int ks = kchunk >> 2, lg = kchunk & 3;
    const int p = lg ^ ((m >> 1) & 3);
    *(bfx8*)(out + ((size_t)(cp * nks + ks)) * 4096 + m * 32 + p * 8) = v;
  }
}

// ---------------- 2-phase fused GEGLU dual-GEMM (256x128 tile, 512 threads) ----------
// C = gelu(A·Wg) * (A·Wa), bf16 out. XCD-chunked block swizzle.
__global__ __launch_bounds__(512, 2)
void ffn_dual256(const __bf16* __restrict__ A, const __bf16* __restrict__ Wg,
                 const __bf16* __restrict__ Wa, __bf16* __restrict__ C,
                 int Mpb, int lda, int strideA, int Kd,
                 int ldc, int strideC, int mbPerBatch) {
  __shared__ __align__(16) __bf16 As[2 * 2 * 8192];  // [buf][half][128x64]
  __shared__ __align__(16) __bf16 Bs[2 * 2 * 8192];  // [buf][pan][128x64]
  const int tid = threadIdx.x;
  const int lane = tid & 63;
  const int wid = tid >> 6;
  const int wr = wid >> 2;
  const int wc = wid & 3;
  const int qi = lane & 15, g = lane >> 4;
  // XCD-chunked swizzle (nwg divisible by 8)
  int bid = blockIdx.y * gridDim.x + blockIdx.x;
  const int nwg = gridDim.x * gridDim.y;
  if ((nwg & 7) == 0) bid = (bid & 7) * (nwg >> 3) + (bid >> 3);
  const int bx = bid % gridDim.x, by = bid / gridDim.x;
  const int b = bx / mbPerBatch;
  const int row0 = (bx % mbPerBatch) * 256;
  const int col0 = by * 128;
  const __bf16* Ab = A + (size_t)b * strideA;
  const size_t nks = (size_t)(Kd >> 5);
  const __bf16* Bgp = Wg + ((size_t)(col0 >> 7)) * nks * 4096;
  const __bf16* Bap = Wa + ((size_t)(col0 >> 7)) * nks * 4096;
  const int NT = Kd >> 6;

  const int sm = tid >> 2, sp = tid & 3;
  const int slg = sp ^ ((sm >> 1) & 3);
  int r0 = row0 + sm;       if (r0 >= Mpb) r0 = Mpb - 1;
  int r1 = row0 + 128 + sm; if (r1 >= Mpb) r1 = Mpb - 1;
  const __bf16* asrc0 = Ab + (size_t)r0 * lda + slg * 8;
  const __bf16* asrc1 = Ab + (size_t)r1 * lda + slg * 8;

  // half order per K-tile t: 0=A0, 1=Bg, 2=A1, 3=Ba
  auto stage_half = [&](int gh) {
    if (gh >= 4 * NT) return;
    const int t = gh >> 2, which = gh & 3;
    const int bufi = t & 1;
    if ((which & 1) == 0) {
      const int h = which >> 1;
      __bf16* dst = &As[bufi * 16384 + h * 8192];
      const __bf16* src = (h ? asrc1 : asrc0) + t * 64;
      gl_lds16(src, dst + tid * 8);
      gl_lds16(src + 32, dst + 4096 + tid * 8);
    } else {
      const int pan = which >> 1;
      __bf16* dst = &Bs[bufi * 16384 + pan * 8192];
      const __bf16* src = (pan ? Bap : Bgp) + (size_t)(t * 2) * 4096 + tid * 8;
      gl_lds16(src, dst + tid * 8);
      gl_lds16(src + 4096, dst + 4096 + tid * 8);
    }
  };

  f32x4 acc[2][2][4][2];
#pragma unroll
  for (int a0 = 0; a0 < 2; ++a0)
#pragma unroll
    for (int a1 = 0; a1 < 2; ++a1)
#pragma unroll
      for (int a2 = 0; a2 < 4; ++a2)
#pragma unroll
        for (int a3 = 0; a3 < 2; ++a3) acc[a0][a1][a2][a3] = f32x4{0.f, 0.f, 0.f, 0.f};

  for (int gh = 0; gh < 6; ++gh) stage_half(gh);
  asm volatile("s_waitcnt vmcnt(4)" ::: "memory");
  __builtin_amdgcn_s_barrier();
  asm volatile("" ::: "memory");

  for (int t = 0; t < NT; ++t) {
    const int cb = (t & 1) * 16384;
    bfx8 af[4][2], bf[2][2][2];

    // ---- PHASE 0: A-half 0, both panels ----
#pragma unroll
    for (int mi = 0; mi < 4; ++mi) {
      const int m = wr * 64 + mi * 16 + qi;
      const int sl = g ^ ((m >> 1) & 3);
      const int ba = cb + m * 32 + sl * 8;
      af[mi][0] = *(const bfx8*)(&As[ba]);
      af[mi][1] = *(const bfx8*)(&As[ba + 4096]);
    }
#pragma unroll
    for (int pan = 0; pan < 2; ++pan)
#pragma unroll
      for (int ni = 0; ni < 2; ++ni) {
        const int m = wc * 32 + ni * 16 + qi;
        const int sl = g ^ ((m >> 1) & 3);
        const int bb = cb + pan * 8192 + m * 32 + sl * 8;
        bf[pan][ni][0] = *(const bfx8*)(&Bs[bb]);
        bf[pan][ni][1] = *(const bfx8*)(&Bs[bb + 4096]);
      }
    stage_half(4 * t + 6);
    stage_half(4 * t + 7);
    __builtin_amdgcn_s_barrier();
    asm volatile("s_waitcnt lgkmcnt(0)" ::: "memory");
    __builtin_amdgcn_sched_barrier(0);
    __builtin_amdgcn_s_setprio(1);
#pragma unroll
    for (int pan = 0; pan < 2; ++pan)
#pragma unroll
      for (int mi = 0; mi < 4; ++mi)
#pragma unroll
        for (int ni = 0; ni < 2; ++ni) {
          acc[0][pan][mi][ni] = MFMA16(af[mi][0], bf[pan][ni][0], acc[0][pan][mi][ni]);
          acc[0][pan][mi][ni] = MFMA16(af[mi][1], bf[pan][ni][1], acc[0][pan][mi][ni]);
        }
    __builtin_amdgcn_s_setprio(0);
    __builtin_amdgcn_s_barrier();
    asm volatile("" ::: "memory");

    // ---- PHASE 1: A-half 1, reuse bf ----
#pragma unroll
    for (int mi = 0; mi < 4; ++mi) {
      const int m = wr * 64 + mi * 16 + qi;
      const int sl = g ^ ((m >> 1) & 3);
      const int ba = cb + 8192 + m * 32 + sl * 8;
      af[mi][0] = *(const bfx8*)(&As[ba]);
      af[mi][1] = *(const bfx8*)(&As[ba + 4096]);
    }
    stage_half(4 * t + 8);
    stage_half(4 * t + 9);
    if (t + 2 < NT) asm volatile("s_waitcnt vmcnt(4)" ::: "memory");
    else            asm volatile("s_waitcnt vmcnt(0)" ::: "memory");
    __builtin_amdgcn_s_barrier();
    asm volatile("s_waitcnt lgkmcnt(0)" ::: "memory");
    __builtin_amdgcn_sched_barrier(0);
    __builtin_amdgcn_s_setprio(1);
#pragma unroll
    for (int pan = 0; pan < 2; ++pan)
#pragma unroll
      for (int mi = 0; mi < 4; ++mi)
#pragma unroll
        for (int ni = 0; ni < 2; ++ni) {
          acc[1][pan][mi][ni] = MFMA16(af[mi][0], bf[pan][ni][0], acc[1][pan][mi][ni]);
          acc[1][pan][mi][ni] = MFMA16(af[mi][1], bf[pan][ni][1], acc[1][pan][mi][ni]);
        }
    __builtin_amdgcn_s_setprio(0);
    __builtin_amdgcn_s_barrier();
    asm volatile("" ::: "memory");
  }

#pragma unroll
  for (int mh = 0; mh < 2; ++mh)
#pragma unroll
    for (int mi = 0; mi < 4; ++mi)
#pragma unroll
      for (int ni = 0; ni < 2; ++ni) {
        const int col = col0 + wc * 32 + ni * 16 + qi;
#pragma unroll
        for (int r = 0; r < 4; ++r) {
          const int row = row0 + mh * 128 + wr * 64 + mi * 16 + g * 4 + r;
          if (row >= Mpb) continue;
          C[(size_t)b * strideC + (size_t)row * ldc + col] =
              (__bf16)(gelu_tanh_f(acc[mh][0][mi][ni][r]) * acc[mh][1][mi][ni][r]);
        }
      }
}

// ---------------- 2-phase single GEMM (256x128 tile, 512 threads) ----------------
// C[b,row,col] = sum_k A[b,row,k]*W[k,col]. outMode: 0 f32, 2 f32+Extra residual,
// 5 QKV scatter (col<2304 bf16; col>=2304 V transposed into C2).
__global__ __launch_bounds__(512, 2)
void gemm256(const __bf16* __restrict__ A, const __bf16* __restrict__ Bt,
             void* __restrict__ C, void* __restrict__ C2, const void* __restrict__ Extra,
             int Mpb, int lda, int strideA, int Kd,
             int ldc, int strideC, int mbPerBatch, int outMode) {
  __shared__ __align__(16) __bf16 As[2 * 2 * 8192];  // [buf][half][128x64]
  __shared__ __align__(16) __bf16 Bs[2 * 8192];      // [buf][128x64]
  const int tid = threadIdx.x;
  const int lane = tid & 63;
  const int wid = tid >> 6;
  const int wr = wid >> 2;
  const int wc = wid & 3;
  const int qi = lane & 15, g = lane >> 4;
  int bid = blockIdx.y * gridDim.x + blockIdx.x;
  const int nwg = gridDim.x * gridDim.y;
  if ((nwg & 7) == 0) bid = (bid & 7) * (nwg >> 3) + (bid >> 3);
  const int bx = bid % gridDim.x, by = bid / gridDim.x;
  const int b = bx / mbPerBatch;
  const int row0 = (bx % mbPerBatch) * 256;
  const int col0 = by * 128;
  const __bf16* Ab = A + (size_t)b * strideA;
  const size_t nks = (size_t)(Kd >> 5);
  const __bf16* Bp = Bt + ((size_t)(col0 >> 7)) * nks * 4096;
  const int NT = Kd >> 6;

  const int sm = tid >> 2, sp = tid & 3;
  const int slg = sp ^ ((sm >> 1) & 3);
  int r0 = row0 + sm;       if (r0 >= Mpb) r0 = Mpb - 1;
  int r1 = row0 + 128 + sm; if (r1 >= Mpb) r1 = Mpb - 1;
  const __bf16* asrc0 = Ab + (size_t)r0 * lda + slg * 8;
  const __bf16* asrc1 = Ab + (size_t)r1 * lda + slg * 8;

  // half order per K-tile t: 0=A0, 1=B, 2=A1
  auto stage_half = [&](int gh) {
    if (gh >= 3 * NT) return;
    const int t = gh / 3, which = gh - 3 * t;
    const int bufi = t & 1;
    if (which == 1) {
      __bf16* dst = &Bs[bufi * 8192];
      const __bf16* src = Bp + (size_t)(t * 2) * 4096 + tid * 8;
      gl_lds16(src, dst + tid * 8);
      gl_lds16(src + 4096, dst + 4096 + tid * 8);
    } else {
      const int h = which >> 1;  // 0 -> A0, 2 -> A1
      __bf16* dst = &As[bufi * 16384 + h * 8192];
      const __bf16* src = (h ? asrc1 : asrc0) + t * 64;
      gl_lds16(src, dst + tid * 8);
      gl_lds16(src + 32, dst + 4096 + tid * 8);
    }
  };

  f32x4 acc[2][4][2];  // [mh][mi][ni]
#pragma unroll
  for (int a0 = 0; a0 < 2; ++a0)
#pragma unroll
    for (int a2 = 0; a2 < 4; ++a2)
#pragma unroll
      for (int a3 = 0; a3 < 2; ++a3) acc[a0][a2][a3] = f32x4{0.f, 0.f, 0.f, 0.f};

  // prologue: tile0 full + A0,B of tile1 (halves 0..4 = 10 loads); wait tile0 (6 loads)
  for (int gh = 0; gh < 5; ++gh) stage_half(gh);
  asm volatile("s_waitcnt vmcnt(4)" ::: "memory");
  __builtin_amdgcn_s_barrier();
  asm volatile("" ::: "memory");

  for (int t = 0; t < NT; ++t) {
    const int cb = (t & 1) * 16384;
    const int cbB = (t & 1) * 8192;
    bfx8 af[4][2], bf[2][2];

    // ---- PHASE 0: A-half 0 + B (B kept for phase 1) ----
#pragma unroll
    for (int mi = 0; mi < 4; ++mi) {
      const int m = wr * 64 + mi * 16 + qi;
      const int sl = g ^ ((m >> 1) & 3);
      const int ba = cb + m * 32 + sl * 8;
      af[mi][0] = *(const bfx8*)(&As[ba]);
      af[mi][1] = *(const bfx8*)(&As[ba + 4096]);
    }
#pragma unroll
    for (int ni = 0; ni < 2; ++ni) {
      const int m = wc * 32 + ni * 16 + qi;
      const int sl = g ^ ((m >> 1) & 3);
      const int bb = cbB + m * 32 + sl * 8;
      bf[ni][0] = *(const bfx8*)(&Bs[bb]);
      bf[ni][1] = *(const bfx8*)(&Bs[bb + 4096]);
    }
    stage_half(3 * t + 5);  // A1 of tile t+1
    __builtin_amdgcn_s_barrier();
    asm volatile("s_waitcnt lgkmcnt(0)" ::: "memory");
    __builtin_amdgcn_sched_barrier(0);
    __builtin_amdgcn_s_setprio(1);
#pragma unroll
    for (int mi = 0; mi < 4; ++mi)
#pragma unroll
      for (int ni = 0; ni < 2; ++ni) {
        acc[0][mi][ni] = MFMA16(af[mi][0], bf[ni][0], acc[0][mi][ni]);
        acc[0][mi][ni] = MFMA16(af[mi][1], bf[ni][1], acc[0][mi][ni]);
      }
    __builtin_amdgcn_s_setprio(0);
    __builtin_amdgcn_s_barrier();
    asm volatile("" ::: "memory");

    // ---- PHASE 1: A-half 1, reuse bf ----
#pragma unroll
    for (int mi = 0; mi < 4; ++mi) {
      const int m = wr * 64 + mi * 16 + qi;
      const int sl = g ^ ((m >> 1) & 3);
      const int ba = cb + 8192 + m * 32 + sl * 8;
      af[mi][0] = *(const bfx8*)(&As[ba]);
      af[mi][1] = *(const bfx8*)(&As[ba + 4096]);
    }
    stage_half(3 * t + 6);  // A0 of tile t+2
    stage_half(3 * t + 7);  // B  of tile t+2
    if (t + 2 < NT) asm volatile("s_waitcnt vmcnt(4)" ::: "memory");
    else            asm volatile("s_waitcnt vmcnt(0)" ::: "memory");
    __builtin_amdgcn_s_barrier();
    asm volatile("s_waitcnt lgkmcnt(0)" ::: "memory");
    __builtin_amdgcn_sched_barrier(0);
    __builtin_amdgcn_s_setprio(1);
#pragma unroll
    for (int mi = 0; mi < 4; ++mi)
#pragma unroll
      for (int ni = 0; ni < 2; ++ni) {
        acc[1][mi][ni] = MFMA16(af[mi][0], bf[ni][0], acc[1][mi][ni]);
        acc[1][mi][ni] = MFMA16(af[mi][1], bf[ni][1], acc[1][mi][ni]);
      }
    __builtin_amdgcn_s_setprio(0);
    __builtin_amdgcn_s_barrier();
    asm volatile("" ::: "memory");
  }

#pragma unroll
  for (int mh = 0; mh < 2; ++mh)
#pragma unroll
    for (int mi = 0; mi < 4; ++mi)
#pragma unroll
      for (int ni = 0; ni < 2; ++ni) {
        const int col = col0 + wc * 32 + ni * 16 + qi;
        if (outMode == 5 && col >= 2304) {
          const int vcol = col - 2304;
          const int rowb = row0 + mh * 128 + wr * 64 + mi * 16 + g * 4;
          if (rowb < Mpb) {
            bfx4 ov;
#pragma unroll
            for (int r = 0; r < 4; ++r) ov[r] = (__bf16)acc[mh][mi][ni][r];
            *(bfx4*)((__bf16*)C2 + (size_t)b * (256 * 816) + (size_t)vcol * 816 + rowb) = ov;
          }
          continue;
        }
#pragma unroll
        for (int r = 0; r < 4; ++r) {
          const int row = row0 + mh * 128 + wr * 64 + mi * 16 + g * 4 + r;
          if (row >= Mpb) continue;
          const float v = acc[mh][mi][ni][r];
          if (outMode == 0) {
            ((float*)C)[(size_t)b * strideC + (size_t)row * ldc + col] = v;
          } else if (outMode == 5) {
            ((__bf16*)C)[(size_t)b * strideC + (size_t)row * ldc + col] = (__bf16)v;
          } else {  // mode 2
            const size_t ix = (size_t)b * strideC + (size_t)row * ldc + col;
            ((float*)C)[ix] = v + ((const float*)Extra)[ix];
          }
        }
      }
}

// ---------------- bf16 GEMM, panel weights, BK=64, counted-vmcnt (small-M path) ------
__global__ __launch_bounds__(256, 2)
void gemm_bt2(const __bf16* __restrict__ A, const __bf16* __restrict__ Bt,
              void* __restrict__ C, void* __restrict__ C2, const void* __restrict__ Extra,
              int Mpb, int lda, int strideA, int Kd,
              int ldc, int strideC, int mbPerBatch,
              int outMode, int ldct) {
  __shared__ __align__(16) __bf16 As[2][8192];
  __shared__ __align__(16) __bf16 Bs[2][8192];
  const int tid = threadIdx.x;
  const int lane = tid & 63;
  const int wid = tid >> 6;
  const int b = blockIdx.x / mbPerBatch;
  const int row0 = (blockIdx.x % mbPerBatch) * 128;
  const int col0 = blockIdx.y * 128;
  const __bf16* Ab = A + (size_t)b * strideA;
  const size_t nks = (size_t)(Kd >> 5);
  const __bf16* Bpan0 = Bt + ((size_t)(col0 >> 7)) * nks * 4096;
  const int wm = (wid >> 1) * 64, wn = (wid & 1) * 64;
  const int qi = lane & 15, g = lane >> 4;

  const int m0 = tid >> 2, p0 = tid & 3;
  const int lg0 = p0 ^ ((m0 >> 1) & 3);
  const int m1 = m0 + 64;
  const int lg1 = p0 ^ ((m1 >> 1) & 3);
  int mr0 = row0 + m0; if (mr0 >= Mpb) mr0 = Mpb - 1;
  int mr1 = row0 + m1; if (mr1 >= Mpb) mr1 = Mpb - 1;
  const __bf16* asrc0 = Ab + (size_t)mr0 * lda + lg0 * 8;
  const __bf16* asrc1 = Ab + (size_t)mr1 * lda + lg1 * 8;
  const int nt = Kd >> 6;

  auto stage = [&](int t, int bufi) {
    const int k0 = t * 64;
    gl_lds16(asrc0 + k0, &As[bufi][tid * 8]);
    gl_lds16(asrc1 + k0, &As[bufi][(tid + 256) * 8]);
    gl_lds16(asrc0 + k0 + 32, &As[bufi][4096 + tid * 8]);
    gl_lds16(asrc1 + k0 + 32, &As[bufi][4096 + (tid + 256) * 8]);
    const __bf16* pb = Bpan0 + (size_t)(k0 >> 5) * 4096;
    gl_lds16(pb + tid * 8, &Bs[bufi][tid * 8]);
    gl_lds16(pb + (tid + 256) * 8, &Bs[bufi][(tid + 256) * 8]);
    gl_lds16(pb + 4096 + tid * 8, &Bs[bufi][4096 + tid * 8]);
    gl_lds16(pb + 4096 + (tid + 256) * 8, &Bs[bufi][4096 + (tid + 256) * 8]);
  };

  f32x4 acc[4][4];
#pragma unroll
  for (int i = 0; i < 4; ++i)
#pragma unroll
    for (int j = 0; j < 4; ++j) acc[i][j] = f32x4{0.f, 0.f, 0.f, 0.f};

  stage(0, 0);
  if (nt > 1) stage(1, 1);

  for (int t = 0; t < nt; ++t) {
    const int cur = t & 1;
    if (t + 1 < nt) asm volatile("s_waitcnt vmcnt(8)" ::: "memory");
    else            asm volatile("s_waitcnt vmcnt(0)" ::: "memory");
    __builtin_amdgcn_s_barrier();
    asm volatile("" ::: "memory");
#pragma unroll
    for (int ks = 0; ks < 2; ++ks) {
      bfx8 af[4], bf[4];
#pragma unroll
      for (int mi = 0; mi < 4; ++mi) {
        const int m = wm + mi * 16 + qi;
        const int sl = g ^ ((m >> 1) & 3);
        af[mi] = *(const bfx8*)(&As[cur][ks * 4096 + m * 32 + sl * 8]);
      }
#pragma unroll
      for (int ni = 0; ni < 4; ++ni) {
        const int n = wn + ni * 16 + qi;
        const int sl = g ^ ((n >> 1) & 3);
        bf[ni] = *(const bfx8*)(&Bs[cur][ks * 4096 + n * 32 + sl * 8]);
      }
#pragma unroll
      for (int mi = 0; mi < 4; ++mi)
#pragma unroll
        for (int ni = 0; ni < 4; ++ni)
          acc[mi][ni] = MFMA16(af[mi], bf[ni], acc[mi][ni]);
    }
    asm volatile("s_waitcnt lgkmcnt(0)" ::: "memory");
    __builtin_amdgcn_s_barrier();
    asm volatile("" ::: "memory");
    if (t + 2 < nt) stage(t + 2, cur);
  }

#pragma unroll
  for (int mi = 0; mi < 4; ++mi) {
#pragma unroll
    for (int ni = 0; ni < 4; ++ni) {
      const int col = col0 + wn + ni * 16 + qi;
      if (outMode == 5 && col >= 2304) {
        const int vcol = col - 2304;
        const int rowb = row0 + wm + mi * 16 + g * 4;
        if (rowb < Mpb) {
          bfx4 ov;
#pragma unroll
          for (int r = 0; r < 4; ++r) ov[r] = (__bf16)acc[mi][ni][r];
          *(bfx4*)((__bf16*)C2 + (size_t)b * (256 * 816) + (size_t)vcol * 816 + rowb) = ov;
        }
        continue;
      }
#pragma unroll
      for (int r = 0; r < 4; ++r) {
        const int row = row0 + wm + mi * 16 + g * 4 + r;
        if (row >= Mpb) continue;
        const float v = acc[mi][ni][r];
        if (outMode == 0) {
          ((float*)C)[(size_t)b * strideC + (size_t)row * ldc + col] = v;
        } else if (outMode == 1 || outMode == 5) {
          ((__bf16*)C)[(size_t)b * strideC + (size_t)row * ldc + col] = (__bf16)v;
        } else {  // mode 2
          const size_t ix = (size_t)b * strideC + (size_t)row * ldc + col;
          ((float*)C)[ix] = v + ((const float*)Extra)[ix];
        }
      }
    }
  }
  (void)ldct;
}

// ---------------- Fused GEGLU dual-GEMM (128-tile, small-M path) ----------------
__global__ __launch_bounds__(256, 2)
void ffn_dual(const __bf16* __restrict__ A, const __bf16* __restrict__ Wg,
              const __bf16* __restrict__ Wa, __bf16* __restrict__ C,
              int Mpb, int lda, int strideA, int Kd,
              int ldc, int strideC, int mbPerBatch) {
  __shared__ __align__(16) __bf16 As[2][8192];
  __shared__ __align__(16) __bf16 Bs[2][8192];
  const int tid = threadIdx.x;
  const int lane = tid & 63;
  const int wid = tid >> 6;
  const int b = blockIdx.x / mbPerBatch;
  const int row0 = (blockIdx.x % mbPerBatch) * 128;
  const int col0 = blockIdx.y * 128;
  const __bf16* Ab = A + (size_t)b * strideA;
  const size_t nks = (size_t)(Kd >> 5);
  const int wm = (wid >> 1) * 64, wn = (wid & 1) * 64;
  const int qi = lane & 15, g = lane >> 4;

  const int m0 = tid >> 2, p0 = tid & 3;
  const int lg0 = p0 ^ ((m0 >> 1) & 3);
  const int m1 = m0 + 64;
  const int lg1 = p0 ^ ((m1 >> 1) & 3);
  int mr0 = row0 + m0; if (mr0 >= Mpb) mr0 = Mpb - 1;
  int mr1 = row0 + m1; if (mr1 >= Mpb) mr1 = Mpb - 1;
  const __bf16* asrc0 = Ab + (size_t)mr0 * lda + lg0 * 8;
  const __bf16* asrc1 = Ab + (size_t)mr1 * lda + lg1 * 8;
  const int nt = Kd >> 6;

  f32x4 gval[4][4];
  f32x4 acc[4][4];

#pragma unroll
  for (int pan = 0; pan < 2; ++pan) {
    const __bf16* Bpan0 = (pan ? Wa : Wg) + ((size_t)(col0 >> 7)) * nks * 4096;

    auto stage = [&](int t, int bufi) {
      const int k0 = t * 64;
      gl_lds16(asrc0 + k0, &As[bufi][tid * 8]);
      gl_lds16(asrc1 + k0, &As[bufi][(tid + 256) * 8]);
      gl_lds16(asrc0 + k0 + 32, &As[bufi][4096 + tid * 8]);
      gl_lds16(asrc1 + k0 + 32, &As[bufi][4096 + (tid + 256) * 8]);
      const __bf16* pb = Bpan0 + (size_t)(k0 >> 5) * 4096;
      gl_lds16(pb + tid * 8, &Bs[bufi][tid * 8]);
      gl_lds16(pb + (tid + 256) * 8, &Bs[bufi][(tid + 256) * 8]);
      gl_lds16(pb + 4096 + tid * 8, &Bs[bufi][4096 + tid * 8]);
      gl_lds16(pb + 4096 + (tid + 256) * 8, &Bs[bufi][4096 + (tid + 256) * 8]);
    };

#pragma unroll
    for (int i = 0; i < 4; ++i)
#pragma unroll
      for (int j = 0; j < 4; ++j) acc[i][j] = f32x4{0.f, 0.f, 0.f, 0.f};

    stage(0, 0);
    if (nt > 1) stage(1, 1);

    for (int t = 0; t < nt; ++t) {
      const int cur = t & 1;
      if (t + 1 < nt) asm volatile("s_waitcnt vmcnt(8)" ::: "memory");
      else            asm volatile("s_waitcnt vmcnt(0)" ::: "memory");
      __builtin_amdgcn_s_barrier();
      asm volatile("" ::: "memory");
#pragma unroll
      for (int ks = 0; ks < 2; ++ks) {
        bfx8 af[4], bf[4];
#pragma unroll
        for (int mi = 0; mi < 4; ++mi) {
          const int m = wm + mi * 16 + qi;
          const int sl = g ^ ((m >> 1) & 3);
          af[mi] = *(const bfx8*)(&As[cur][ks * 4096 + m * 32 + sl * 8]);
        }
#pragma unroll
        for (int ni = 0; ni < 4; ++ni) {
          const int n = wn + ni * 16 + qi;
          const int sl = g ^ ((n >> 1) & 3);
          bf[ni] = *(const bfx8*)(&Bs[cur][ks * 4096 + n * 32 + sl * 8]);
        }
#pragma unroll
        for (int mi = 0; mi < 4; ++mi)
#pragma unroll
          for (int ni = 0; ni < 4; ++ni)
            acc[mi][ni] = MFMA16(af[mi], bf[ni], acc[mi][ni]);
      }
      asm volatile("s_waitcnt lgkmcnt(0)" ::: "memory");
      __builtin_amdgcn_s_barrier();
      asm volatile("" ::: "memory");
      if (t + 2 < nt) stage(t + 2, cur);
    }

    if (pan == 0) {
#pragma unroll
      for (int i = 0; i < 4; ++i)
#pragma unroll
        for (int j = 0; j < 4; ++j)
#pragma unroll
          for (int r = 0; r < 4; ++r) gval[i][j][r] = gelu_tanh_f(acc[i][j][r]);
    }
  }

#pragma unroll
  for (int mi = 0; mi < 4; ++mi) {
#pragma unroll
    for (int ni = 0; ni < 4; ++ni) {
      const int col = col0 + wn + ni * 16 + qi;
#pragma unroll
      for (int r = 0; r < 4; ++r) {
        const int row = row0 + wm + mi * 16 + g * 4 + r;
        if (row >= Mpb) continue;
        C[(size_t)b * strideC + (size_t)row * ldc + col] =
            (__bf16)(gval[mi][ni][r] * acc[mi][ni][r]);
      }
    }
  }
}

// ---------------- Old GEMM (f32 weights on the fly) — legacy fallback ----------------
__global__ __launch_bounds__(256, 2)
void gemm_kernel(const __bf16* __restrict__ A, const float* __restrict__ Bw,
                 void* __restrict__ C, const void* __restrict__ Extra,
                 int Mpb, int lda, int strideA,
                 int ldb, int headDim, int Kd,
                 int ldc, int strideC, int mbPerBatch,
                 int outMode, int ldct) {
  __shared__ __align__(16) __bf16 As[128 * 32];
  __shared__ __align__(16) __bf16 Bs[128 * 32];
  const int tid = threadIdx.x;
  const int lane = tid & 63;
  const int wid = tid >> 6;
  const int b = blockIdx.x / mbPerBatch;
  const int row0 = (blockIdx.x % mbPerBatch) * 128;
  const int col0 = blockIdx.y * 128;
  const __bf16* Ab = A + (size_t)b * strideA;
  const float* Bb = (headDim > 0)
      ? (Bw + (size_t)(col0 / headDim) * (size_t)Kd * headDim + (col0 % headDim))
      : (Bw + col0);
  const int wm = (wid >> 1) * 64, wn = (wid & 1) * 64;
  const int qi = lane & 15, g = lane >> 4;

  f32x4 acc[4][4];
#pragma unroll
  for (int i = 0; i < 4; ++i)
#pragma unroll
    for (int j = 0; j < 4; ++j) acc[i][j] = f32x4{0.f, 0.f, 0.f, 0.f};

  const int am = tid >> 2, ap = tid & 3;
  const int bn = tid >> 2, bc = tid & 3;

  for (int k0 = 0; k0 < Kd; k0 += 32) {
    __syncthreads();
#pragma unroll
    for (int s = 0; s < 2; ++s) {
      const int m = am + s * 64;
      int mr = row0 + m;
      if (mr >= Mpb) mr = Mpb - 1;
      const int lg = ap ^ ((m >> 1) & 3);
      bfx8 v = *(const bfx8*)(Ab + (size_t)mr * lda + k0 + lg * 8);
      *(bfx8*)(&As[m * 32 + ap * 8]) = v;
    }
#pragma unroll
    for (int s = 0; s < 2; ++s) {
      const int n = bn + s * 64;
      const float* bp = Bb + (size_t)(k0 + bc * 8) * ldb + n;
      bfx8 v;
#pragma unroll
      for (int i = 0; i < 8; ++i) v[i] = (__bf16)bp[(size_t)i * ldb];
      const int p = bc ^ ((n >> 1) & 3);
      *(bfx8*)(&Bs[n * 32 + p * 8]) = v;
    }
    __syncthreads();
    bfx8 af[4], bf[4];
#pragma unroll
    for (int mi = 0; mi < 4; ++mi) {
      const int m = wm + mi * 16 + qi;
      const int sl = g ^ ((m >> 1) & 3);
      af[mi] = *(const bfx8*)(&As[m * 32 + sl * 8]);
    }
#pragma unroll
    for (int ni = 0; ni < 4; ++ni) {
      const int n = wn + ni * 16 + qi;
      const int sl = g ^ ((n >> 1) & 3);
      bf[ni] = *(const bfx8*)(&Bs[n * 32 + sl * 8]);
    }
#pragma unroll
    for (int mi = 0; mi < 4; ++mi)
#pragma unroll
      for (int ni = 0; ni < 4; ++ni)
        acc[mi][ni] = MFMA16(af[mi], bf[ni], acc[mi][ni]);
  }

#pragma unroll
  for (int mi = 0; mi < 4; ++mi) {
#pragma unroll
    for (int ni = 0; ni < 4; ++ni) {
      const int col = col0 + wn + ni * 16 + qi;
#pragma unroll
      for (int r = 0; r < 4; ++r) {
        const int row = row0 + wm + mi * 16 + g * 4 + r;
        if (row >= Mpb) continue;
        const float v = acc[mi][ni][r];
        if (outMode == 0) {
          ((float*)C)[(size_t)b * strideC + (size_t)row * ldc + col] = v;
        } else if (outMode == 1) {
          ((__bf16*)C)[(size_t)b * strideC + (size_t)row * ldc + col] = (__bf16)v;
        } else if (outMode == 2) {
          const size_t ix = (size_t)b * strideC + (size_t)row * ldc + col;
          ((float*)C)[ix] = v + ((const float*)Extra)[ix];
        } else if (outMode == 3) {
          ((__bf16*)C)[(size_t)b * strideC + (size_t)col * ldct + row] = (__bf16)v;
        } else {
          const size_t ix = (size_t)b * strideC + (size_t)row * ldc + col;
          const float gt = (float)((const __bf16*)Extra)[ix];
          ((__bf16*)C)[ix] = (__bf16)(gelu_tanh_f(gt) * v);
        }
      }
    }
  }
}

// ---------------- Fused attention (q/k strides parameterized) ----------------
__global__ __launch_bounds__(256, 2)
void attn_kernel(const __bf16* __restrict__ qp, const __bf16* __restrict__ kp0,
                 const __bf16* __restrict__ vt, __bf16* __restrict__ ao,
                 int qstride, int kstride) {
  __shared__ __align__(16) __bf16 Ps[4][1024];
  __shared__ float denw[4][16];
  const int tid = threadIdx.x, lane = tid & 63, wid = tid >> 6;
  const int qt = blockIdx.x, hn = blockIdx.y, b = blockIdx.z;
  const int q0 = qt * 64;
  const int qi = lane & 15, g = lane >> 4;

  int qrow = q0 + wid * 16 + qi;
  if (qrow > 815) qrow = 815;
  const int cmq = (qrow >= 768) + (qrow >= 771);
  const __bf16* qrp = qp + (size_t)(b * 816 + qrow) * qstride + hn * 256 + g * 8;
  bfx8 qf[8];
#pragma unroll
  for (int kf = 0; kf < 8; ++kf) qf[kf] = *(const bfx8*)(qrp + kf * 32);

  f32x4 oacc[16];
#pragma unroll
  for (int i = 0; i < 16; ++i) oacc[i] = f32x4{0.f, 0.f, 0.f, 0.f};
  float den = 0.f;

  const int ntiles = (q0 + 63 < 768) ? 12 : 13;
  for (int t = 0; t < ntiles; ++t) {
    const int kv0 = t * 64;
#pragma unroll
    for (int mi = 0; mi < 4; ++mi) {
      f32x4 sac = f32x4{0.f, 0.f, 0.f, 0.f};
      int srow = kv0 + mi * 16 + qi;
      if (srow > 815) srow = 815;
      const __bf16* kp = kp0 + (size_t)(b * 816 + srow) * kstride + g * 8;
#pragma unroll
      for (int kf = 0; kf < 8; ++kf) {
        bfx8 a = *(const bfx8*)(kp + kf * 32);
        sac = MFMA16(a, qf[kf], sac);
      }
      float pv[4];
#pragma unroll
      for (int r = 0; r < 4; ++r) {
        const int s = kv0 + mi * 16 + g * 4 + r;
        const float l = sac[r];
        const float e2 = __expf(l * 0.04f);
        const float capped = 50.f * (e2 - 1.f) / (e2 + 1.f);
        const int cms = (s >= 768) + (s >= 771);
        const bool ok = (s < 816) && (cms <= cmq);
        const float p = ok ? __expf(capped) : 0.f;
        den += p;
        pv[r] = p;
      }
      const unsigned lo = pack_bf2(pv[0], pv[1]);
      const unsigned hi = pack_bf2(pv[2], pv[3]);
      const int slot = 2 * mi + (g >> 1);
      const int phys = slot ^ (qi & 7);
      char* pb = (char*)&Ps[wid][0] + qi * 128 + phys * 16 + (g & 1) * 8;
      *(unsigned*)(pb) = lo;
      *(unsigned*)(pb + 4) = hi;
    }
    asm volatile("s_waitcnt lgkmcnt(0)" ::: "memory");
    bfx8 pa[2];
#pragma unroll
    for (int k2 = 0; k2 < 2; ++k2) {
      const int sl = (k2 * 4 + g) ^ (qi & 7);
      pa[k2] = *(const bfx8*)((const char*)&Ps[wid][0] + qi * 128 + sl * 16);
    }
#pragma unroll
    for (int hf = 0; hf < 16; ++hf) {
      const int h = hf * 16 + qi;
#pragma unroll
      for (int k2 = 0; k2 < 2; ++k2) {
        int s0 = kv0 + k2 * 32 + g * 8;
        if (s0 > 808) s0 = 808;
        bfx8 vb = *(const bfx8*)(vt + ((size_t)(b * 256 + h)) * 816 + s0);
        oacc[hf] = MFMA16(pa[k2], vb, oacc[hf]);
      }
    }
    asm volatile("s_waitcnt lgkmcnt(0)" ::: "memory");
  }

  den += __shfl_xor(den, 16, 64);
  den += __shfl_xor(den, 32, 64);
  if (lane < 16) denw[wid][qi] = den;
  asm volatile("s_waitcnt lgkmcnt(0)" ::: "memory");
#pragma unroll
  for (int r = 0; r < 4; ++r) {
    const int qg = q0 + wid * 16 + g * 4 + r;
    if (qg >= 816) continue;
    const float di = 1.f / denw[wid][g * 4 + r];
#pragma unroll
    for (int hf = 0; hf < 16; ++hf) {
      ao[((size_t)(b * 816 + qg)) * 2048 + hn * 256 + hf * 16 + qi] =
          (__bf16)(oacc[hf][r] * di);
    }
  }
}

// ---------------- Host orchestration ----------------
extern "C" void kernel_launch(void* const* d_in, const int* in_sizes, int n_in,
                              void* d_out, int out_size, void* d_ws, size_t ws_size,
                              hipStream_t stream) {
  (void)in_sizes; (void)n_in; (void)out_size;
  const float* x      = (const float*)d_in[0];
  const int*   pos    = (const int*)d_in[1];
  const float* s_attn = (const float*)d_in[4];
  const float* s_ffw  = (const float*)d_in[5];
  const float* gq     = (const float*)d_in[6];
  const float* gkv    = (const float*)d_in[7];
  const float* go     = (const float*)d_in[8];
  const float* aq     = (const float*)d_in[9];
  const float* akv    = (const float*)d_in[10];
  const float* aow    = (const float*)d_in[11];
  const float* gg     = (const float*)d_in[12];
  const float* gl     = (const float*)d_in[13];
  const float* ag     = (const float*)d_in[14];
  const float* al     = (const float*)d_in[15];
  float* outp = (float*)d_out;
  char* ws = (char*)d_ws;
  dim3 blk(256);

  const size_t NEED_BATCH = 577437696u;
  const size_t NEED_FAST  = 423297024u;

  if (ws_size >= NEED_FAST) {
    const bool batched = (ws_size >= NEED_BATCH);
    // weights (tile-panel bf16); QKV fused: [Q 16 panels][K 2][V 2] contiguous
    __bf16* wQKVg = (__bf16*)(ws + 0);          // 20 panels x 64ks x 4096
    __bf16* wQKVa = (__bf16*)(ws + 10485760);
    __bf16* goT = (__bf16*)(ws + 20971520);
    __bf16* aoT = (__bf16*)(ws + 29360128);
    __bf16* ggT = (__bf16*)(ws + 37748736);     // [2] x [16384 x 2048]
    __bf16* glT = (__bf16*)(ws + 171966464);    // [2048 x 16384]
    __bf16* agT = (__bf16*)(ws + 239075328);    // [2] x [4096 x 2048]
    __bf16* alT = (__bf16*)(ws + 272629760);    // [2048 x 4096]
    // activations
    __bf16* xn   = (__bf16*)(ws + 289406976);   // [3264][2048]
    __bf16* qkb  = (__bf16*)(ws + 302776320);   // [3264][2304]  Q cols 0-2047, K 2048-2303
    __bf16* vt   = (__bf16*)(ws + 317816832);   // [4][256][816]
    __bf16* aob  = (__bf16*)(ws + 319488000);   // [3264][2048]
    float*  ob   = (float*)(ws + 332857344);    // [3264][2048] f32
    __bf16* hb   = (__bf16*)(ws + 359596032);   // [3264][2048]
    __bf16* gate  = (__bf16*)(ws + 372965376);  // per-batch scratch
    __bf16* act   = (__bf16*)(ws + 398131200);  // per-batch [768][16384]
    __bf16* act4  = (__bf16*)(ws + 473628672);  // batched [4][768][16384]
    __bf16* actA4 = (__bf16*)(ws + 575864832);  // batched [4][48][4096]

    // weight conversion (f32 [K][N] -> bf16 panel)
    convw_kernel<<<dim3(32, 32), blk, 0, stream>>>(gq, wQKVg, 2048, 256);
    convw_kernel<<<dim3(4, 32), blk, 0, stream>>>(gkv, wQKVg + 16 * 64 * 4096, 2048, 256);
    convw_kernel<<<dim3(4, 32), blk, 0, stream>>>(gkv + 2048 * 256, wQKVg + 18 * 64 * 4096, 2048, 256);
    convw_kernel<<<dim3(32, 32), blk, 0, stream>>>(aq, wQKVa, 2048, 256);
    convw_kernel<<<dim3(4, 32), blk, 0, stream>>>(akv, wQKVa + 16 * 64 * 4096, 2048, 256);
    convw_kernel<<<dim3(4, 32), blk, 0, stream>>>(akv + 2048 * 256, wQKVa + 18 * 64 * 4096, 2048, 256);
    convw_kernel<<<dim3(32, 32), blk, 0, stream>>>(go, goT, 2048, 2048);
    convw_kernel<<<dim3(32, 32), blk, 0, stream>>>(aow, aoT, 2048, 2048);
    convw_kernel<<<dim3(256, 32), blk, 0, stream>>>(gg, ggT, 2048, 16384);
    convw_kernel<<<dim3(256, 32), blk, 0, stream>>>(gg + (size_t)2048 * 16384, ggT + (size_t)16384 * 2048, 2048, 16384);
    convw_kernel<<<dim3(32, 256), blk, 0, stream>>>(gl, glT, 16384, 2048);
    convw_kernel<<<dim3(64, 32), blk, 0, stream>>>(ag, agT, 2048, 4096);
    convw_kernel<<<dim3(64, 32), blk, 0, stream>>>(ag + (size_t)2048 * 4096, agT + (size_t)4096 * 2048, 2048, 4096);
    convw_kernel<<<dim3(32, 64), blk, 0, stream>>>(al, alT, 4096, 2048);

    // 1. pre-attention rmsnorm
    rmsnorm_kernel<<<3264, blk, 0, stream>>>(x, nullptr, s_attn, xn);

    // 2. fused QKV projection (Q,K -> qkb; V -> vt transposed)
    gemm256<<<dim3(12, 20), dim3(512), 0, stream>>>(xn, wQKVg, qkb, vt, nullptr,
        768, 2048, 816 * 2048, 2048, 2304, 816 * 2304, 3, 5);
    gemm_bt2<<<dim3(4, 20), blk, 0, stream>>>(xn + 768 * 2048, wQKVa, qkb + 768 * 2304, vt + 768, nullptr,
        48, 2048, 816 * 2048, 2048, 2304, 816 * 2304, 1, 5, 0);

    // 3. RoPE in place (q scaled by H^-0.5)
    rope_bf_kernel<<<3264, blk, 0, stream>>>(qkb, pos, 8, 2304, 0.0625f);
    rope_bf_kernel<<<3264, blk, 0, stream>>>(qkb + 2048, pos, 1, 2304, 1.0f);

    // 4. attention
    attn_kernel<<<dim3(13, 8, 4), blk, 0, stream>>>(qkb, qkb + 2048, vt, aob, 2304, 2304);

    // 5. output projection
    gemm256<<<dim3(12, 16), dim3(512), 0, stream>>>(aob, goT, ob, nullptr, nullptr,
        768, 2048, 816 * 2048, 2048, 2048, 816 * 2048, 3, 0);
    gemm_bt2<<<dim3(4, 16), blk, 0, stream>>>(aob + 768 * 2048, aoT, ob + 768 * 2048, nullptr, nullptr,
        48, 2048, 816 * 2048, 2048, 2048, 816 * 2048, 1, 0, 0);

    // 6. pre-FFW rmsnorm of (o + x)
    rmsnorm_kernel<<<3264, blk, 0, stream>>>(ob, x, s_ffw, hb);

    // 7. FFN (2-phase fused gate+act dual GEMM, then 2-phase down-proj with residual)
    if (batched) {
      ffn_dual256<<<dim3(12, 128), dim3(512), 0, stream>>>(hb, ggT, ggT + (size_t)16384 * 2048, act4,
          768, 2048, 816 * 2048, 2048, 16384, 768 * 16384, 3);
      gemm256<<<dim3(12, 16), dim3(512), 0, stream>>>(act4, glT, outp, nullptr, x,
          768, 16384, 768 * 16384, 16384, 2048, 816 * 2048, 3, 2);
      ffn_dual<<<dim3(4, 32), blk, 0, stream>>>(hb + 768 * 2048, agT, agT + (size_t)4096 * 2048, actA4,
          48, 2048, 816 * 2048, 2048, 4096, 48 * 4096, 1);
      gemm_bt2<<<dim3(4, 16), blk, 0, stream>>>(actA4, alT, outp + 768 * 2048, nullptr, x + 768 * 2048,
          48, 4096, 48 * 4096, 4096, 2048, 816 * 2048, 1, 2, 0);
    } else {
      for (int bb = 0; bb < 4; ++bb) {
        const __bf16* hg = hb + (size_t)bb * 816 * 2048;
        float* og = outp + (size_t)bb * 816 * 2048;
        const float* xg = x + (size_t)bb * 816 * 2048;
        ffn_dual<<<dim3(6, 128), blk, 0, stream>>>(hg, ggT, ggT + (size_t)16384 * 2048, act,
            768, 2048, 0, 2048, 16384, 0, 6);
        gemm_bt2<<<dim3(6, 16), blk, 0, stream>>>(act, glT, og, nullptr, xg,
            768, 16384, 0, 16384, 2048, 0, 6, 2, 0);
        const __bf16* ha = hg + 768 * 2048;
        ffn_dual<<<dim3(1, 32), blk, 0, stream>>>(ha, agT, agT + (size_t)4096 * 2048, gate,
            48, 2048, 0, 2048, 4096, 0, 1);
        gemm_bt2<<<dim3(1, 16), blk, 0, stream>>>(gate, alT, og + 768 * 2048, nullptr, xg + 768 * 2048,
            48, 4096, 0, 4096, 2048, 0, 1, 2, 0);
      }
    }
    return;
  }

  // ---- legacy fallback path (round-0, on-the-fly f32 weights) ----
  if (ws_size < 164000000u) return;
  __bf16* xn   = (__bf16*)(ws + 0);
  float*  qf   = (float*)(ws + 13369344);
  __bf16* qbb  = (__bf16*)(ws + 40108032);
  float*  kf   = (float*)(ws + 53477376);
  __bf16* kbb  = (__bf16*)(ws + 56819712);
  __bf16* vt   = (__bf16*)(ws + 58490880);
  __bf16* aob  = (__bf16*)(ws + 60162048);
  float*  ob   = (float*)(ws + 73531392);
  __bf16* hb   = (__bf16*)(ws + 100270080);
  __bf16* gate = (__bf16*)(ws + 113639424);
  __bf16* act  = (__bf16*)(ws + 138805248);

  rmsnorm_kernel<<<3264, blk, 0, stream>>>(x, nullptr, s_attn, xn);
  gemm_kernel<<<dim3(24, 16), blk, 0, stream>>>(xn, gq, qf, nullptr,
      768, 2048, 816 * 2048, 256, 256, 2048, 2048, 816 * 2048, 6, 0, 0);
  gemm_kernel<<<dim3(4, 16), blk, 0, stream>>>(xn + 768 * 2048, aq, qf + 768 * 2048, nullptr,
      48, 2048, 816 * 2048, 256, 256, 2048, 2048, 816 * 2048, 1, 0, 0);
  gemm_kernel<<<dim3(24, 2), blk, 0, stream>>>(xn, gkv, kf, nullptr,
      768, 2048, 816 * 2048, 256, 256, 2048, 256, 816 * 256, 6, 0, 0);
  gemm_kernel<<<dim3(4, 2), blk, 0, stream>>>(xn + 768 * 2048, akv, kf + 768 * 256, nullptr,
      48, 2048, 816 * 2048, 256, 256, 2048, 256, 816 * 256, 1, 0, 0);
  gemm_kernel<<<dim3(24, 2), blk, 0, stream>>>(xn, gkv + 2048 * 256, vt, nullptr,
      768, 2048, 816 * 2048, 256, 256, 2048, 0, 256 * 816, 6, 3, 816);
  gemm_kernel<<<dim3(4, 2), blk, 0, stream>>>(xn + 768 * 2048, akv + 2048 * 256, vt + 768, nullptr,
      48, 2048, 816 * 2048, 256, 256, 2048, 0, 256 * 816, 1, 3, 816);
  rope_kernel<<<3264, blk, 0, stream>>>(qf, pos, qbb, 8, 0.0625f);
  rope_kernel<<<3264, blk, 0, stream>>>(kf, pos, kbb, 1, 1.0f);
  attn_kernel<<<dim3(13, 8, 4), blk, 0, stream>>>(qbb, kbb, vt, aob, 2048, 256);
  gemm_kernel<<<dim3(24, 16), blk, 0, stream>>>(aob, go, ob, nullptr,
      768, 2048, 816 * 2048, 2048, 0, 2048, 2048, 816 * 2048, 6, 0, 0);
  gemm_kernel<<<dim3(4, 16), blk, 0, stream>>>(aob + 768 * 2048, aow, ob + 768 * 2048, nullptr,
      48, 2048, 816 * 2048, 2048, 0, 2048, 2048, 816 * 2048, 1, 0, 0);
  rmsnorm_kernel<<<3264, blk, 0, stream>>>(ob, x, s_ffw, hb);
  for (int bb = 0; bb < 4; ++bb) {
    const __bf16* hg = hb + (size_t)bb * 816 * 2048;
    float* og = outp + (size_t)bb * 816 * 2048;
    const float* xg = x + (size_t)bb * 816 * 2048;
    gemm_kernel<<<dim3(6, 128), blk, 0, stream>>>(hg, gg, gate, nullptr,
        768, 2048, 0, 16384, 0, 2048, 16384, 0, 6, 1, 0);
    gemm_kernel<<<dim3(6, 128), blk, 0, stream>>>(hg, gg + 2048 * 16384, act, gate,
        768, 2048, 0, 16384, 0, 2048, 16384, 0, 6, 4, 0);
    gemm_kernel<<<dim3(6, 16), blk, 0, stream>>>(act, gl, og, xg,
        768, 16384, 0, 2048, 0, 16384, 2048, 0, 6, 2, 0);
    const __bf16* ha = hg + 768 * 2048;
    gemm_kernel<<<dim3(1, 32), blk, 0, stream>>>(ha, ag, gate, nullptr,
        48, 2048, 0, 4096, 0, 2048, 4096, 0, 1, 1, 0);
    gemm_kernel<<<dim3(1, 32), blk, 0, stream>>>(ha, ag + 2048 * 4096, act, gate,
        48, 2048, 0, 4096, 0, 2048, 4096, 0, 1, 4, 0);
    gemm_kernel<<<dim3(1, 16), blk, 0, stream>>>(act, al, og + 768 * 2048, xg + 768 * 2048,
        48, 4096, 0, 2048, 0, 4096, 2048, 0, 1, 2, 0);
  }
}

// Round 16
// 1353.182 us; speedup vs baseline: 1.1481x; 1.0417x over previous
//
#include <hip/hip_runtime.h>
#include <hip/hip_bf16.h>

typedef __bf16 bfx8 __attribute__((ext_vector_type(8)));
typedef __bf16 bfx4 __attribute__((ext_vector_type(4)));
typedef float f32x4 __attribute__((ext_vector_type(4)));

#define MFMA16(a, b, c) __builtin_amdgcn_mfma_f32_16x16x32_bf16((a), (b), (c), 0, 0, 0)

__device__ __forceinline__ void gl_lds16(const __bf16* g, __bf16* l) {
  __builtin_amdgcn_global_load_lds(
      (const __attribute__((address_space(1))) unsigned int*)(const void*)g,
      (__attribute__((address_space(3))) unsigned int*)(void*)l, 16, 0, 0);
}

__device__ __forceinline__ unsigned pack_bf2(float a, float b) {
  unsigned short ua = __builtin_bit_cast(unsigned short, (__bf16)a);
  unsigned short ub = __builtin_bit_cast(unsigned short, (__bf16)b);
  return (unsigned)ua | ((unsigned)ub << 16);
}

__device__ __forceinline__ float gelu_tanh_f(float x) {
  float u = 0.7978845608028654f * (x + 0.044715f * x * x * x);
  float t;
  if (u > 10.f) t = 1.f;
  else if (u < -10.f) t = -1.f;
  else { float e = __expf(2.f * u); t = (e - 1.f) / (e + 1.f); }
  return 0.5f * x * (1.f + t);
}

// ---------------- RMSNorm (optionally fused residual add) ----------------
__global__ __launch_bounds__(256)
void rmsnorm_kernel(const float* __restrict__ X, const float* __restrict__ X2,
                    const float* __restrict__ scale, __bf16* __restrict__ out) {
  __shared__ float wsum[4];
  const int row = blockIdx.x, tid = threadIdx.x;
  const size_t base = (size_t)row * 2048;
  f32x4 v[2];
  float ss = 0.f;
#pragma unroll
  for (int i = 0; i < 2; ++i) {
    const int idx = tid * 4 + i * 1024;
    v[i] = *(const f32x4*)(X + base + idx);
    if (X2) { f32x4 u = *(const f32x4*)(X2 + base + idx); v[i] = v[i] + u; }
#pragma unroll
    for (int j = 0; j < 4; ++j) ss += v[i][j] * v[i][j];
  }
#pragma unroll
  for (int o = 32; o > 0; o >>= 1) ss += __shfl_xor(ss, o, 64);
  if ((tid & 63) == 0) wsum[tid >> 6] = ss;
  __syncthreads();
  const float tot = wsum[0] + wsum[1] + wsum[2] + wsum[3];
  const float rs = rsqrtf(tot * (1.f / 2048.f) + 1e-6f);
#pragma unroll
  for (int i = 0; i < 2; ++i) {
    const int idx = tid * 4 + i * 1024;
    f32x4 sc = *(const f32x4*)(scale + idx);
    bfx4 ov;
#pragma unroll
    for (int j = 0; j < 4; ++j) ov[j] = (__bf16)(v[i][j] * rs * (1.f + sc[j]));
    *(bfx4*)(out + base + idx) = ov;
  }
}

// ---------------- RoPE in-place on bf16, per-head scale (q heads scaled, K head not) --
__global__ __launch_bounds__(256)
void rope_bf_kernel(__bf16* __restrict__ buf, const int* __restrict__ pos,
                    int nheads, int rstride, int qheads, float qscale) {
  const int row = blockIdx.x;
  const float p = (float)pos[row];
  const int total = nheads * 128;
  const size_t rbase = (size_t)row * (size_t)rstride;
  for (int idx = threadIdx.x; idx < total; idx += 256) {
    const int n = idx >> 7, i = idx & 127;
    const float outscale = (n < qheads) ? qscale : 1.0f;
    const float ts = __expf(-(float)i * 0.071955784f);  // 10000^(-i/128)
    float sn, cs;
    __sincosf(p * ts, &sn, &cs);
    __bf16* bp = buf + rbase + n * 256 + i;
    const float x1 = (float)bp[0], x2 = (float)bp[128];
    bp[0]   = (__bf16)((x1 * cs - x2 * sn) * outscale);
    bp[128] = (__bf16)((x2 * cs + x1 * sn) * outscale);
  }
}

// ---------------- RoPE f32 -> bf16 (fallback path) ----------------
__global__ __launch_bounds__(256)
void rope_kernel(const float* __restrict__ in, const int* __restrict__ pos,
                 __bf16* __restrict__ outp, int nheads, float outscale) {
  const int row = blockIdx.x;
  const float p = (float)pos[row];
  const int total = nheads * 128;
  const size_t rbase = (size_t)row * (size_t)(nheads * 256);
  for (int idx = threadIdx.x; idx < total; idx += 256) {
    const int n = idx >> 7, i = idx & 127;
    const float ts = __expf(-(float)i * 0.071955784f);
    float sn, cs;
    __sincosf(p * ts, &sn, &cs);
    const float* bp = in + rbase + n * 256 + i;
    const float x1 = bp[0], x2 = bp[128];
    __bf16* ob = outp + rbase + n * 256 + i;
    ob[0]   = (__bf16)((x1 * cs - x2 * sn) * outscale);
    ob[128] = (__bf16)((x2 * cs + x1 * sn) * outscale);
  }
}

// ---------------- Weight convert: f32 W[k][c] -> bf16 tile-panel layout ----------------
// Panel: (cp*(K/32)+ks)*4096 holds the 128x32 tile pre-swizzled in LDS-linear order:
// element (m=col&127, k): lg=(k%32)/8, p=lg^((m>>1)&3), offset = m*32 + p*8 + (k&7).
__global__ __launch_bounds__(256)
void convw_kernel(const float* __restrict__ in, __bf16* __restrict__ out,
                  int K, int headDim) {
  __shared__ __bf16 tile[64][65];
  const int tc0 = blockIdx.x * 64;
  const int tk0 = blockIdx.y * 64;
  const int tid = threadIdx.x;
  const int cchunk = tid & 15, krow = tid >> 4;
  const int c = tc0 + cchunk * 4;
  const float* colbase = in + (size_t)(c / headDim) * (size_t)K * headDim + (c % headDim);
#pragma unroll
  for (int i = 0; i < 4; ++i) {
    const int k = tk0 + krow + i * 16;
    f32x4 v = *(const f32x4*)(colbase + (size_t)k * headDim);
#pragma unroll
    for (int j = 0; j < 4; ++j) tile[cchunk * 4 + j][krow + i * 16] = (__bf16)v[j];
  }
  __syncthreads();
  const int nks = K >> 5;
#pragma unroll
  for (int s = 0; s < 2; ++s) {
    const int ch = tid + s * 256;
    const int wc = ch >> 3, wk8 = (ch & 7) * 8;
    bfx8 v;
#pragma unroll
    for (int j = 0; j < 8; ++j) v[j] = tile[wc][wk8 + j];
    const int col = tc0 + wc;
    const int kchunk = (tk0 + wk8) >> 3;
    const int cp = col >> 7, m = col & 127;
    const int ks = kchunk >> 2, lg = kchunk & 3;
    const int p = lg ^ ((m >> 1) & 3);
    *(bfx8*)(out + ((size_t)(cp * nks + ks)) * 4096 + m * 32 + p * 8) = v;
  }
}

// ---------------- 2-phase fused GEGLU dual-GEMM (256x128 tile, 512 threads) ----------
// C = gelu(A·Wg) * (A·Wa), bf16 out. XCD-chunked block swizzle.
__global__ __launch_bounds__(512, 2)
void ffn_dual256(const __bf16* __restrict__ A, const __bf16* __restrict__ Wg,
                 const __bf16* __restrict__ Wa, __bf16* __restrict__ C,
                 int Mpb, int lda, int strideA, int Kd,
                 int ldc, int strideC, int mbPerBatch) {
  __shared__ __align__(16) __bf16 As[2 * 2 * 8192];  // [buf][half][128x64]
  __shared__ __align__(16) __bf16 Bs[2 * 2 * 8192];  // [buf][pan][128x64]
  const int tid = threadIdx.x;
  const int lane = tid & 63;
  const int wid = tid >> 6;
  const int wr = wid >> 2;
  const int wc = wid & 3;
  const int qi = lane & 15, g = lane >> 4;
  // XCD-chunked swizzle (nwg divisible by 8)
  int bid = blockIdx.y * gridDim.x + blockIdx.x;
  const int nwg = gridDim.x * gridDim.y;
  if ((nwg & 7) == 0) bid = (bid & 7) * (nwg >> 3) + (bid >> 3);
  const int bx = bid % gridDim.x, by = bid / gridDim.x;
  const int b = bx / mbPerBatch;
  const int row0 = (bx % mbPerBatch) * 256;
  const int col0 = by * 128;
  const __bf16* Ab = A + (size_t)b * strideA;
  const size_t nks = (size_t)(Kd >> 5);
  const __bf16* Bgp = Wg + ((size_t)(col0 >> 7)) * nks * 4096;
  const __bf16* Bap = Wa + ((size_t)(col0 >> 7)) * nks * 4096;
  const int NT = Kd >> 6;

  const int sm = tid >> 2, sp = tid & 3;
  const int slg = sp ^ ((sm >> 1) & 3);
  int r0 = row0 + sm;       if (r0 >= Mpb) r0 = Mpb - 1;
  int r1 = row0 + 128 + sm; if (r1 >= Mpb) r1 = Mpb - 1;
  const __bf16* asrc0 = Ab + (size_t)r0 * lda + slg * 8;
  const __bf16* asrc1 = Ab + (size_t)r1 * lda + slg * 8;

  // half order per K-tile t: 0=A0, 1=Bg, 2=A1, 3=Ba
  auto stage_half = [&](int gh) {
    if (gh >= 4 * NT) return;
    const int t = gh >> 2, which = gh & 3;
    const int bufi = t & 1;
    if ((which & 1) == 0) {
      const int h = which >> 1;
      __bf16* dst = &As[bufi * 16384 + h * 8192];
      const __bf16* src = (h ? asrc1 : asrc0) + t * 64;
      gl_lds16(src, dst + tid * 8);
      gl_lds16(src + 32, dst + 4096 + tid * 8);
    } else {
      const int pan = which >> 1;
      __bf16* dst = &Bs[bufi * 16384 + pan * 8192];
      const __bf16* src = (pan ? Bap : Bgp) + (size_t)(t * 2) * 4096 + tid * 8;
      gl_lds16(src, dst + tid * 8);
      gl_lds16(src + 4096, dst + 4096 + tid * 8);
    }
  };

  f32x4 acc[2][2][4][2];
#pragma unroll
  for (int a0 = 0; a0 < 2; ++a0)
#pragma unroll
    for (int a1 = 0; a1 < 2; ++a1)
#pragma unroll
      for (int a2 = 0; a2 < 4; ++a2)
#pragma unroll
        for (int a3 = 0; a3 < 2; ++a3) acc[a0][a1][a2][a3] = f32x4{0.f, 0.f, 0.f, 0.f};

  for (int gh = 0; gh < 6; ++gh) stage_half(gh);
  asm volatile("s_waitcnt vmcnt(4)" ::: "memory");
  __builtin_amdgcn_s_barrier();
  asm volatile("" ::: "memory");

  for (int t = 0; t < NT; ++t) {
    const int cb = (t & 1) * 16384;
    bfx8 af[4][2], bf[2][2][2];

    // ---- PHASE 0: A-half 0, both panels ----
#pragma unroll
    for (int mi = 0; mi < 4; ++mi) {
      const int m = wr * 64 + mi * 16 + qi;
      const int sl = g ^ ((m >> 1) & 3);
      const int ba = cb + m * 32 + sl * 8;
      af[mi][0] = *(const bfx8*)(&As[ba]);
      af[mi][1] = *(const bfx8*)(&As[ba + 4096]);
    }
#pragma unroll
    for (int pan = 0; pan < 2; ++pan)
#pragma unroll
      for (int ni = 0; ni < 2; ++ni) {
        const int m = wc * 32 + ni * 16 + qi;
        const int sl = g ^ ((m >> 1) & 3);
        const int bb = cb + pan * 8192 + m * 32 + sl * 8;
        bf[pan][ni][0] = *(const bfx8*)(&Bs[bb]);
        bf[pan][ni][1] = *(const bfx8*)(&Bs[bb + 4096]);
      }
    stage_half(4 * t + 6);
    stage_half(4 * t + 7);
    __builtin_amdgcn_s_barrier();
    asm volatile("s_waitcnt lgkmcnt(0)" ::: "memory");
    __builtin_amdgcn_sched_barrier(0);
    __builtin_amdgcn_s_setprio(1);
#pragma unroll
    for (int pan = 0; pan < 2; ++pan)
#pragma unroll
      for (int mi = 0; mi < 4; ++mi)
#pragma unroll
        for (int ni = 0; ni < 2; ++ni) {
          acc[0][pan][mi][ni] = MFMA16(af[mi][0], bf[pan][ni][0], acc[0][pan][mi][ni]);
          acc[0][pan][mi][ni] = MFMA16(af[mi][1], bf[pan][ni][1], acc[0][pan][mi][ni]);
        }
    __builtin_amdgcn_s_setprio(0);
    __builtin_amdgcn_s_barrier();
    asm volatile("" ::: "memory");

    // ---- PHASE 1: A-half 1, reuse bf ----
#pragma unroll
    for (int mi = 0; mi < 4; ++mi) {
      const int m = wr * 64 + mi * 16 + qi;
      const int sl = g ^ ((m >> 1) & 3);
      const int ba = cb + 8192 + m * 32 + sl * 8;
      af[mi][0] = *(const bfx8*)(&As[ba]);
      af[mi][1] = *(const bfx8*)(&As[ba + 4096]);
    }
    stage_half(4 * t + 8);
    stage_half(4 * t + 9);
    if (t + 2 < NT) asm volatile("s_waitcnt vmcnt(4)" ::: "memory");
    else            asm volatile("s_waitcnt vmcnt(0)" ::: "memory");
    __builtin_amdgcn_s_barrier();
    asm volatile("s_waitcnt lgkmcnt(0)" ::: "memory");
    __builtin_amdgcn_sched_barrier(0);
    __builtin_amdgcn_s_setprio(1);
#pragma unroll
    for (int pan = 0; pan < 2; ++pan)
#pragma unroll
      for (int mi = 0; mi < 4; ++mi)
#pragma unroll
        for (int ni = 0; ni < 2; ++ni) {
          acc[1][pan][mi][ni] = MFMA16(af[mi][0], bf[pan][ni][0], acc[1][pan][mi][ni]);
          acc[1][pan][mi][ni] = MFMA16(af[mi][1], bf[pan][ni][1], acc[1][pan][mi][ni]);
        }
    __builtin_amdgcn_s_setprio(0);
    __builtin_amdgcn_s_barrier();
    asm volatile("" ::: "memory");
  }

#pragma unroll
  for (int mh = 0; mh < 2; ++mh)
#pragma unroll
    for (int mi = 0; mi < 4; ++mi)
#pragma unroll
      for (int ni = 0; ni < 2; ++ni) {
        const int col = col0 + wc * 32 + ni * 16 + qi;
#pragma unroll
        for (int r = 0; r < 4; ++r) {
          const int row = row0 + mh * 128 + wr * 64 + mi * 16 + g * 4 + r;
          if (row >= Mpb) continue;
          C[(size_t)b * strideC + (size_t)row * ldc + col] =
              (__bf16)(gelu_tanh_f(acc[mh][0][mi][ni][r]) * acc[mh][1][mi][ni][r]);
        }
      }
}

// ---------------- 2-phase single GEMM (256x128 tile, 512 threads) ----------------
// C[b,row,col] = sum_k A[b,row,k]*W[k,col]. outMode: 0 f32, 2 f32+Extra residual,
// 5 QKV scatter (col<2304 bf16; col>=2304 V transposed into C2).
// If BtA != nullptr, row-blocks with row0==768 (action segment) use BtA weights.
__global__ __launch_bounds__(512, 2)
void gemm256(const __bf16* __restrict__ A, const __bf16* __restrict__ Bt,
             const __bf16* __restrict__ BtA,
             void* __restrict__ C, void* __restrict__ C2, const void* __restrict__ Extra,
             int Mpb, int lda, int strideA, int Kd,
             int ldc, int strideC, int mbPerBatch, int outMode) {
  __shared__ __align__(16) __bf16 As[2 * 2 * 8192];  // [buf][half][128x64]
  __shared__ __align__(16) __bf16 Bs[2 * 8192];      // [buf][128x64]
  const int tid = threadIdx.x;
  const int lane = tid & 63;
  const int wid = tid >> 6;
  const int wr = wid >> 2;
  const int wc = wid & 3;
  const int qi = lane & 15, g = lane >> 4;
  int bid = blockIdx.y * gridDim.x + blockIdx.x;
  const int nwg = gridDim.x * gridDim.y;
  if ((nwg & 7) == 0) bid = (bid & 7) * (nwg >> 3) + (bid >> 3);
  const int bx = bid % gridDim.x, by = bid / gridDim.x;
  const int b = bx / mbPerBatch;
  const int row0 = (bx % mbPerBatch) * 256;
  const int col0 = by * 128;
  const __bf16* Ab = A + (size_t)b * strideA;
  const size_t nks = (size_t)(Kd >> 5);
  const __bf16* Wsel = (BtA != nullptr && row0 == 768) ? BtA : Bt;
  const __bf16* Bp = Wsel + ((size_t)(col0 >> 7)) * nks * 4096;
  const int NT = Kd >> 6;

  const int sm = tid >> 2, sp = tid & 3;
  const int slg = sp ^ ((sm >> 1) & 3);
  int r0 = row0 + sm;       if (r0 >= Mpb) r0 = Mpb - 1;
  int r1 = row0 + 128 + sm; if (r1 >= Mpb) r1 = Mpb - 1;
  const __bf16* asrc0 = Ab + (size_t)r0 * lda + slg * 8;
  const __bf16* asrc1 = Ab + (size_t)r1 * lda + slg * 8;

  // half order per K-tile t: 0=A0, 1=B, 2=A1
  auto stage_half = [&](int gh) {
    if (gh >= 3 * NT) return;
    const int t = gh / 3, which = gh - 3 * t;
    const int bufi = t & 1;
    if (which == 1) {
      __bf16* dst = &Bs[bufi * 8192];
      const __bf16* src = Bp + (size_t)(t * 2) * 4096 + tid * 8;
      gl_lds16(src, dst + tid * 8);
      gl_lds16(src + 4096, dst + 4096 + tid * 8);
    } else {
      const int h = which >> 1;  // 0 -> A0, 2 -> A1
      __bf16* dst = &As[bufi * 16384 + h * 8192];
      const __bf16* src = (h ? asrc1 : asrc0) + t * 64;
      gl_lds16(src, dst + tid * 8);
      gl_lds16(src + 32, dst + 4096 + tid * 8);
    }
  };

  f32x4 acc[2][4][2];  // [mh][mi][ni]
#pragma unroll
  for (int a0 = 0; a0 < 2; ++a0)
#pragma unroll
    for (int a2 = 0; a2 < 4; ++a2)
#pragma unroll
      for (int a3 = 0; a3 < 2; ++a3) acc[a0][a2][a3] = f32x4{0.f, 0.f, 0.f, 0.f};

  // prologue: tile0 full + A0,B of tile1 (halves 0..4 = 10 loads); wait tile0 (6 loads)
  for (int gh = 0; gh < 5; ++gh) stage_half(gh);
  asm volatile("s_waitcnt vmcnt(4)" ::: "memory");
  __builtin_amdgcn_s_barrier();
  asm volatile("" ::: "memory");

  for (int t = 0; t < NT; ++t) {
    const int cb = (t & 1) * 16384;
    const int cbB = (t & 1) * 8192;
    bfx8 af[4][2], bf[2][2];

    // ---- PHASE 0: A-half 0 + B (B kept for phase 1) ----
#pragma unroll
    for (int mi = 0; mi < 4; ++mi) {
      const int m = wr * 64 + mi * 16 + qi;
      const int sl = g ^ ((m >> 1) & 3);
      const int ba = cb + m * 32 + sl * 8;
      af[mi][0] = *(const bfx8*)(&As[ba]);
      af[mi][1] = *(const bfx8*)(&As[ba + 4096]);
    }
#pragma unroll
    for (int ni = 0; ni < 2; ++ni) {
      const int m = wc * 32 + ni * 16 + qi;
      const int sl = g ^ ((m >> 1) & 3);
      const int bb = cbB + m * 32 + sl * 8;
      bf[ni][0] = *(const bfx8*)(&Bs[bb]);
      bf[ni][1] = *(const bfx8*)(&Bs[bb + 4096]);
    }
    stage_half(3 * t + 5);  // A1 of tile t+1
    __builtin_amdgcn_s_barrier();
    asm volatile("s_waitcnt lgkmcnt(0)" ::: "memory");
    __builtin_amdgcn_sched_barrier(0);
    __builtin_amdgcn_s_setprio(1);
#pragma unroll
    for (int mi = 0; mi < 4; ++mi)
#pragma unroll
      for (int ni = 0; ni < 2; ++ni) {
        acc[0][mi][ni] = MFMA16(af[mi][0], bf[ni][0], acc[0][mi][ni]);
        acc[0][mi][ni] = MFMA16(af[mi][1], bf[ni][1], acc[0][mi][ni]);
      }
    __builtin_amdgcn_s_setprio(0);
    __builtin_amdgcn_s_barrier();
    asm volatile("" ::: "memory");

    // ---- PHASE 1: A-half 1, reuse bf ----
#pragma unroll
    for (int mi = 0; mi < 4; ++mi) {
      const int m = wr * 64 + mi * 16 + qi;
      const int sl = g ^ ((m >> 1) & 3);
      const int ba = cb + 8192 + m * 32 + sl * 8;
      af[mi][0] = *(const bfx8*)(&As[ba]);
      af[mi][1] = *(const bfx8*)(&As[ba + 4096]);
    }
    stage_half(3 * t + 6);  // A0 of tile t+2
    stage_half(3 * t + 7);  // B  of tile t+2
    if (t + 2 < NT) asm volatile("s_waitcnt vmcnt(4)" ::: "memory");
    else            asm volatile("s_waitcnt vmcnt(0)" ::: "memory");
    __builtin_amdgcn_s_barrier();
    asm volatile("s_waitcnt lgkmcnt(0)" ::: "memory");
    __builtin_amdgcn_sched_barrier(0);
    __builtin_amdgcn_s_setprio(1);
#pragma unroll
    for (int mi = 0; mi < 4; ++mi)
#pragma unroll
      for (int ni = 0; ni < 2; ++ni) {
        acc[1][mi][ni] = MFMA16(af[mi][0], bf[ni][0], acc[1][mi][ni]);
        acc[1][mi][ni] = MFMA16(af[mi][1], bf[ni][1], acc[1][mi][ni]);
      }
    __builtin_amdgcn_s_setprio(0);
    __builtin_amdgcn_s_barrier();
    asm volatile("" ::: "memory");
  }

#pragma unroll
  for (int mh = 0; mh < 2; ++mh)
#pragma unroll
    for (int mi = 0; mi < 4; ++mi)
#pragma unroll
      for (int ni = 0; ni < 2; ++ni) {
        const int col = col0 + wc * 32 + ni * 16 + qi;
        if (outMode == 5 && col >= 2304) {
          const int vcol = col - 2304;
          const int rowb = row0 + mh * 128 + wr * 64 + mi * 16 + g * 4;
          if (rowb < Mpb) {
            bfx4 ov;
#pragma unroll
            for (int r = 0; r < 4; ++r) ov[r] = (__bf16)acc[mh][mi][ni][r];
            *(bfx4*)((__bf16*)C2 + (size_t)b * (256 * 816) + (size_t)vcol * 816 + rowb) = ov;
          }
          continue;
        }
#pragma unroll
        for (int r = 0; r < 4; ++r) {
          const int row = row0 + mh * 128 + wr * 64 + mi * 16 + g * 4 + r;
          if (row >= Mpb) continue;
          const float v = acc[mh][mi][ni][r];
          if (outMode == 0) {
            ((float*)C)[(size_t)b * strideC + (size_t)row * ldc + col] = v;
          } else if (outMode == 5) {
            ((__bf16*)C)[(size_t)b * strideC + (size_t)row * ldc + col] = (__bf16)v;
          } else {  // mode 2
            const size_t ix = (size_t)b * strideC + (size_t)row * ldc + col;
            ((float*)C)[ix] = v + ((const float*)Extra)[ix];
          }
        }
      }
}

// ---------------- bf16 GEMM, panel weights, BK=64, counted-vmcnt (small-M path) ------
__global__ __launch_bounds__(256, 2)
void gemm_bt2(const __bf16* __restrict__ A, const __bf16* __restrict__ Bt,
              void* __restrict__ C, void* __restrict__ C2, const void* __restrict__ Extra,
              int Mpb, int lda, int strideA, int Kd,
              int ldc, int strideC, int mbPerBatch,
              int outMode, int ldct) {
  __shared__ __align__(16) __bf16 As[2][8192];
  __shared__ __align__(16) __bf16 Bs[2][8192];
  const int tid = threadIdx.x;
  const int lane = tid & 63;
  const int wid = tid >> 6;
  const int b = blockIdx.x / mbPerBatch;
  const int row0 = (blockIdx.x % mbPerBatch) * 128;
  const int col0 = blockIdx.y * 128;
  const __bf16* Ab = A + (size_t)b * strideA;
  const size_t nks = (size_t)(Kd >> 5);
  const __bf16* Bpan0 = Bt + ((size_t)(col0 >> 7)) * nks * 4096;
  const int wm = (wid >> 1) * 64, wn = (wid & 1) * 64;
  const int qi = lane & 15, g = lane >> 4;

  const int m0 = tid >> 2, p0 = tid & 3;
  const int lg0 = p0 ^ ((m0 >> 1) & 3);
  const int m1 = m0 + 64;
  const int lg1 = p0 ^ ((m1 >> 1) & 3);
  int mr0 = row0 + m0; if (mr0 >= Mpb) mr0 = Mpb - 1;
  int mr1 = row0 + m1; if (mr1 >= Mpb) mr1 = Mpb - 1;
  const __bf16* asrc0 = Ab + (size_t)mr0 * lda + lg0 * 8;
  const __bf16* asrc1 = Ab + (size_t)mr1 * lda + lg1 * 8;
  const int nt = Kd >> 6;

  auto stage = [&](int t, int bufi) {
    const int k0 = t * 64;
    gl_lds16(asrc0 + k0, &As[bufi][tid * 8]);
    gl_lds16(asrc1 + k0, &As[bufi][(tid + 256) * 8]);
    gl_lds16(asrc0 + k0 + 32, &As[bufi][4096 + tid * 8]);
    gl_lds16(asrc1 + k0 + 32, &As[bufi][4096 + (tid + 256) * 8]);
    const __bf16* pb = Bpan0 + (size_t)(k0 >> 5) * 4096;
    gl_lds16(pb + tid * 8, &Bs[bufi][tid * 8]);
    gl_lds16(pb + (tid + 256) * 8, &Bs[bufi][(tid + 256) * 8]);
    gl_lds16(pb + 4096 + tid * 8, &Bs[bufi][4096 + tid * 8]);
    gl_lds16(pb + 4096 + (tid + 256) * 8, &Bs[bufi][4096 + (tid + 256) * 8]);
  };

  f32x4 acc[4][4];
#pragma unroll
  for (int i = 0; i < 4; ++i)
#pragma unroll
    for (int j = 0; j < 4; ++j) acc[i][j] = f32x4{0.f, 0.f, 0.f, 0.f};

  stage(0, 0);
  if (nt > 1) stage(1, 1);

  for (int t = 0; t < nt; ++t) {
    const int cur = t & 1;
    if (t + 1 < nt) asm volatile("s_waitcnt vmcnt(8)" ::: "memory");
    else            asm volatile("s_waitcnt vmcnt(0)" ::: "memory");
    __builtin_amdgcn_s_barrier();
    asm volatile("" ::: "memory");
#pragma unroll
    for (int ks = 0; ks < 2; ++ks) {
      bfx8 af[4], bf[4];
#pragma unroll
      for (int mi = 0; mi < 4; ++mi) {
        const int m = wm + mi * 16 + qi;
        const int sl = g ^ ((m >> 1) & 3);
        af[mi] = *(const bfx8*)(&As[cur][ks * 4096 + m * 32 + sl * 8]);
      }
#pragma unroll
      for (int ni = 0; ni < 4; ++ni) {
        const int n = wn + ni * 16 + qi;
        const int sl = g ^ ((n >> 1) & 3);
        bf[ni] = *(const bfx8*)(&Bs[cur][ks * 4096 + n * 32 + sl * 8]);
      }
#pragma unroll
      for (int mi = 0; mi < 4; ++mi)
#pragma unroll
        for (int ni = 0; ni < 4; ++ni)
          acc[mi][ni] = MFMA16(af[mi], bf[ni], acc[mi][ni]);
    }
    asm volatile("s_waitcnt lgkmcnt(0)" ::: "memory");
    __builtin_amdgcn_s_barrier();
    asm volatile("" ::: "memory");
    if (t + 2 < nt) stage(t + 2, cur);
  }

#pragma unroll
  for (int mi = 0; mi < 4; ++mi) {
#pragma unroll
    for (int ni = 0; ni < 4; ++ni) {
      const int col = col0 + wn + ni * 16 + qi;
      if (outMode == 5 && col >= 2304) {
        const int vcol = col - 2304;
        const int rowb = row0 + wm + mi * 16 + g * 4;
        if (rowb < Mpb) {
          bfx4 ov;
#pragma unroll
          for (int r = 0; r < 4; ++r) ov[r] = (__bf16)acc[mi][ni][r];
          *(bfx4*)((__bf16*)C2 + (size_t)b * (256 * 816) + (size_t)vcol * 816 + rowb) = ov;
        }
        continue;
      }
#pragma unroll
      for (int r = 0; r < 4; ++r) {
        const int row = row0 + wm + mi * 16 + g * 4 + r;
        if (row >= Mpb) continue;
        const float v = acc[mi][ni][r];
        if (outMode == 0) {
          ((float*)C)[(size_t)b * strideC + (size_t)row * ldc + col] = v;
        } else if (outMode == 1 || outMode == 5) {
          ((__bf16*)C)[(size_t)b * strideC + (size_t)row * ldc + col] = (__bf16)v;
        } else {  // mode 2
          const size_t ix = (size_t)b * strideC + (size_t)row * ldc + col;
          ((float*)C)[ix] = v + ((const float*)Extra)[ix];
        }
      }
    }
  }
  (void)ldct;
}

// ---------------- Fused GEGLU dual-GEMM (128-tile, small-M path) ----------------
__global__ __launch_bounds__(256, 2)
void ffn_dual(const __bf16* __restrict__ A, const __bf16* __restrict__ Wg,
              const __bf16* __restrict__ Wa, __bf16* __restrict__ C,
              int Mpb, int lda, int strideA, int Kd,
              int ldc, int strideC, int mbPerBatch) {
  __shared__ __align__(16) __bf16 As[2][8192];
  __shared__ __align__(16) __bf16 Bs[2][8192];
  const int tid = threadIdx.x;
  const int lane = tid & 63;
  const int wid = tid >> 6;
  const int b = blockIdx.x / mbPerBatch;
  const int row0 = (blockIdx.x % mbPerBatch) * 128;
  const int col0 = blockIdx.y * 128;
  const __bf16* Ab = A + (size_t)b * strideA;
  const size_t nks = (size_t)(Kd >> 5);
  const int wm = (wid >> 1) * 64, wn = (wid & 1) * 64;
  const int qi = lane & 15, g = lane >> 4;

  const int m0 = tid >> 2, p0 = tid & 3;
  const int lg0 = p0 ^ ((m0 >> 1) & 3);
  const int m1 = m0 + 64;
  const int lg1 = p0 ^ ((m1 >> 1) & 3);
  int mr0 = row0 + m0; if (mr0 >= Mpb) mr0 = Mpb - 1;
  int mr1 = row0 + m1; if (mr1 >= Mpb) mr1 = Mpb - 1;
  const __bf16* asrc0 = Ab + (size_t)mr0 * lda + lg0 * 8;
  const __bf16* asrc1 = Ab + (size_t)mr1 * lda + lg1 * 8;
  const int nt = Kd >> 6;

  f32x4 gval[4][4];
  f32x4 acc[4][4];

#pragma unroll
  for (int pan = 0; pan < 2; ++pan) {
    const __bf16* Bpan0 = (pan ? Wa : Wg) + ((size_t)(col0 >> 7)) * nks * 4096;

    auto stage = [&](int t, int bufi) {
      const int k0 = t * 64;
      gl_lds16(asrc0 + k0, &As[bufi][tid * 8]);
      gl_lds16(asrc1 + k0, &As[bufi][(tid + 256) * 8]);
      gl_lds16(asrc0 + k0 + 32, &As[bufi][4096 + tid * 8]);
      gl_lds16(asrc1 + k0 + 32, &As[bufi][4096 + (tid + 256) * 8]);
      const __bf16* pb = Bpan0 + (size_t)(k0 >> 5) * 4096;
      gl_lds16(pb + tid * 8, &Bs[bufi][tid * 8]);
      gl_lds16(pb + (tid + 256) * 8, &Bs[bufi][(tid + 256) * 8]);
      gl_lds16(pb + 4096 + tid * 8, &Bs[bufi][4096 + tid * 8]);
      gl_lds16(pb + 4096 + (tid + 256) * 8, &Bs[bufi][4096 + (tid + 256) * 8]);
    };

#pragma unroll
    for (int i = 0; i < 4; ++i)
#pragma unroll
      for (int j = 0; j < 4; ++j) acc[i][j] = f32x4{0.f, 0.f, 0.f, 0.f};

    stage(0, 0);
    if (nt > 1) stage(1, 1);

    for (int t = 0; t < nt; ++t) {
      const int cur = t & 1;
      if (t + 1 < nt) asm volatile("s_waitcnt vmcnt(8)" ::: "memory");
      else            asm volatile("s_waitcnt vmcnt(0)" ::: "memory");
      __builtin_amdgcn_s_barrier();
      asm volatile("" ::: "memory");
#pragma unroll
      for (int ks = 0; ks < 2; ++ks) {
        bfx8 af[4], bf[4];
#pragma unroll
        for (int mi = 0; mi < 4; ++mi) {
          const int m = wm + mi * 16 + qi;
          const int sl = g ^ ((m >> 1) & 3);
          af[mi] = *(const bfx8*)(&As[cur][ks * 4096 + m * 32 + sl * 8]);
        }
#pragma unroll
        for (int ni = 0; ni < 4; ++ni) {
          const int n = wn + ni * 16 + qi;
          const int sl = g ^ ((n >> 1) & 3);
          bf[ni] = *(const bfx8*)(&Bs[cur][ks * 4096 + n * 32 + sl * 8]);
        }
#pragma unroll
        for (int mi = 0; mi < 4; ++mi)
#pragma unroll
          for (int ni = 0; ni < 4; ++ni)
            acc[mi][ni] = MFMA16(af[mi], bf[ni], acc[mi][ni]);
      }
      asm volatile("s_waitcnt lgkmcnt(0)" ::: "memory");
      __builtin_amdgcn_s_barrier();
      asm volatile("" ::: "memory");
      if (t + 2 < nt) stage(t + 2, cur);
    }

    if (pan == 0) {
#pragma unroll
      for (int i = 0; i < 4; ++i)
#pragma unroll
        for (int j = 0; j < 4; ++j)
#pragma unroll
          for (int r = 0; r < 4; ++r) gval[i][j][r] = gelu_tanh_f(acc[i][j][r]);
    }
  }

#pragma unroll
  for (int mi = 0; mi < 4; ++mi) {
#pragma unroll
    for (int ni = 0; ni < 4; ++ni) {
      const int col = col0 + wn + ni * 16 + qi;
#pragma unroll
      for (int r = 0; r < 4; ++r) {
        const int row = row0 + wm + mi * 16 + g * 4 + r;
        if (row >= Mpb) continue;
        C[(size_t)b * strideC + (size_t)row * ldc + col] =
            (__bf16)(gval[mi][ni][r] * acc[mi][ni][r]);
      }
    }
  }
}

// ---------------- Old GEMM (f32 weights on the fly) — legacy fallback ----------------
__global__ __launch_bounds__(256, 2)
void gemm_kernel(const __bf16* __restrict__ A, const float* __restrict__ Bw,
                 void* __restrict__ C, const void* __restrict__ Extra,
                 int Mpb, int lda, int strideA,
                 int ldb, int headDim, int Kd,
                 int ldc, int strideC, int mbPerBatch,
                 int outMode, int ldct) {
  __shared__ __align__(16) __bf16 As[128 * 32];
  __shared__ __align__(16) __bf16 Bs[128 * 32];
  const int tid = threadIdx.x;
  const int lane = tid & 63;
  const int wid = tid >> 6;
  const int b = blockIdx.x / mbPerBatch;
  const int row0 = (blockIdx.x % mbPerBatch) * 128;
  const int col0 = blockIdx.y * 128;
  const __bf16* Ab = A + (size_t)b * strideA;
  const float* Bb = (headDim > 0)
      ? (Bw + (size_t)(col0 / headDim) * (size_t)Kd * headDim + (col0 % headDim))
      : (Bw + col0);
  const int wm = (wid >> 1) * 64, wn = (wid & 1) * 64;
  const int qi = lane & 15, g = lane >> 4;

  f32x4 acc[4][4];
#pragma unroll
  for (int i = 0; i < 4; ++i)
#pragma unroll
    for (int j = 0; j < 4; ++j) acc[i][j] = f32x4{0.f, 0.f, 0.f, 0.f};

  const int am = tid >> 2, ap = tid & 3;
  const int bn = tid >> 2, bc = tid & 3;

  for (int k0 = 0; k0 < Kd; k0 += 32) {
    __syncthreads();
#pragma unroll
    for (int s = 0; s < 2; ++s) {
      const int m = am + s * 64;
      int mr = row0 + m;
      if (mr >= Mpb) mr = Mpb - 1;
      const int lg = ap ^ ((m >> 1) & 3);
      bfx8 v = *(const bfx8*)(Ab + (size_t)mr * lda + k0 + lg * 8);
      *(bfx8*)(&As[m * 32 + ap * 8]) = v;
    }
#pragma unroll
    for (int s = 0; s < 2; ++s) {
      const int n = bn + s * 64;
      const float* bp = Bb + (size_t)(k0 + bc * 8) * ldb + n;
      bfx8 v;
#pragma unroll
      for (int i = 0; i < 8; ++i) v[i] = (__bf16)bp[(size_t)i * ldb];
      const int p = bc ^ ((n >> 1) & 3);
      *(bfx8*)(&Bs[n * 32 + p * 8]) = v;
    }
    __syncthreads();
    bfx8 af[4], bf[4];
#pragma unroll
    for (int mi = 0; mi < 4; ++mi) {
      const int m = wm + mi * 16 + qi;
      const int sl = g ^ ((m >> 1) & 3);
      af[mi] = *(const bfx8*)(&As[m * 32 + sl * 8]);
    }
#pragma unroll
    for (int ni = 0; ni < 4; ++ni) {
      const int n = wn + ni * 16 + qi;
      const int sl = g ^ ((n >> 1) & 3);
      bf[ni] = *(const bfx8*)(&Bs[n * 32 + sl * 8]);
    }
#pragma unroll
    for (int mi = 0; mi < 4; ++mi)
#pragma unroll
      for (int ni = 0; ni < 4; ++ni)
        acc[mi][ni] = MFMA16(af[mi], bf[ni], acc[mi][ni]);
  }

#pragma unroll
  for (int mi = 0; mi < 4; ++mi) {
#pragma unroll
    for (int ni = 0; ni < 4; ++ni) {
      const int col = col0 + wn + ni * 16 + qi;
#pragma unroll
      for (int r = 0; r < 4; ++r) {
        const int row = row0 + wm + mi * 16 + g * 4 + r;
        if (row >= Mpb) continue;
        const float v = acc[mi][ni][r];
        if (outMode == 0) {
          ((float*)C)[(size_t)b * strideC + (size_t)row * ldc + col] = v;
        } else if (outMode == 1) {
          ((__bf16*)C)[(size_t)b * strideC + (size_t)row * ldc + col] = (__bf16)v;
        } else if (outMode == 2) {
          const size_t ix = (size_t)b * strideC + (size_t)row * ldc + col;
          ((float*)C)[ix] = v + ((const float*)Extra)[ix];
        } else if (outMode == 3) {
          ((__bf16*)C)[(size_t)b * strideC + (size_t)col * ldct + row] = (__bf16)v;
        } else {
          const size_t ix = (size_t)b * strideC + (size_t)row * ldc + col;
          const float gt = (float)((const __bf16*)Extra)[ix];
          ((__bf16*)C)[ix] = (__bf16)(gelu_tanh_f(gt) * v);
        }
      }
    }
  }
}

// ---------------- Fused attention (q/k strides parameterized) ----------------
__global__ __launch_bounds__(256, 2)
void attn_kernel(const __bf16* __restrict__ qp, const __bf16* __restrict__ kp0,
                 const __bf16* __restrict__ vt, __bf16* __restrict__ ao,
                 int qstride, int kstride) {
  __shared__ __align__(16) __bf16 Ps[4][1024];
  __shared__ float denw[4][16];
  const int tid = threadIdx.x, lane = tid & 63, wid = tid >> 6;
  const int qt = blockIdx.x, hn = blockIdx.y, b = blockIdx.z;
  const int q0 = qt * 64;
  const int qi = lane & 15, g = lane >> 4;

  int qrow = q0 + wid * 16 + qi;
  if (qrow > 815) qrow = 815;
  const int cmq = (qrow >= 768) + (qrow >= 771);
  const __bf16* qrp = qp + (size_t)(b * 816 + qrow) * qstride + hn * 256 + g * 8;
  bfx8 qf[8];
#pragma unroll
  for (int kf = 0; kf < 8; ++kf) qf[kf] = *(const bfx8*)(qrp + kf * 32);

  f32x4 oacc[16];
#pragma unroll
  for (int i = 0; i < 16; ++i) oacc[i] = f32x4{0.f, 0.f, 0.f, 0.f};
  float den = 0.f;

  const int ntiles = (q0 + 63 < 768) ? 12 : 13;
  for (int t = 0; t < ntiles; ++t) {
    const int kv0 = t * 64;
#pragma unroll
    for (int mi = 0; mi < 4; ++mi) {
      f32x4 sac = f32x4{0.f, 0.f, 0.f, 0.f};
      int srow = kv0 + mi * 16 + qi;
      if (srow > 815) srow = 815;
      const __bf16* kp = kp0 + (size_t)(b * 816 + srow) * kstride + g * 8;
#pragma unroll
      for (int kf = 0; kf < 8; ++kf) {
        bfx8 a = *(const bfx8*)(kp + kf * 32);
        sac = MFMA16(a, qf[kf], sac);
      }
      float pv[4];
#pragma unroll
      for (int r = 0; r < 4; ++r) {
        const int s = kv0 + mi * 16 + g * 4 + r;
        const float l = sac[r];
        const float e2 = __expf(l * 0.04f);
        const float capped = 50.f * (e2 - 1.f) / (e2 + 1.f);
        const int cms = (s >= 768) + (s >= 771);
        const bool ok = (s < 816) && (cms <= cmq);
        const float p = ok ? __expf(capped) : 0.f;
        den += p;
        pv[r] = p;
      }
      const unsigned lo = pack_bf2(pv[0], pv[1]);
      const unsigned hi = pack_bf2(pv[2], pv[3]);
      const int slot = 2 * mi + (g >> 1);
      const int phys = slot ^ (qi & 7);
      char* pb = (char*)&Ps[wid][0] + qi * 128 + phys * 16 + (g & 1) * 8;
      *(unsigned*)(pb) = lo;
      *(unsigned*)(pb + 4) = hi;
    }
    asm volatile("s_waitcnt lgkmcnt(0)" ::: "memory");
    bfx8 pa[2];
#pragma unroll
    for (int k2 = 0; k2 < 2; ++k2) {
      const int sl = (k2 * 4 + g) ^ (qi & 7);
      pa[k2] = *(const bfx8*)((const char*)&Ps[wid][0] + qi * 128 + sl * 16);
    }
#pragma unroll
    for (int hf = 0; hf < 16; ++hf) {
      const int h = hf * 16 + qi;
#pragma unroll
      for (int k2 = 0; k2 < 2; ++k2) {
        int s0 = kv0 + k2 * 32 + g * 8;
        if (s0 > 808) s0 = 808;
        bfx8 vb = *(const bfx8*)(vt + ((size_t)(b * 256 + h)) * 816 + s0);
        oacc[hf] = MFMA16(pa[k2], vb, oacc[hf]);
      }
    }
    asm volatile("s_waitcnt lgkmcnt(0)" ::: "memory");
  }

  den += __shfl_xor(den, 16, 64);
  den += __shfl_xor(den, 32, 64);
  if (lane < 16) denw[wid][qi] = den;
  asm volatile("s_waitcnt lgkmcnt(0)" ::: "memory");
#pragma unroll
  for (int r = 0; r < 4; ++r) {
    const int qg = q0 + wid * 16 + g * 4 + r;
    if (qg >= 816) continue;
    const float di = 1.f / denw[wid][g * 4 + r];
#pragma unroll
    for (int hf = 0; hf < 16; ++hf) {
      ao[((size_t)(b * 816 + qg)) * 2048 + hn * 256 + hf * 16 + qi] =
          (__bf16)(oacc[hf][r] * di);
    }
  }
}

// ---------------- Host orchestration ----------------
extern "C" void kernel_launch(void* const* d_in, const int* in_sizes, int n_in,
                              void* d_out, int out_size, void* d_ws, size_t ws_size,
                              hipStream_t stream) {
  (void)in_sizes; (void)n_in; (void)out_size;
  const float* x      = (const float*)d_in[0];
  const int*   pos    = (const int*)d_in[1];
  const float* s_attn = (const float*)d_in[4];
  const float* s_ffw  = (const float*)d_in[5];
  const float* gq     = (const float*)d_in[6];
  const float* gkv    = (const float*)d_in[7];
  const float* go     = (const float*)d_in[8];
  const float* aq     = (const float*)d_in[9];
  const float* akv    = (const float*)d_in[10];
  const float* aow    = (const float*)d_in[11];
  const float* gg     = (const float*)d_in[12];
  const float* gl     = (const float*)d_in[13];
  const float* ag     = (const float*)d_in[14];
  const float* al     = (const float*)d_in[15];
  float* outp = (float*)d_out;
  char* ws = (char*)d_ws;
  dim3 blk(256);

  const size_t NEED_BATCH = 577437696u;
  const size_t NEED_FAST  = 423297024u;

  if (ws_size >= NEED_FAST) {
    const bool batched = (ws_size >= NEED_BATCH);
    // weights (tile-panel bf16); QKV fused: [Q 16 panels][K 2][V 2] contiguous
    __bf16* wQKVg = (__bf16*)(ws + 0);          // 20 panels x 64ks x 4096
    __bf16* wQKVa = (__bf16*)(ws + 10485760);
    __bf16* goT = (__bf16*)(ws + 20971520);
    __bf16* aoT = (__bf16*)(ws + 29360128);
    __bf16* ggT = (__bf16*)(ws + 37748736);     // [2] x [16384 x 2048]
    __bf16* glT = (__bf16*)(ws + 171966464);    // [2048 x 16384]
    __bf16* agT = (__bf16*)(ws + 239075328);    // [2] x [4096 x 2048]
    __bf16* alT = (__bf16*)(ws + 272629760);    // [2048 x 4096]
    // activations
    __bf16* xn   = (__bf16*)(ws + 289406976);   // [3264][2048]
    __bf16* qkb  = (__bf16*)(ws + 302776320);   // [3264][2304]  Q cols 0-2047, K 2048-2303
    __bf16* vt   = (__bf16*)(ws + 317816832);   // [4][256][816]
    __bf16* aob  = (__bf16*)(ws + 319488000);   // [3264][2048]
    float*  ob   = (float*)(ws + 332857344);    // [3264][2048] f32
    __bf16* hb   = (__bf16*)(ws + 359596032);   // [3264][2048]
    __bf16* gate  = (__bf16*)(ws + 372965376);  // per-batch scratch
    __bf16* act   = (__bf16*)(ws + 398131200);  // per-batch [768][16384]
    __bf16* act4  = (__bf16*)(ws + 473628672);  // batched [4][768][16384]
    __bf16* actA4 = (__bf16*)(ws + 575864832);  // batched [4][48][4096]

    // weight conversion (f32 [K][N] -> bf16 panel)
    convw_kernel<<<dim3(32, 32), blk, 0, stream>>>(gq, wQKVg, 2048, 256);
    convw_kernel<<<dim3(4, 32), blk, 0, stream>>>(gkv, wQKVg + 16 * 64 * 4096, 2048, 256);
    convw_kernel<<<dim3(4, 32), blk, 0, stream>>>(gkv + 2048 * 256, wQKVg + 18 * 64 * 4096, 2048, 256);
    convw_kernel<<<dim3(32, 32), blk, 0, stream>>>(aq, wQKVa, 2048, 256);
    convw_kernel<<<dim3(4, 32), blk, 0, stream>>>(akv, wQKVa + 16 * 64 * 4096, 2048, 256);
    convw_kernel<<<dim3(4, 32), blk, 0, stream>>>(akv + 2048 * 256, wQKVa + 18 * 64 * 4096, 2048, 256);
    convw_kernel<<<dim3(32, 32), blk, 0, stream>>>(go, goT, 2048, 2048);
    convw_kernel<<<dim3(32, 32), blk, 0, stream>>>(aow, aoT, 2048, 2048);
    convw_kernel<<<dim3(256, 32), blk, 0, stream>>>(gg, ggT, 2048, 16384);
    convw_kernel<<<dim3(256, 32), blk, 0, stream>>>(gg + (size_t)2048 * 16384, ggT + (size_t)16384 * 2048, 2048, 16384);
    convw_kernel<<<dim3(32, 256), blk, 0, stream>>>(gl, glT, 16384, 2048);
    convw_kernel<<<dim3(64, 32), blk, 0, stream>>>(ag, agT, 2048, 4096);
    convw_kernel<<<dim3(64, 32), blk, 0, stream>>>(ag + (size_t)2048 * 4096, agT + (size_t)4096 * 2048, 2048, 4096);
    convw_kernel<<<dim3(32, 64), blk, 0, stream>>>(al, alT, 4096, 2048);

    // 1. pre-attention rmsnorm
    rmsnorm_kernel<<<3264, blk, 0, stream>>>(x, nullptr, s_attn, xn);

    // 2. fused QKV projection, gemma+action merged (row-block 3 = action weights)
    gemm256<<<dim3(16, 20), dim3(512), 0, stream>>>(xn, wQKVg, wQKVa, qkb, vt, nullptr,
        816, 2048, 816 * 2048, 2048, 2304, 816 * 2304, 4, 5);

    // 3. RoPE in place, Q+K in one launch (heads 0-7 scaled by H^-0.5, head 8 = K unscaled)
    rope_bf_kernel<<<3264, blk, 0, stream>>>(qkb, pos, 9, 2304, 8, 0.0625f);

    // 4. attention
    attn_kernel<<<dim3(13, 8, 4), blk, 0, stream>>>(qkb, qkb + 2048, vt, aob, 2304, 2304);

    // 5. output projection, gemma+action merged
    gemm256<<<dim3(16, 16), dim3(512), 0, stream>>>(aob, goT, aoT, ob, nullptr, nullptr,
        816, 2048, 816 * 2048, 2048, 2048, 816 * 2048, 4, 0);

    // 6. pre-FFW rmsnorm of (o + x)
    rmsnorm_kernel<<<3264, blk, 0, stream>>>(ob, x, s_ffw, hb);

    // 7. FFN (2-phase fused gate+act dual GEMM, then 2-phase down-proj with residual)
    if (batched) {
      ffn_dual256<<<dim3(12, 128), dim3(512), 0, stream>>>(hb, ggT, ggT + (size_t)16384 * 2048, act4,
          768, 2048, 816 * 2048, 2048, 16384, 768 * 16384, 3);
      gemm256<<<dim3(12, 16), dim3(512), 0, stream>>>(act4, glT, nullptr, outp, nullptr, x,
          768, 16384, 768 * 16384, 16384, 2048, 816 * 2048, 3, 2);
      ffn_dual<<<dim3(4, 32), blk, 0, stream>>>(hb + 768 * 2048, agT, agT + (size_t)4096 * 2048, actA4,
          48, 2048, 816 * 2048, 2048, 4096, 48 * 4096, 1);
      gemm_bt2<<<dim3(4, 16), blk, 0, stream>>>(actA4, alT, outp + 768 * 2048, nullptr, x + 768 * 2048,
          48, 4096, 48 * 4096, 4096, 2048, 816 * 2048, 1, 2, 0);
    } else {
      for (int bb = 0; bb < 4; ++bb) {
        const __bf16* hg = hb + (size_t)bb * 816 * 2048;
        float* og = outp + (size_t)bb * 816 * 2048;
        const float* xg = x + (size_t)bb * 816 * 2048;
        ffn_dual<<<dim3(6, 128), blk, 0, stream>>>(hg, ggT, ggT + (size_t)16384 * 2048, act,
            768, 2048, 0, 2048, 16384, 0, 6);
        gemm_bt2<<<dim3(6, 16), blk, 0, stream>>>(act, glT, og, nullptr, xg,
            768, 16384, 0, 16384, 2048, 0, 6, 2, 0);
        const __bf16* ha = hg + 768 * 2048;
        ffn_dual<<<dim3(1, 32), blk, 0, stream>>>(ha, agT, agT + (size_t)4096 * 2048, gate,
            48, 2048, 0, 2048, 4096, 0, 1);
        gemm_bt2<<<dim3(1, 16), blk, 0, stream>>>(gate, alT, og + 768 * 2048, nullptr, xg + 768 * 2048,
            48, 4096, 0, 4096, 2048, 0, 1, 2, 0);
      }
    }
    return;
  }

  // ---- legacy fallback path (round-0, on-the-fly f32 weights) ----
  if (ws_size < 164000000u) return;
  __bf16* xn   = (__bf16*)(ws + 0);
  float*  qf   = (float*)(ws + 13369344);
  __bf16* qbb  = (__bf16*)(ws + 40108032);
  float*  kf   = (float*)(ws + 53477376);
  __bf16* kbb  = (__bf16*)(ws + 56819712);
  __bf16* vt   = (__bf16*)(ws + 58490880);
  __bf16* aob  = (__bf16*)(ws + 60162048);
  float*  ob   = (float*)(ws + 73531392);
  __bf16* hb   = (__bf16*)(ws + 100270080);
  __bf16* gate = (__bf16*)(ws + 113639424);
  __bf16* act  = (__bf16*)(ws + 138805248);

  rmsnorm_kernel<<<3264, blk, 0, stream>>>(x, nullptr, s_attn, xn);
  gemm_kernel<<<dim3(24, 16), blk, 0, stream>>>(xn, gq, qf, nullptr,
      768, 2048, 816 * 2048, 256, 256, 2048, 2048, 816 * 2048, 6, 0, 0);
  gemm_kernel<<<dim3(4, 16), blk, 0, stream>>>(xn + 768 * 2048, aq, qf + 768 * 2048, nullptr,
      48, 2048, 816 * 2048, 256, 256, 2048, 2048, 816 * 2048, 1, 0, 0);
  gemm_kernel<<<dim3(24, 2), blk, 0, stream>>>(xn, gkv, kf, nullptr,
      768, 2048, 816 * 2048, 256, 256, 2048, 256, 816 * 256, 6, 0, 0);
  gemm_kernel<<<dim3(4, 2), blk, 0, stream>>>(xn + 768 * 2048, akv, kf + 768 * 256, nullptr,
      48, 2048, 816 * 2048, 256, 256, 2048, 256, 816 * 256, 1, 0, 0);
  gemm_kernel<<<dim3(24, 2), blk, 0, stream>>>(xn, gkv + 2048 * 256, vt, nullptr,
      768, 2048, 816 * 2048, 256, 256, 2048, 0, 256 * 816, 6, 3, 816);
  gemm_kernel<<<dim3(4, 2), blk, 0, stream>>>(xn + 768 * 2048, akv + 2048 * 256, vt + 768, nullptr,
      48, 2048, 816 * 2048, 256, 256, 2048, 0, 256 * 816, 1, 3, 816);
  rope_kernel<<<3264, blk, 0, stream>>>(qf, pos, qbb, 8, 0.0625f);
  rope_kernel<<<3264, blk, 0, stream>>>(kf, pos, kbb, 1, 1.0f);
  attn_kernel<<<dim3(13, 8, 4), blk, 0, stream>>>(qbb, kbb, vt, aob, 2048, 256);
  gemm_kernel<<<dim3(24, 16), blk, 0, stream>>>(aob, go, ob, nullptr,
      768, 2048, 816 * 2048, 2048, 0, 2048, 2048, 816 * 2048, 6, 0, 0);
  gemm_kernel<<<dim3(4, 16), blk, 0, stream>>>(aob + 768 * 2048, aow, ob + 768 * 2048, nullptr,
      48, 2048, 816 * 2048, 2048, 0, 2048, 2048, 816 * 2048, 1, 0, 0);
  rmsnorm_kernel<<<3264, blk, 0, stream>>>(ob, x, s_ffw, hb);
  for (int bb = 0; bb < 4; ++bb) {
    const __bf16* hg = hb + (size_t)bb * 816 * 2048;
    float* og = outp + (size_t)bb * 816 * 2048;
    const float* xg = x + (size_t)bb * 816 * 2048;
    gemm_kernel<<<dim3(6, 128), blk, 0, stream>>>(hg, gg, gate, nullptr,
        768, 2048, 0, 16384, 0, 2048, 16384, 0, 6, 1, 0);
    gemm_kernel<<<dim3(6, 128), blk, 0, stream>>>(hg, gg + 2048 * 16384, act, gate,
        768, 2048, 0, 16384, 0, 2048, 16384, 0, 6, 4, 0);
    gemm_kernel<<<dim3(6, 16), blk, 0, stream>>>(act, gl, og, xg,
        768, 16384, 0, 2048, 0, 16384, 2048, 0, 6, 2, 0);
    const __bf16* ha = hg + 768 * 2048;
    gemm_kernel<<<dim3(1, 32), blk, 0, stream>>>(ha, ag, gate, nullptr,
        48, 2048, 0, 4096, 0, 2048, 4096, 0, 1, 1, 0);
    gemm_kernel<<<dim3(1, 32), blk, 0, stream>>>(ha, ag + 2048 * 4096, act, gate,
        48, 2048, 0, 4096, 0, 2048, 4096, 0, 1, 4, 0);
    gemm_kernel<<<dim3(1, 16), blk, 0, stream>>>(act, al, og + 768 * 2048, xg + 768 * 2048,
        48, 4096, 0, 2048, 0, 4096, 2048, 0, 1, 2, 0);
  }
}

// Round 17
// 1257.949 us; speedup vs baseline: 1.2350x; 1.0757x over previous
//
#include <hip/hip_runtime.h>
#include <hip/hip_bf16.h>

typedef __bf16 bfx8 __attribute__((ext_vector_type(8)));
typedef __bf16 bfx4 __attribute__((ext_vector_type(4)));
typedef float f32x4 __attribute__((ext_vector_type(4)));

#define MFMA16(a, b, c) __builtin_amdgcn_mfma_f32_16x16x32_bf16((a), (b), (c), 0, 0, 0)

__device__ __forceinline__ void gl_lds16(const __bf16* g, __bf16* l) {
  __builtin_amdgcn_global_load_lds(
      (const __attribute__((address_space(1))) unsigned int*)(const void*)g,
      (__attribute__((address_space(3))) unsigned int*)(void*)l, 16, 0, 0);
}

__device__ __forceinline__ unsigned pack_bf2(float a, float b) {
  unsigned short ua = __builtin_bit_cast(unsigned short, (__bf16)a);
  unsigned short ub = __builtin_bit_cast(unsigned short, (__bf16)b);
  return (unsigned)ua | ((unsigned)ub << 16);
}

__device__ __forceinline__ float gelu_tanh_f(float x) {
  float u = 0.7978845608028654f * (x + 0.044715f * x * x * x);
  float t;
  if (u > 10.f) t = 1.f;
  else if (u < -10.f) t = -1.f;
  else { float e = __expf(2.f * u); t = (e - 1.f) / (e + 1.f); }
  return 0.5f * x * (1.f + t);
}

// ---------------- RMSNorm (optionally fused residual add) ----------------
__global__ __launch_bounds__(256)
void rmsnorm_kernel(const float* __restrict__ X, const float* __restrict__ X2,
                    const float* __restrict__ scale, __bf16* __restrict__ out) {
  __shared__ float wsum[4];
  const int row = blockIdx.x, tid = threadIdx.x;
  const size_t base = (size_t)row * 2048;
  f32x4 v[2];
  float ss = 0.f;
#pragma unroll
  for (int i = 0; i < 2; ++i) {
    const int idx = tid * 4 + i * 1024;
    v[i] = *(const f32x4*)(X + base + idx);
    if (X2) { f32x4 u = *(const f32x4*)(X2 + base + idx); v[i] = v[i] + u; }
#pragma unroll
    for (int j = 0; j < 4; ++j) ss += v[i][j] * v[i][j];
  }
#pragma unroll
  for (int o = 32; o > 0; o >>= 1) ss += __shfl_xor(ss, o, 64);
  if ((tid & 63) == 0) wsum[tid >> 6] = ss;
  __syncthreads();
  const float tot = wsum[0] + wsum[1] + wsum[2] + wsum[3];
  const float rs = rsqrtf(tot * (1.f / 2048.f) + 1e-6f);
#pragma unroll
  for (int i = 0; i < 2; ++i) {
    const int idx = tid * 4 + i * 1024;
    f32x4 sc = *(const f32x4*)(scale + idx);
    bfx4 ov;
#pragma unroll
    for (int j = 0; j < 4; ++j) ov[j] = (__bf16)(v[i][j] * rs * (1.f + sc[j]));
    *(bfx4*)(out + base + idx) = ov;
  }
}

// ---------------- RoPE in-place on bf16, per-head scale (q heads scaled, K head not) --
__global__ __launch_bounds__(256)
void rope_bf_kernel(__bf16* __restrict__ buf, const int* __restrict__ pos,
                    int nheads, int rstride, int qheads, float qscale) {
  const int row = blockIdx.x;
  const float p = (float)pos[row];
  const int total = nheads * 128;
  const size_t rbase = (size_t)row * (size_t)rstride;
  for (int idx = threadIdx.x; idx < total; idx += 256) {
    const int n = idx >> 7, i = idx & 127;
    const float outscale = (n < qheads) ? qscale : 1.0f;
    const float ts = __expf(-(float)i * 0.071955784f);  // 10000^(-i/128)
    float sn, cs;
    __sincosf(p * ts, &sn, &cs);
    __bf16* bp = buf + rbase + n * 256 + i;
    const float x1 = (float)bp[0], x2 = (float)bp[128];
    bp[0]   = (__bf16)((x1 * cs - x2 * sn) * outscale);
    bp[128] = (__bf16)((x2 * cs + x1 * sn) * outscale);
  }
}

// ---------------- RoPE f32 -> bf16 (fallback path) ----------------
__global__ __launch_bounds__(256)
void rope_kernel(const float* __restrict__ in, const int* __restrict__ pos,
                 __bf16* __restrict__ outp, int nheads, float outscale) {
  const int row = blockIdx.x;
  const float p = (float)pos[row];
  const int total = nheads * 128;
  const size_t rbase = (size_t)row * (size_t)(nheads * 256);
  for (int idx = threadIdx.x; idx < total; idx += 256) {
    const int n = idx >> 7, i = idx & 127;
    const float ts = __expf(-(float)i * 0.071955784f);
    float sn, cs;
    __sincosf(p * ts, &sn, &cs);
    const float* bp = in + rbase + n * 256 + i;
    const float x1 = bp[0], x2 = bp[128];
    __bf16* ob = outp + rbase + n * 256 + i;
    ob[0]   = (__bf16)((x1 * cs - x2 * sn) * outscale);
    ob[128] = (__bf16)((x2 * cs + x1 * sn) * outscale);
  }
}

// ---------------- Weight convert: f32 W[k][c] -> bf16 tile-panel layout ----------------
// Panel: (cp*(K/32)+ks)*4096 holds the 128x32 tile pre-swizzled in LDS-linear order:
// element (m=col&127, k): lg=(k%32)/8, p=lg^((m>>1)&3), offset = m*32 + p*8 + (k&7).
__global__ __launch_bounds__(256)
void convw_kernel(const float* __restrict__ in, __bf16* __restrict__ out,
                  int K, int headDim) {
  __shared__ __bf16 tile[64][65];
  const int tc0 = blockIdx.x * 64;
  const int tk0 = blockIdx.y * 64;
  const int tid = threadIdx.x;
  const int cchunk = tid & 15, krow = tid >> 4;
  const int c = tc0 + cchunk * 4;
  const float* colbase = in + (size_t)(c / headDim) * (size_t)K * headDim + (c % headDim);
#pragma unroll
  for (int i = 0; i < 4; ++i) {
    const int k = tk0 + krow + i * 16;
    f32x4 v = *(const f32x4*)(colbase + (size_t)k * headDim);
#pragma unroll
    for (int j = 0; j < 4; ++j) tile[cchunk * 4 + j][krow + i * 16] = (__bf16)v[j];
  }
  __syncthreads();
  const int nks = K >> 5;
#pragma unroll
  for (int s = 0; s < 2; ++s) {
    const int ch = tid + s * 256;
    const int wc = ch >> 3, wk8 = (ch & 7) * 8;
    bfx8 v;
#pragma unroll
    for (int j = 0; j < 8; ++j) v[j] = tile[wc][wk8 + j];
    const int col = tc0 + wc;
    const int kchunk = (tk0 + wk8) >> 3;
    const int cp = col >> 7, m = col & 127;
    const int ks = kchunk >> 2, lg = kchunk & 3;
    const int p = lg ^ ((m >> 1) & 3);
    *(bfx8*)(out + ((size_t)(cp * nks + ks)) * 4096 + m * 32 + p * 8) = v;
  }
}

// ---------------- 2-phase fused GEGLU dual-GEMM (256x128 tile, 512 threads) ----------
// C = gelu(A·Wg) * (A·Wa), bf16 out. XCD-chunked block swizzle.
__global__ __launch_bounds__(512, 2)
void ffn_dual256(const __bf16* __restrict__ A, const __bf16* __restrict__ Wg,
                 const __bf16* __restrict__ Wa, __bf16* __restrict__ C,
                 int Mpb, int lda, int strideA, int Kd,
                 int ldc, int strideC, int mbPerBatch) {
  __shared__ __align__(16) __bf16 As[2 * 2 * 8192];  // [buf][half][128x64]
  __shared__ __align__(16) __bf16 Bs[2 * 2 * 8192];  // [buf][pan][128x64]
  const int tid = threadIdx.x;
  const int lane = tid & 63;
  const int wid = tid >> 6;
  const int wr = wid >> 2;
  const int wc = wid & 3;
  const int qi = lane & 15, g = lane >> 4;
  // XCD-chunked swizzle (nwg divisible by 8)
  int bid = blockIdx.y * gridDim.x + blockIdx.x;
  const int nwg = gridDim.x * gridDim.y;
  if ((nwg & 7) == 0) bid = (bid & 7) * (nwg >> 3) + (bid >> 3);
  const int bx = bid % gridDim.x, by = bid / gridDim.x;
  const int b = bx / mbPerBatch;
  const int row0 = (bx % mbPerBatch) * 256;
  const int col0 = by * 128;
  const __bf16* Ab = A + (size_t)b * strideA;
  const size_t nks = (size_t)(Kd >> 5);
  const __bf16* Bgp = Wg + ((size_t)(col0 >> 7)) * nks * 4096;
  const __bf16* Bap = Wa + ((size_t)(col0 >> 7)) * nks * 4096;
  const int NT = Kd >> 6;

  const int sm = tid >> 2, sp = tid & 3;
  const int slg = sp ^ ((sm >> 1) & 3);
  int r0 = row0 + sm;       if (r0 >= Mpb) r0 = Mpb - 1;
  int r1 = row0 + 128 + sm; if (r1 >= Mpb) r1 = Mpb - 1;
  const __bf16* asrc0 = Ab + (size_t)r0 * lda + slg * 8;
  const __bf16* asrc1 = Ab + (size_t)r1 * lda + slg * 8;

  // half order per K-tile t: 0=A0, 1=Bg, 2=A1, 3=Ba
  auto stage_half = [&](int gh) {
    if (gh >= 4 * NT) return;
    const int t = gh >> 2, which = gh & 3;
    const int bufi = t & 1;
    if ((which & 1) == 0) {
      const int h = which >> 1;
      __bf16* dst = &As[bufi * 16384 + h * 8192];
      const __bf16* src = (h ? asrc1 : asrc0) + t * 64;
      gl_lds16(src, dst + tid * 8);
      gl_lds16(src + 32, dst + 4096 + tid * 8);
    } else {
      const int pan = which >> 1;
      __bf16* dst = &Bs[bufi * 16384 + pan * 8192];
      const __bf16* src = (pan ? Bap : Bgp) + (size_t)(t * 2) * 4096 + tid * 8;
      gl_lds16(src, dst + tid * 8);
      gl_lds16(src + 4096, dst + 4096 + tid * 8);
    }
  };

  f32x4 acc[2][2][4][2];
#pragma unroll
  for (int a0 = 0; a0 < 2; ++a0)
#pragma unroll
    for (int a1 = 0; a1 < 2; ++a1)
#pragma unroll
      for (int a2 = 0; a2 < 4; ++a2)
#pragma unroll
        for (int a3 = 0; a3 < 2; ++a3) acc[a0][a1][a2][a3] = f32x4{0.f, 0.f, 0.f, 0.f};

  for (int gh = 0; gh < 6; ++gh) stage_half(gh);
  asm volatile("s_waitcnt vmcnt(4)" ::: "memory");
  __builtin_amdgcn_s_barrier();
  asm volatile("" ::: "memory");

  for (int t = 0; t < NT; ++t) {
    const int cb = (t & 1) * 16384;
    bfx8 af[4][2], bf[2][2][2];

    // ---- PHASE 0: A-half 0, both panels ----
#pragma unroll
    for (int mi = 0; mi < 4; ++mi) {
      const int m = wr * 64 + mi * 16 + qi;
      const int sl = g ^ ((m >> 1) & 3);
      const int ba = cb + m * 32 + sl * 8;
      af[mi][0] = *(const bfx8*)(&As[ba]);
      af[mi][1] = *(const bfx8*)(&As[ba + 4096]);
    }
#pragma unroll
    for (int pan = 0; pan < 2; ++pan)
#pragma unroll
      for (int ni = 0; ni < 2; ++ni) {
        const int m = wc * 32 + ni * 16 + qi;
        const int sl = g ^ ((m >> 1) & 3);
        const int bb = cb + pan * 8192 + m * 32 + sl * 8;
        bf[pan][ni][0] = *(const bfx8*)(&Bs[bb]);
        bf[pan][ni][1] = *(const bfx8*)(&Bs[bb + 4096]);
      }
    stage_half(4 * t + 6);
    stage_half(4 * t + 7);
    __builtin_amdgcn_s_barrier();
    asm volatile("s_waitcnt lgkmcnt(0)" ::: "memory");
    __builtin_amdgcn_sched_barrier(0);
    __builtin_amdgcn_s_setprio(1);
#pragma unroll
    for (int pan = 0; pan < 2; ++pan)
#pragma unroll
      for (int mi = 0; mi < 4; ++mi)
#pragma unroll
        for (int ni = 0; ni < 2; ++ni) {
          acc[0][pan][mi][ni] = MFMA16(af[mi][0], bf[pan][ni][0], acc[0][pan][mi][ni]);
          acc[0][pan][mi][ni] = MFMA16(af[mi][1], bf[pan][ni][1], acc[0][pan][mi][ni]);
        }
    __builtin_amdgcn_s_setprio(0);
    __builtin_amdgcn_s_barrier();
    asm volatile("" ::: "memory");

    // ---- PHASE 1: A-half 1, reuse bf ----
#pragma unroll
    for (int mi = 0; mi < 4; ++mi) {
      const int m = wr * 64 + mi * 16 + qi;
      const int sl = g ^ ((m >> 1) & 3);
      const int ba = cb + 8192 + m * 32 + sl * 8;
      af[mi][0] = *(const bfx8*)(&As[ba]);
      af[mi][1] = *(const bfx8*)(&As[ba + 4096]);
    }
    stage_half(4 * t + 8);
    stage_half(4 * t + 9);
    if (t + 2 < NT) asm volatile("s_waitcnt vmcnt(4)" ::: "memory");
    else            asm volatile("s_waitcnt vmcnt(0)" ::: "memory");
    __builtin_amdgcn_s_barrier();
    asm volatile("s_waitcnt lgkmcnt(0)" ::: "memory");
    __builtin_amdgcn_sched_barrier(0);
    __builtin_amdgcn_s_setprio(1);
#pragma unroll
    for (int pan = 0; pan < 2; ++pan)
#pragma unroll
      for (int mi = 0; mi < 4; ++mi)
#pragma unroll
        for (int ni = 0; ni < 2; ++ni) {
          acc[1][pan][mi][ni] = MFMA16(af[mi][0], bf[pan][ni][0], acc[1][pan][mi][ni]);
          acc[1][pan][mi][ni] = MFMA16(af[mi][1], bf[pan][ni][1], acc[1][pan][mi][ni]);
        }
    __builtin_amdgcn_s_setprio(0);
    __builtin_amdgcn_s_barrier();
    asm volatile("" ::: "memory");
  }

#pragma unroll
  for (int mh = 0; mh < 2; ++mh)
#pragma unroll
    for (int mi = 0; mi < 4; ++mi)
#pragma unroll
      for (int ni = 0; ni < 2; ++ni) {
        const int col = col0 + wc * 32 + ni * 16 + qi;
#pragma unroll
        for (int r = 0; r < 4; ++r) {
          const int row = row0 + mh * 128 + wr * 64 + mi * 16 + g * 4 + r;
          if (row >= Mpb) continue;
          C[(size_t)b * strideC + (size_t)row * ldc + col] =
              (__bf16)(gelu_tanh_f(acc[mh][0][mi][ni][r]) * acc[mh][1][mi][ni][r]);
        }
      }
}

// ---------------- 2-phase single GEMM (256x128 tile, 512 threads) ----------------
// C[b,row,col] = sum_k A[b,row,k]*W[k,col]. outMode: 0 f32, 2 f32+Extra residual,
// 5 QKV scatter (col<2304 bf16; col>=2304 V transposed into C2).
// Row-blocks with row0==768 (action segment): if BtA != nullptr use BtA weights; if
// AA != nullptr additionally switch the A-source to AA (ldaA/strideAA/KdA, local rows).
__global__ __launch_bounds__(512, 2)
void gemm256(const __bf16* __restrict__ A, const __bf16* __restrict__ Bt,
             const __bf16* __restrict__ BtA,
             void* __restrict__ C, void* __restrict__ C2, const void* __restrict__ Extra,
             int Mpb, int lda, int strideA, int Kd,
             int ldc, int strideC, int mbPerBatch, int outMode,
             const __bf16* __restrict__ AA, int ldaA, int strideAA, int KdA) {
  __shared__ __align__(16) __bf16 As[2 * 2 * 8192];  // [buf][half][128x64]
  __shared__ __align__(16) __bf16 Bs[2 * 8192];      // [buf][128x64]
  const int tid = threadIdx.x;
  const int lane = tid & 63;
  const int wid = tid >> 6;
  const int wr = wid >> 2;
  const int wc = wid & 3;
  const int qi = lane & 15, g = lane >> 4;
  int bid = blockIdx.y * gridDim.x + blockIdx.x;
  const int nwg = gridDim.x * gridDim.y;
  if ((nwg & 7) == 0) bid = (bid & 7) * (nwg >> 3) + (bid >> 3);
  const int bx = bid % gridDim.x, by = bid / gridDim.x;
  const int b = bx / mbPerBatch;
  const int row0 = (bx % mbPerBatch) * 256;
  const int col0 = by * 128;
  const bool act = (row0 == 768) && (BtA != nullptr || AA != nullptr);
  const bool actA = act && (AA != nullptr);
  const __bf16* Abase = actA ? AA : A;
  const int ldaU = actA ? ldaA : lda;
  const size_t strU = actA ? (size_t)strideAA : (size_t)strideA;
  const int KdU = actA ? KdA : Kd;
  const int rbase = actA ? 768 : 0;
  const __bf16* Ab = Abase + (size_t)b * strU;
  const size_t nks = (size_t)(KdU >> 5);
  const __bf16* Wsel = (act && BtA != nullptr) ? BtA : Bt;
  const __bf16* Bp = Wsel + ((size_t)(col0 >> 7)) * nks * 4096;
  const int NT = KdU >> 6;

  const int sm = tid >> 2, sp = tid & 3;
  const int slg = sp ^ ((sm >> 1) & 3);
  int r0 = row0 + sm;       if (r0 >= Mpb) r0 = Mpb - 1;
  int r1 = row0 + 128 + sm; if (r1 >= Mpb) r1 = Mpb - 1;
  const __bf16* asrc0 = Ab + (size_t)(r0 - rbase) * ldaU + slg * 8;
  const __bf16* asrc1 = Ab + (size_t)(r1 - rbase) * ldaU + slg * 8;

  // half order per K-tile t: 0=A0, 1=B, 2=A1
  auto stage_half = [&](int gh) {
    if (gh >= 3 * NT) return;
    const int t = gh / 3, which = gh - 3 * t;
    const int bufi = t & 1;
    if (which == 1) {
      __bf16* dst = &Bs[bufi * 8192];
      const __bf16* src = Bp + (size_t)(t * 2) * 4096 + tid * 8;
      gl_lds16(src, dst + tid * 8);
      gl_lds16(src + 4096, dst + 4096 + tid * 8);
    } else {
      const int h = which >> 1;  // 0 -> A0, 2 -> A1
      __bf16* dst = &As[bufi * 16384 + h * 8192];
      const __bf16* src = (h ? asrc1 : asrc0) + t * 64;
      gl_lds16(src, dst + tid * 8);
      gl_lds16(src + 32, dst + 4096 + tid * 8);
    }
  };

  f32x4 acc[2][4][2];  // [mh][mi][ni]
#pragma unroll
  for (int a0 = 0; a0 < 2; ++a0)
#pragma unroll
    for (int a2 = 0; a2 < 4; ++a2)
#pragma unroll
      for (int a3 = 0; a3 < 2; ++a3) acc[a0][a2][a3] = f32x4{0.f, 0.f, 0.f, 0.f};

  // prologue: tile0 full + A0,B of tile1 (halves 0..4 = 10 loads); wait tile0 (6 loads)
  for (int gh = 0; gh < 5; ++gh) stage_half(gh);
  asm volatile("s_waitcnt vmcnt(4)" ::: "memory");
  __builtin_amdgcn_s_barrier();
  asm volatile("" ::: "memory");

  for (int t = 0; t < NT; ++t) {
    const int cb = (t & 1) * 16384;
    const int cbB = (t & 1) * 8192;
    bfx8 af[4][2], bf[2][2];

    // ---- PHASE 0: A-half 0 + B (B kept for phase 1) ----
#pragma unroll
    for (int mi = 0; mi < 4; ++mi) {
      const int m = wr * 64 + mi * 16 + qi;
      const int sl = g ^ ((m >> 1) & 3);
      const int ba = cb + m * 32 + sl * 8;
      af[mi][0] = *(const bfx8*)(&As[ba]);
      af[mi][1] = *(const bfx8*)(&As[ba + 4096]);
    }
#pragma unroll
    for (int ni = 0; ni < 2; ++ni) {
      const int m = wc * 32 + ni * 16 + qi;
      const int sl = g ^ ((m >> 1) & 3);
      const int bb = cbB + m * 32 + sl * 8;
      bf[ni][0] = *(const bfx8*)(&Bs[bb]);
      bf[ni][1] = *(const bfx8*)(&Bs[bb + 4096]);
    }
    stage_half(3 * t + 5);  // A1 of tile t+1
    __builtin_amdgcn_s_barrier();
    asm volatile("s_waitcnt lgkmcnt(0)" ::: "memory");
    __builtin_amdgcn_sched_barrier(0);
    __builtin_amdgcn_s_setprio(1);
#pragma unroll
    for (int mi = 0; mi < 4; ++mi)
#pragma unroll
      for (int ni = 0; ni < 2; ++ni) {
        acc[0][mi][ni] = MFMA16(af[mi][0], bf[ni][0], acc[0][mi][ni]);
        acc[0][mi][ni] = MFMA16(af[mi][1], bf[ni][1], acc[0][mi][ni]);
      }
    __builtin_amdgcn_s_setprio(0);
    __builtin_amdgcn_s_barrier();
    asm volatile("" ::: "memory");

    // ---- PHASE 1: A-half 1, reuse bf ----
#pragma unroll
    for (int mi = 0; mi < 4; ++mi) {
      const int m = wr * 64 + mi * 16 + qi;
      const int sl = g ^ ((m >> 1) & 3);
      const int ba = cb + 8192 + m * 32 + sl * 8;
      af[mi][0] = *(const bfx8*)(&As[ba]);
      af[mi][1] = *(const bfx8*)(&As[ba + 4096]);
    }
    stage_half(3 * t + 6);  // A0 of tile t+2
    stage_half(3 * t + 7);  // B  of tile t+2
    if (t + 2 < NT) asm volatile("s_waitcnt vmcnt(4)" ::: "memory");
    else            asm volatile("s_waitcnt vmcnt(0)" ::: "memory");
    __builtin_amdgcn_s_barrier();
    asm volatile("s_waitcnt lgkmcnt(0)" ::: "memory");
    __builtin_amdgcn_sched_barrier(0);
    __builtin_amdgcn_s_setprio(1);
#pragma unroll
    for (int mi = 0; mi < 4; ++mi)
#pragma unroll
      for (int ni = 0; ni < 2; ++ni) {
        acc[1][mi][ni] = MFMA16(af[mi][0], bf[ni][0], acc[1][mi][ni]);
        acc[1][mi][ni] = MFMA16(af[mi][1], bf[ni][1], acc[1][mi][ni]);
      }
    __builtin_amdgcn_s_setprio(0);
    __builtin_amdgcn_s_barrier();
    asm volatile("" ::: "memory");
  }

#pragma unroll
  for (int mh = 0; mh < 2; ++mh)
#pragma unroll
    for (int mi = 0; mi < 4; ++mi)
#pragma unroll
      for (int ni = 0; ni < 2; ++ni) {
        const int col = col0 + wc * 32 + ni * 16 + qi;
        if (outMode == 5 && col >= 2304) {
          const int vcol = col - 2304;
          const int rowb = row0 + mh * 128 + wr * 64 + mi * 16 + g * 4;
          if (rowb < Mpb) {
            bfx4 ov;
#pragma unroll
            for (int r = 0; r < 4; ++r) ov[r] = (__bf16)acc[mh][mi][ni][r];
            *(bfx4*)((__bf16*)C2 + (size_t)b * (256 * 816) + (size_t)vcol * 816 + rowb) = ov;
          }
          continue;
        }
#pragma unroll
        for (int r = 0; r < 4; ++r) {
          const int row = row0 + mh * 128 + wr * 64 + mi * 16 + g * 4 + r;
          if (row >= Mpb) continue;
          const float v = acc[mh][mi][ni][r];
          if (outMode == 0) {
            ((float*)C)[(size_t)b * strideC + (size_t)row * ldc + col] = v;
          } else if (outMode == 5) {
            ((__bf16*)C)[(size_t)b * strideC + (size_t)row * ldc + col] = (__bf16)v;
          } else {  // mode 2
            const size_t ix = (size_t)b * strideC + (size_t)row * ldc + col;
            ((float*)C)[ix] = v + ((const float*)Extra)[ix];
          }
        }
      }
}

// ---------------- bf16 GEMM, panel weights, BK=64, counted-vmcnt (small-M path) ------
__global__ __launch_bounds__(256, 2)
void gemm_bt2(const __bf16* __restrict__ A, const __bf16* __restrict__ Bt,
              void* __restrict__ C, void* __restrict__ C2, const void* __restrict__ Extra,
              int Mpb, int lda, int strideA, int Kd,
              int ldc, int strideC, int mbPerBatch,
              int outMode, int ldct) {
  __shared__ __align__(16) __bf16 As[2][8192];
  __shared__ __align__(16) __bf16 Bs[2][8192];
  const int tid = threadIdx.x;
  const int lane = tid & 63;
  const int wid = tid >> 6;
  const int b = blockIdx.x / mbPerBatch;
  const int row0 = (blockIdx.x % mbPerBatch) * 128;
  const int col0 = blockIdx.y * 128;
  const __bf16* Ab = A + (size_t)b * strideA;
  const size_t nks = (size_t)(Kd >> 5);
  const __bf16* Bpan0 = Bt + ((size_t)(col0 >> 7)) * nks * 4096;
  const int wm = (wid >> 1) * 64, wn = (wid & 1) * 64;
  const int qi = lane & 15, g = lane >> 4;

  const int m0 = tid >> 2, p0 = tid & 3;
  const int lg0 = p0 ^ ((m0 >> 1) & 3);
  const int m1 = m0 + 64;
  const int lg1 = p0 ^ ((m1 >> 1) & 3);
  int mr0 = row0 + m0; if (mr0 >= Mpb) mr0 = Mpb - 1;
  int mr1 = row0 + m1; if (mr1 >= Mpb) mr1 = Mpb - 1;
  const __bf16* asrc0 = Ab + (size_t)mr0 * lda + lg0 * 8;
  const __bf16* asrc1 = Ab + (size_t)mr1 * lda + lg1 * 8;
  const int nt = Kd >> 6;

  auto stage = [&](int t, int bufi) {
    const int k0 = t * 64;
    gl_lds16(asrc0 + k0, &As[bufi][tid * 8]);
    gl_lds16(asrc1 + k0, &As[bufi][(tid + 256) * 8]);
    gl_lds16(asrc0 + k0 + 32, &As[bufi][4096 + tid * 8]);
    gl_lds16(asrc1 + k0 + 32, &As[bufi][4096 + (tid + 256) * 8]);
    const __bf16* pb = Bpan0 + (size_t)(k0 >> 5) * 4096;
    gl_lds16(pb + tid * 8, &Bs[bufi][tid * 8]);
    gl_lds16(pb + (tid + 256) * 8, &Bs[bufi][(tid + 256) * 8]);
    gl_lds16(pb + 4096 + tid * 8, &Bs[bufi][4096 + tid * 8]);
    gl_lds16(pb + 4096 + (tid + 256) * 8, &Bs[bufi][4096 + (tid + 256) * 8]);
  };

  f32x4 acc[4][4];
#pragma unroll
  for (int i = 0; i < 4; ++i)
#pragma unroll
    for (int j = 0; j < 4; ++j) acc[i][j] = f32x4{0.f, 0.f, 0.f, 0.f};

  stage(0, 0);
  if (nt > 1) stage(1, 1);

  for (int t = 0; t < nt; ++t) {
    const int cur = t & 1;
    if (t + 1 < nt) asm volatile("s_waitcnt vmcnt(8)" ::: "memory");
    else            asm volatile("s_waitcnt vmcnt(0)" ::: "memory");
    __builtin_amdgcn_s_barrier();
    asm volatile("" ::: "memory");
#pragma unroll
    for (int ks = 0; ks < 2; ++ks) {
      bfx8 af[4], bf[4];
#pragma unroll
      for (int mi = 0; mi < 4; ++mi) {
        const int m = wm + mi * 16 + qi;
        const int sl = g ^ ((m >> 1) & 3);
        af[mi] = *(const bfx8*)(&As[cur][ks * 4096 + m * 32 + sl * 8]);
      }
#pragma unroll
      for (int ni = 0; ni < 4; ++ni) {
        const int n = wn + ni * 16 + qi;
        const int sl = g ^ ((n >> 1) & 3);
        bf[ni] = *(const bfx8*)(&Bs[cur][ks * 4096 + n * 32 + sl * 8]);
      }
#pragma unroll
      for (int mi = 0; mi < 4; ++mi)
#pragma unroll
        for (int ni = 0; ni < 4; ++ni)
          acc[mi][ni] = MFMA16(af[mi], bf[ni], acc[mi][ni]);
    }
    asm volatile("s_waitcnt lgkmcnt(0)" ::: "memory");
    __builtin_amdgcn_s_barrier();
    asm volatile("" ::: "memory");
    if (t + 2 < nt) stage(t + 2, cur);
  }

#pragma unroll
  for (int mi = 0; mi < 4; ++mi) {
#pragma unroll
    for (int ni = 0; ni < 4; ++ni) {
      const int col = col0 + wn + ni * 16 + qi;
      if (outMode == 5 && col >= 2304) {
        const int vcol = col - 2304;
        const int rowb = row0 + wm + mi * 16 + g * 4;
        if (rowb < Mpb) {
          bfx4 ov;
#pragma unroll
          for (int r = 0; r < 4; ++r) ov[r] = (__bf16)acc[mi][ni][r];
          *(bfx4*)((__bf16*)C2 + (size_t)b * (256 * 816) + (size_t)vcol * 816 + rowb) = ov;
        }
        continue;
      }
#pragma unroll
      for (int r = 0; r < 4; ++r) {
        const int row = row0 + wm + mi * 16 + g * 4 + r;
        if (row >= Mpb) continue;
        const float v = acc[mi][ni][r];
        if (outMode == 0) {
          ((float*)C)[(size_t)b * strideC + (size_t)row * ldc + col] = v;
        } else if (outMode == 1 || outMode == 5) {
          ((__bf16*)C)[(size_t)b * strideC + (size_t)row * ldc + col] = (__bf16)v;
        } else {  // mode 2
          const size_t ix = (size_t)b * strideC + (size_t)row * ldc + col;
          ((float*)C)[ix] = v + ((const float*)Extra)[ix];
        }
      }
    }
  }
  (void)ldct;
}

// ---------------- Fused GEGLU dual-GEMM (128-tile, small-M path) ----------------
__global__ __launch_bounds__(256, 2)
void ffn_dual(const __bf16* __restrict__ A, const __bf16* __restrict__ Wg,
              const __bf16* __restrict__ Wa, __bf16* __restrict__ C,
              int Mpb, int lda, int strideA, int Kd,
              int ldc, int strideC, int mbPerBatch) {
  __shared__ __align__(16) __bf16 As[2][8192];
  __shared__ __align__(16) __bf16 Bs[2][8192];
  const int tid = threadIdx.x;
  const int lane = tid & 63;
  const int wid = tid >> 6;
  const int b = blockIdx.x / mbPerBatch;
  const int row0 = (blockIdx.x % mbPerBatch) * 128;
  const int col0 = blockIdx.y * 128;
  const __bf16* Ab = A + (size_t)b * strideA;
  const size_t nks = (size_t)(Kd >> 5);
  const int wm = (wid >> 1) * 64, wn = (wid & 1) * 64;
  const int qi = lane & 15, g = lane >> 4;

  const int m0 = tid >> 2, p0 = tid & 3;
  const int lg0 = p0 ^ ((m0 >> 1) & 3);
  const int m1 = m0 + 64;
  const int lg1 = p0 ^ ((m1 >> 1) & 3);
  int mr0 = row0 + m0; if (mr0 >= Mpb) mr0 = Mpb - 1;
  int mr1 = row0 + m1; if (mr1 >= Mpb) mr1 = Mpb - 1;
  const __bf16* asrc0 = Ab + (size_t)mr0 * lda + lg0 * 8;
  const __bf16* asrc1 = Ab + (size_t)mr1 * lda + lg1 * 8;
  const int nt = Kd >> 6;

  f32x4 gval[4][4];
  f32x4 acc[4][4];

#pragma unroll
  for (int pan = 0; pan < 2; ++pan) {
    const __bf16* Bpan0 = (pan ? Wa : Wg) + ((size_t)(col0 >> 7)) * nks * 4096;

    auto stage = [&](int t, int bufi) {
      const int k0 = t * 64;
      gl_lds16(asrc0 + k0, &As[bufi][tid * 8]);
      gl_lds16(asrc1 + k0, &As[bufi][(tid + 256) * 8]);
      gl_lds16(asrc0 + k0 + 32, &As[bufi][4096 + tid * 8]);
      gl_lds16(asrc1 + k0 + 32, &As[bufi][4096 + (tid + 256) * 8]);
      const __bf16* pb = Bpan0 + (size_t)(k0 >> 5) * 4096;
      gl_lds16(pb + tid * 8, &Bs[bufi][tid * 8]);
      gl_lds16(pb + (tid + 256) * 8, &Bs[bufi][(tid + 256) * 8]);
      gl_lds16(pb + 4096 + tid * 8, &Bs[bufi][4096 + tid * 8]);
      gl_lds16(pb + 4096 + (tid + 256) * 8, &Bs[bufi][4096 + (tid + 256) * 8]);
    };

#pragma unroll
    for (int i = 0; i < 4; ++i)
#pragma unroll
      for (int j = 0; j < 4; ++j) acc[i][j] = f32x4{0.f, 0.f, 0.f, 0.f};

    stage(0, 0);
    if (nt > 1) stage(1, 1);

    for (int t = 0; t < nt; ++t) {
      const int cur = t & 1;
      if (t + 1 < nt) asm volatile("s_waitcnt vmcnt(8)" ::: "memory");
      else            asm volatile("s_waitcnt vmcnt(0)" ::: "memory");
      __builtin_amdgcn_s_barrier();
      asm volatile("" ::: "memory");
#pragma unroll
      for (int ks = 0; ks < 2; ++ks) {
        bfx8 af[4], bf[4];
#pragma unroll
        for (int mi = 0; mi < 4; ++mi) {
          const int m = wm + mi * 16 + qi;
          const int sl = g ^ ((m >> 1) & 3);
          af[mi] = *(const bfx8*)(&As[cur][ks * 4096 + m * 32 + sl * 8]);
        }
#pragma unroll
        for (int ni = 0; ni < 4; ++ni) {
          const int n = wn + ni * 16 + qi;
          const int sl = g ^ ((n >> 1) & 3);
          bf[ni] = *(const bfx8*)(&Bs[cur][ks * 4096 + n * 32 + sl * 8]);
        }
#pragma unroll
        for (int mi = 0; mi < 4; ++mi)
#pragma unroll
          for (int ni = 0; ni < 4; ++ni)
            acc[mi][ni] = MFMA16(af[mi], bf[ni], acc[mi][ni]);
      }
      asm volatile("s_waitcnt lgkmcnt(0)" ::: "memory");
      __builtin_amdgcn_s_barrier();
      asm volatile("" ::: "memory");
      if (t + 2 < nt) stage(t + 2, cur);
    }

    if (pan == 0) {
#pragma unroll
      for (int i = 0; i < 4; ++i)
#pragma unroll
        for (int j = 0; j < 4; ++j)
#pragma unroll
          for (int r = 0; r < 4; ++r) gval[i][j][r] = gelu_tanh_f(acc[i][j][r]);
    }
  }

#pragma unroll
  for (int mi = 0; mi < 4; ++mi) {
#pragma unroll
    for (int ni = 0; ni < 4; ++ni) {
      const int col = col0 + wn + ni * 16 + qi;
#pragma unroll
      for (int r = 0; r < 4; ++r) {
        const int row = row0 + wm + mi * 16 + g * 4 + r;
        if (row >= Mpb) continue;
        C[(size_t)b * strideC + (size_t)row * ldc + col] =
            (__bf16)(gval[mi][ni][r] * acc[mi][ni][r]);
      }
    }
  }
}

// ---------------- Old GEMM (f32 weights on the fly) — legacy fallback ----------------
__global__ __launch_bounds__(256, 2)
void gemm_kernel(const __bf16* __restrict__ A, const float* __restrict__ Bw,
                 void* __restrict__ C, const void* __restrict__ Extra,
                 int Mpb, int lda, int strideA,
                 int ldb, int headDim, int Kd,
                 int ldc, int strideC, int mbPerBatch,
                 int outMode, int ldct) {
  __shared__ __align__(16) __bf16 As[128 * 32];
  __shared__ __align__(16) __bf16 Bs[128 * 32];
  const int tid = threadIdx.x;
  const int lane = tid & 63;
  const int wid = tid >> 6;
  const int b = blockIdx.x / mbPerBatch;
  const int row0 = (blockIdx.x % mbPerBatch) * 128;
  const int col0 = blockIdx.y * 128;
  const __bf16* Ab = A + (size_t)b * strideA;
  const float* Bb = (headDim > 0)
      ? (Bw + (size_t)(col0 / headDim) * (size_t)Kd * headDim + (col0 % headDim))
      : (Bw + col0);
  const int wm = (wid >> 1) * 64, wn = (wid & 1) * 64;
  const int qi = lane & 15, g = lane >> 4;

  f32x4 acc[4][4];
#pragma unroll
  for (int i = 0; i < 4; ++i)
#pragma unroll
    for (int j = 0; j < 4; ++j) acc[i][j] = f32x4{0.f, 0.f, 0.f, 0.f};

  const int am = tid >> 2, ap = tid & 3;
  const int bn = tid >> 2, bc = tid & 3;

  for (int k0 = 0; k0 < Kd; k0 += 32) {
    __syncthreads();
#pragma unroll
    for (int s = 0; s < 2; ++s) {
      const int m = am + s * 64;
      int mr = row0 + m;
      if (mr >= Mpb) mr = Mpb - 1;
      const int lg = ap ^ ((m >> 1) & 3);
      bfx8 v = *(const bfx8*)(Ab + (size_t)mr * lda + k0 + lg * 8);
      *(bfx8*)(&As[m * 32 + ap * 8]) = v;
    }
#pragma unroll
    for (int s = 0; s < 2; ++s) {
      const int n = bn + s * 64;
      const float* bp = Bb + (size_t)(k0 + bc * 8) * ldb + n;
      bfx8 v;
#pragma unroll
      for (int i = 0; i < 8; ++i) v[i] = (__bf16)bp[(size_t)i * ldb];
      const int p = bc ^ ((n >> 1) & 3);
      *(bfx8*)(&Bs[n * 32 + p * 8]) = v;
    }
    __syncthreads();
    bfx8 af[4], bf[4];
#pragma unroll
    for (int mi = 0; mi < 4; ++mi) {
      const int m = wm + mi * 16 + qi;
      const int sl = g ^ ((m >> 1) & 3);
      af[mi] = *(const bfx8*)(&As[m * 32 + sl * 8]);
    }
#pragma unroll
    for (int ni = 0; ni < 4; ++ni) {
      const int n = wn + ni * 16 + qi;
      const int sl = g ^ ((n >> 1) & 3);
      bf[ni] = *(const bfx8*)(&Bs[n * 32 + sl * 8]);
    }
#pragma unroll
    for (int mi = 0; mi < 4; ++mi)
#pragma unroll
      for (int ni = 0; ni < 4; ++ni)
        acc[mi][ni] = MFMA16(af[mi], bf[ni], acc[mi][ni]);
  }

#pragma unroll
  for (int mi = 0; mi < 4; ++mi) {
#pragma unroll
    for (int ni = 0; ni < 4; ++ni) {
      const int col = col0 + wn + ni * 16 + qi;
#pragma unroll
      for (int r = 0; r < 4; ++r) {
        const int row = row0 + wm + mi * 16 + g * 4 + r;
        if (row >= Mpb) continue;
        const float v = acc[mi][ni][r];
        if (outMode == 0) {
          ((float*)C)[(size_t)b * strideC + (size_t)row * ldc + col] = v;
        } else if (outMode == 1) {
          ((__bf16*)C)[(size_t)b * strideC + (size_t)row * ldc + col] = (__bf16)v;
        } else if (outMode == 2) {
          const size_t ix = (size_t)b * strideC + (size_t)row * ldc + col;
          ((float*)C)[ix] = v + ((const float*)Extra)[ix];
        } else if (outMode == 3) {
          ((__bf16*)C)[(size_t)b * strideC + (size_t)col * ldct + row] = (__bf16)v;
        } else {
          const size_t ix = (size_t)b * strideC + (size_t)row * ldc + col;
          const float gt = (float)((const __bf16*)Extra)[ix];
          ((__bf16*)C)[ix] = (__bf16)(gelu_tanh_f(gt) * v);
        }
      }
    }
  }
}

// ---------------- Fused attention (q/k strides parameterized) ----------------
__global__ __launch_bounds__(256, 2)
void attn_kernel(const __bf16* __restrict__ qp, const __bf16* __restrict__ kp0,
                 const __bf16* __restrict__ vt, __bf16* __restrict__ ao,
                 int qstride, int kstride) {
  __shared__ __align__(16) __bf16 Ps[4][1024];
  __shared__ float denw[4][16];
  const int tid = threadIdx.x, lane = tid & 63, wid = tid >> 6;
  const int qt = blockIdx.x, hn = blockIdx.y, b = blockIdx.z;
  const int q0 = qt * 64;
  const int qi = lane & 15, g = lane >> 4;

  int qrow = q0 + wid * 16 + qi;
  if (qrow > 815) qrow = 815;
  const int cmq = (qrow >= 768) + (qrow >= 771);
  const __bf16* qrp = qp + (size_t)(b * 816 + qrow) * qstride + hn * 256 + g * 8;
  bfx8 qf[8];
#pragma unroll
  for (int kf = 0; kf < 8; ++kf) qf[kf] = *(const bfx8*)(qrp + kf * 32);

  f32x4 oacc[16];
#pragma unroll
  for (int i = 0; i < 16; ++i) oacc[i] = f32x4{0.f, 0.f, 0.f, 0.f};
  float den = 0.f;

  const int ntiles = (q0 + 63 < 768) ? 12 : 13;
  for (int t = 0; t < ntiles; ++t) {
    const int kv0 = t * 64;
#pragma unroll
    for (int mi = 0; mi < 4; ++mi) {
      f32x4 sac = f32x4{0.f, 0.f, 0.f, 0.f};
      int srow = kv0 + mi * 16 + qi;
      if (srow > 815) srow = 815;
      const __bf16* kp = kp0 + (size_t)(b * 816 + srow) * kstride + g * 8;
#pragma unroll
      for (int kf = 0; kf < 8; ++kf) {
        bfx8 a = *(const bfx8*)(kp + kf * 32);
        sac = MFMA16(a, qf[kf], sac);
      }
      float pv[4];
#pragma unroll
      for (int r = 0; r < 4; ++r) {
        const int s = kv0 + mi * 16 + g * 4 + r;
        const float l = sac[r];
        const float e2 = __expf(l * 0.04f);
        const float capped = 50.f * (e2 - 1.f) / (e2 + 1.f);
        const int cms = (s >= 768) + (s >= 771);
        const bool ok = (s < 816) && (cms <= cmq);
        const float p = ok ? __expf(capped) : 0.f;
        den += p;
        pv[r] = p;
      }
      const unsigned lo = pack_bf2(pv[0], pv[1]);
      const unsigned hi = pack_bf2(pv[2], pv[3]);
      const int slot = 2 * mi + (g >> 1);
      const int phys = slot ^ (qi & 7);
      char* pb = (char*)&Ps[wid][0] + qi * 128 + phys * 16 + (g & 1) * 8;
      *(unsigned*)(pb) = lo;
      *(unsigned*)(pb + 4) = hi;
    }
    asm volatile("s_waitcnt lgkmcnt(0)" ::: "memory");
    bfx8 pa[2];
#pragma unroll
    for (int k2 = 0; k2 < 2; ++k2) {
      const int sl = (k2 * 4 + g) ^ (qi & 7);
      pa[k2] = *(const bfx8*)((const char*)&Ps[wid][0] + qi * 128 + sl * 16);
    }
#pragma unroll
    for (int hf = 0; hf < 16; ++hf) {
      const int h = hf * 16 + qi;
#pragma unroll
      for (int k2 = 0; k2 < 2; ++k2) {
        int s0 = kv0 + k2 * 32 + g * 8;
        if (s0 > 808) s0 = 808;
        bfx8 vb = *(const bfx8*)(vt + ((size_t)(b * 256 + h)) * 816 + s0);
        oacc[hf] = MFMA16(pa[k2], vb, oacc[hf]);
      }
    }
    asm volatile("s_waitcnt lgkmcnt(0)" ::: "memory");
  }

  den += __shfl_xor(den, 16, 64);
  den += __shfl_xor(den, 32, 64);
  if (lane < 16) denw[wid][qi] = den;
  asm volatile("s_waitcnt lgkmcnt(0)" ::: "memory");
#pragma unroll
  for (int r = 0; r < 4; ++r) {
    const int qg = q0 + wid * 16 + g * 4 + r;
    if (qg >= 816) continue;
    const float di = 1.f / denw[wid][g * 4 + r];
#pragma unroll
    for (int hf = 0; hf < 16; ++hf) {
      ao[((size_t)(b * 816 + qg)) * 2048 + hn * 256 + hf * 16 + qi] =
          (__bf16)(oacc[hf][r] * di);
    }
  }
}

// ---------------- Host orchestration ----------------
extern "C" void kernel_launch(void* const* d_in, const int* in_sizes, int n_in,
                              void* d_out, int out_size, void* d_ws, size_t ws_size,
                              hipStream_t stream) {
  (void)in_sizes; (void)n_in; (void)out_size;
  const float* x      = (const float*)d_in[0];
  const int*   pos    = (const int*)d_in[1];
  const float* s_attn = (const float*)d_in[4];
  const float* s_ffw  = (const float*)d_in[5];
  const float* gq     = (const float*)d_in[6];
  const float* gkv    = (const float*)d_in[7];
  const float* go     = (const float*)d_in[8];
  const float* aq     = (const float*)d_in[9];
  const float* akv    = (const float*)d_in[10];
  const float* aow    = (const float*)d_in[11];
  const float* gg     = (const float*)d_in[12];
  const float* gl     = (const float*)d_in[13];
  const float* ag     = (const float*)d_in[14];
  const float* al     = (const float*)d_in[15];
  float* outp = (float*)d_out;
  char* ws = (char*)d_ws;
  dim3 blk(256);

  const size_t NEED_BATCH = 577437696u;
  const size_t NEED_FAST  = 423297024u;

  if (ws_size >= NEED_FAST) {
    const bool batched = (ws_size >= NEED_BATCH);
    // weights (tile-panel bf16); QKV fused: [Q 16 panels][K 2][V 2] contiguous
    __bf16* wQKVg = (__bf16*)(ws + 0);          // 20 panels x 64ks x 4096
    __bf16* wQKVa = (__bf16*)(ws + 10485760);
    __bf16* goT = (__bf16*)(ws + 20971520);
    __bf16* aoT = (__bf16*)(ws + 29360128);
    __bf16* ggT = (__bf16*)(ws + 37748736);     // [2] x [16384 x 2048]
    __bf16* glT = (__bf16*)(ws + 171966464);    // [2048 x 16384]
    __bf16* agT = (__bf16*)(ws + 239075328);    // [2] x [4096 x 2048]
    __bf16* alT = (__bf16*)(ws + 272629760);    // [2048 x 4096]
    // activations
    __bf16* xn   = (__bf16*)(ws + 289406976);   // [3264][2048]
    __bf16* qkb  = (__bf16*)(ws + 302776320);   // [3264][2304]  Q cols 0-2047, K 2048-2303
    __bf16* vt   = (__bf16*)(ws + 317816832);   // [4][256][816]
    __bf16* aob  = (__bf16*)(ws + 319488000);   // [3264][2048]
    float*  ob   = (float*)(ws + 332857344);    // [3264][2048] f32
    __bf16* hb   = (__bf16*)(ws + 359596032);   // [3264][2048]
    __bf16* gate  = (__bf16*)(ws + 372965376);  // per-batch scratch
    __bf16* act   = (__bf16*)(ws + 398131200);  // per-batch [768][16384]
    __bf16* act4  = (__bf16*)(ws + 473628672);  // batched [4][768][16384]
    __bf16* actA4 = (__bf16*)(ws + 575864832);  // batched [4][48][4096]

    // weight conversion (f32 [K][N] -> bf16 panel)
    convw_kernel<<<dim3(32, 32), blk, 0, stream>>>(gq, wQKVg, 2048, 256);
    convw_kernel<<<dim3(4, 32), blk, 0, stream>>>(gkv, wQKVg + 16 * 64 * 4096, 2048, 256);
    convw_kernel<<<dim3(4, 32), blk, 0, stream>>>(gkv + 2048 * 256, wQKVg + 18 * 64 * 4096, 2048, 256);
    convw_kernel<<<dim3(32, 32), blk, 0, stream>>>(aq, wQKVa, 2048, 256);
    convw_kernel<<<dim3(4, 32), blk, 0, stream>>>(akv, wQKVa + 16 * 64 * 4096, 2048, 256);
    convw_kernel<<<dim3(4, 32), blk, 0, stream>>>(akv + 2048 * 256, wQKVa + 18 * 64 * 4096, 2048, 256);
    convw_kernel<<<dim3(32, 32), blk, 0, stream>>>(go, goT, 2048, 2048);
    convw_kernel<<<dim3(32, 32), blk, 0, stream>>>(aow, aoT, 2048, 2048);
    convw_kernel<<<dim3(256, 32), blk, 0, stream>>>(gg, ggT, 2048, 16384);
    convw_kernel<<<dim3(256, 32), blk, 0, stream>>>(gg + (size_t)2048 * 16384, ggT + (size_t)16384 * 2048, 2048, 16384);
    convw_kernel<<<dim3(32, 256), blk, 0, stream>>>(gl, glT, 16384, 2048);
    convw_kernel<<<dim3(64, 32), blk, 0, stream>>>(ag, agT, 2048, 4096);
    convw_kernel<<<dim3(64, 32), blk, 0, stream>>>(ag + (size_t)2048 * 4096, agT + (size_t)4096 * 2048, 2048, 4096);
    convw_kernel<<<dim3(32, 64), blk, 0, stream>>>(al, alT, 4096, 2048);

    // 1. pre-attention rmsnorm
    rmsnorm_kernel<<<3264, blk, 0, stream>>>(x, nullptr, s_attn, xn);

    // 2. fused QKV projection, gemma+action merged (row-block 3 = action weights)
    gemm256<<<dim3(16, 20), dim3(512), 0, stream>>>(xn, wQKVg, wQKVa, qkb, vt, nullptr,
        816, 2048, 816 * 2048, 2048, 2304, 816 * 2304, 4, 5, nullptr, 0, 0, 0);

    // 3. RoPE in place, Q+K in one launch (heads 0-7 scaled by H^-0.5, head 8 = K unscaled)
    rope_bf_kernel<<<3264, blk, 0, stream>>>(qkb, pos, 9, 2304, 8, 0.0625f);

    // 4. attention
    attn_kernel<<<dim3(13, 8, 4), blk, 0, stream>>>(qkb, qkb + 2048, vt, aob, 2304, 2304);

    // 5. output projection, gemma+action merged
    gemm256<<<dim3(16, 16), dim3(512), 0, stream>>>(aob, goT, aoT, ob, nullptr, nullptr,
        816, 2048, 816 * 2048, 2048, 2048, 816 * 2048, 4, 0, nullptr, 0, 0, 0);

    // 6. pre-FFW rmsnorm of (o + x)
    rmsnorm_kernel<<<3264, blk, 0, stream>>>(ob, x, s_ffw, hb);

    // 7. FFN: gemma gate+act dual GEMM; action gate (small); down-proj merged g+a
    if (batched) {
      ffn_dual256<<<dim3(12, 128), dim3(512), 0, stream>>>(hb, ggT, ggT + (size_t)16384 * 2048, act4,
          768, 2048, 816 * 2048, 2048, 16384, 768 * 16384, 3);
      ffn_dual<<<dim3(4, 32), blk, 0, stream>>>(hb + 768 * 2048, agT, agT + (size_t)4096 * 2048, actA4,
          48, 2048, 816 * 2048, 2048, 4096, 48 * 4096, 1);
      // merged down-proj: row-blocks 0-2 = gemma (act4, glT, K=16384),
      // row-block 3 = action (actA4, alT, K=4096); epilogue residual indexing identical.
      gemm256<<<dim3(16, 16), dim3(512), 0, stream>>>(act4, glT, alT, outp, nullptr, x,
          816, 16384, 768 * 16384, 16384, 2048, 816 * 2048, 4, 2,
          actA4, 4096, 48 * 4096, 4096);
    } else {
      for (int bb = 0; bb < 4; ++bb) {
        const __bf16* hg = hb + (size_t)bb * 816 * 2048;
        float* og = outp + (size_t)bb * 816 * 2048;
        const float* xg = x + (size_t)bb * 816 * 2048;
        ffn_dual<<<dim3(6, 128), blk, 0, stream>>>(hg, ggT, ggT + (size_t)16384 * 2048, act,
            768, 2048, 0, 2048, 16384, 0, 6);
        gemm_bt2<<<dim3(6, 16), blk, 0, stream>>>(act, glT, og, nullptr, xg,
            768, 16384, 0, 16384, 2048, 0, 6, 2, 0);
        const __bf16* ha = hg + 768 * 2048;
        ffn_dual<<<dim3(1, 32), blk, 0, stream>>>(ha, agT, agT + (size_t)4096 * 2048, gate,
            48, 2048, 0, 2048, 4096, 0, 1);
        gemm_bt2<<<dim3(1, 16), blk, 0, stream>>>(gate, alT, og + 768 * 2048, nullptr, xg + 768 * 2048,
            48, 4096, 0, 4096, 2048, 0, 1, 2, 0);
      }
    }
    return;
  }

  // ---- legacy fallback path (round-0, on-the-fly f32 weights) ----
  if (ws_size < 164000000u) return;
  __bf16* xn   = (__bf16*)(ws + 0);
  float*  qf   = (float*)(ws + 13369344);
  __bf16* qbb  = (__bf16*)(ws + 40108032);
  float*  kf   = (float*)(ws + 53477376);
  __bf16* kbb  = (__bf16*)(ws + 56819712);
  __bf16* vt   = (__bf16*)(ws + 58490880);
  __bf16* aob  = (__bf16*)(ws + 60162048);
  float*  ob   = (float*)(ws + 73531392);
  __bf16* hb   = (__bf16*)(ws + 100270080);
  __bf16* gate = (__bf16*)(ws + 113639424);
  __bf16* act  = (__bf16*)(ws + 138805248);

  rmsnorm_kernel<<<3264, blk, 0, stream>>>(x, nullptr, s_attn, xn);
  gemm_kernel<<<dim3(24, 16), blk, 0, stream>>>(xn, gq, qf, nullptr,
      768, 2048, 816 * 2048, 256, 256, 2048, 2048, 816 * 2048, 6, 0, 0);
  gemm_kernel<<<dim3(4, 16), blk, 0, stream>>>(xn + 768 * 2048, aq, qf + 768 * 2048, nullptr,
      48, 2048, 816 * 2048, 256, 256, 2048, 2048, 816 * 2048, 1, 0, 0);
  gemm_kernel<<<dim3(24, 2), blk, 0, stream>>>(xn, gkv, kf, nullptr,
      768, 2048, 816 * 2048, 256, 256, 2048, 256, 816 * 256, 6, 0, 0);
  gemm_kernel<<<dim3(4, 2), blk, 0, stream>>>(xn + 768 * 2048, akv, kf + 768 * 256, nullptr,
      48, 2048, 816 * 2048, 256, 256, 2048, 256, 816 * 256, 1, 0, 0);
  gemm_kernel<<<dim3(24, 2), blk, 0, stream>>>(xn, gkv + 2048 * 256, vt, nullptr,
      768, 2048, 816 * 2048, 256, 256, 2048, 0, 256 * 816, 6, 3, 816);
  gemm_kernel<<<dim3(4, 2), blk, 0, stream>>>(xn + 768 * 2048, akv + 2048 * 256, vt + 768, nullptr,
      48, 2048, 816 * 2048, 256, 256, 2048, 0, 256 * 816, 1, 3, 816);
  rope_kernel<<<3264, blk, 0, stream>>>(qf, pos, qbb, 8, 0.0625f);
  rope_kernel<<<3264, blk, 0, stream>>>(kf, pos, kbb, 1, 1.0f);
  attn_kernel<<<dim3(13, 8, 4), blk, 0, stream>>>(qbb, kbb, vt, aob, 2048, 256);
  gemm_kernel<<<dim3(24, 16), blk, 0, stream>>>(aob, go, ob, nullptr,
      768, 2048, 816 * 2048, 2048, 0, 2048, 2048, 816 * 2048, 6, 0, 0);
  gemm_kernel<<<dim3(4, 16), blk, 0, stream>>>(aob + 768 * 2048, aow, ob + 768 * 2048, nullptr,
      48, 2048, 816 * 2048, 2048, 0, 2048, 2048, 816 * 2048, 1, 0, 0);
  rmsnorm_kernel<<<3264, blk, 0, stream>>>(ob, x, s_ffw, hb);
  for (int bb = 0; bb < 4; ++bb) {
    const __bf16* hg = hb + (size_t)bb * 816 * 2048;
    float* og = outp + (size_t)bb * 816 * 2048;
    const float* xg = x + (size_t)bb * 816 * 2048;
    gemm_kernel<<<dim3(6, 128), blk, 0, stream>>>(hg, gg, gate, nullptr,
        768, 2048, 0, 16384, 0, 2048, 16384, 0, 6, 1, 0);
    gemm_kernel<<<dim3(6, 128), blk, 0, stream>>>(hg, gg + 2048 * 16384, act, gate,
        768, 2048, 0, 16384, 0, 2048, 16384, 0, 6, 4, 0);
    gemm_kernel<<<dim3(6, 16), blk, 0, stream>>>(act, gl, og, xg,
        768, 16384, 0, 2048, 0, 16384, 2048, 0, 6, 2, 0);
    const __bf16* ha = hg + 768 * 2048;
    gemm_kernel<<<dim3(1, 32), blk, 0, stream>>>(ha, ag, gate, nullptr,
        48, 2048, 0, 4096, 0, 2048, 4096, 0, 1, 1, 0);
    gemm_kernel<<<dim3(1, 32), blk, 0, stream>>>(ha, ag + 2048 * 4096, act, gate,
        48, 2048, 0, 4096, 0, 2048, 4096, 0, 1, 4, 0);
    gemm_kernel<<<dim3(1, 16), blk, 0, stream>>>(act, al, og + 768 * 2048, xg + 768 * 2048,
        48, 4096, 0, 2048, 0, 4096, 2048, 0, 1, 2, 0);
  }
}

// Round 18
// 1255.953 us; speedup vs baseline: 1.2370x; 1.0016x over previous
//
#include <hip/hip_runtime.h>
#include <hip/hip_bf16.h>

typedef __bf16 bfx8 __attribute__((ext_vector_type(8)));
typedef __bf16 bfx4 __attribute__((ext_vector_type(4)));
typedef float f32x4 __attribute__((ext_vector_type(4)));

#define MFMA16(a, b, c) __builtin_amdgcn_mfma_f32_16x16x32_bf16((a), (b), (c), 0, 0, 0)

__device__ __forceinline__ void gl_lds16(const __bf16* g, __bf16* l) {
  __builtin_amdgcn_global_load_lds(
      (const __attribute__((address_space(1))) unsigned int*)(const void*)g,
      (__attribute__((address_space(3))) unsigned int*)(void*)l, 16, 0, 0);
}

__device__ __forceinline__ unsigned pack_bf2(float a, float b) {
  unsigned short ua = __builtin_bit_cast(unsigned short, (__bf16)a);
  unsigned short ub = __builtin_bit_cast(unsigned short, (__bf16)b);
  return (unsigned)ua | ((unsigned)ub << 16);
}

__device__ __forceinline__ float gelu_tanh_f(float x) {
  float u = 0.7978845608028654f * (x + 0.044715f * x * x * x);
  float t;
  if (u > 10.f) t = 1.f;
  else if (u < -10.f) t = -1.f;
  else { float e = __expf(2.f * u); t = (e - 1.f) / (e + 1.f); }
  return 0.5f * x * (1.f + t);
}

// ---------------- RMSNorm (optionally fused residual add) ----------------
__global__ __launch_bounds__(256)
void rmsnorm_kernel(const float* __restrict__ X, const float* __restrict__ X2,
                    const float* __restrict__ scale, __bf16* __restrict__ out) {
  __shared__ float wsum[4];
  const int row = blockIdx.x, tid = threadIdx.x;
  const size_t base = (size_t)row * 2048;
  f32x4 v[2];
  float ss = 0.f;
#pragma unroll
  for (int i = 0; i < 2; ++i) {
    const int idx = tid * 4 + i * 1024;
    v[i] = *(const f32x4*)(X + base + idx);
    if (X2) { f32x4 u = *(const f32x4*)(X2 + base + idx); v[i] = v[i] + u; }
#pragma unroll
    for (int j = 0; j < 4; ++j) ss += v[i][j] * v[i][j];
  }
#pragma unroll
  for (int o = 32; o > 0; o >>= 1) ss += __shfl_xor(ss, o, 64);
  if ((tid & 63) == 0) wsum[tid >> 6] = ss;
  __syncthreads();
  const float tot = wsum[0] + wsum[1] + wsum[2] + wsum[3];
  const float rs = rsqrtf(tot * (1.f / 2048.f) + 1e-6f);
#pragma unroll
  for (int i = 0; i < 2; ++i) {
    const int idx = tid * 4 + i * 1024;
    f32x4 sc = *(const f32x4*)(scale + idx);
    bfx4 ov;
#pragma unroll
    for (int j = 0; j < 4; ++j) ov[j] = (__bf16)(v[i][j] * rs * (1.f + sc[j]));
    *(bfx4*)(out + base + idx) = ov;
  }
}

// ---------------- RoPE in-place on bf16, per-head scale (q heads scaled, K head not) --
__global__ __launch_bounds__(256)
void rope_bf_kernel(__bf16* __restrict__ buf, const int* __restrict__ pos,
                    int nheads, int rstride, int qheads, float qscale) {
  const int row = blockIdx.x;
  const float p = (float)pos[row];
  const int total = nheads * 128;
  const size_t rbase = (size_t)row * (size_t)rstride;
  for (int idx = threadIdx.x; idx < total; idx += 256) {
    const int n = idx >> 7, i = idx & 127;
    const float outscale = (n < qheads) ? qscale : 1.0f;
    const float ts = __expf(-(float)i * 0.071955784f);  // 10000^(-i/128)
    float sn, cs;
    __sincosf(p * ts, &sn, &cs);
    __bf16* bp = buf + rbase + n * 256 + i;
    const float x1 = (float)bp[0], x2 = (float)bp[128];
    bp[0]   = (__bf16)((x1 * cs - x2 * sn) * outscale);
    bp[128] = (__bf16)((x2 * cs + x1 * sn) * outscale);
  }
}

// ---------------- RoPE f32 -> bf16 (fallback path) ----------------
__global__ __launch_bounds__(256)
void rope_kernel(const float* __restrict__ in, const int* __restrict__ pos,
                 __bf16* __restrict__ outp, int nheads, float outscale) {
  const int row = blockIdx.x;
  const float p = (float)pos[row];
  const int total = nheads * 128;
  const size_t rbase = (size_t)row * (size_t)(nheads * 256);
  for (int idx = threadIdx.x; idx < total; idx += 256) {
    const int n = idx >> 7, i = idx & 127;
    const float ts = __expf(-(float)i * 0.071955784f);
    float sn, cs;
    __sincosf(p * ts, &sn, &cs);
    const float* bp = in + rbase + n * 256 + i;
    const float x1 = bp[0], x2 = bp[128];
    __bf16* ob = outp + rbase + n * 256 + i;
    ob[0]   = (__bf16)((x1 * cs - x2 * sn) * outscale);
    ob[128] = (__bf16)((x2 * cs + x1 * sn) * outscale);
  }
}

// ---------------- Weight convert: f32 W[k][c] -> bf16 tile-panel layout ----------------
// Panel: (cp*(K/32)+ks)*4096 holds the 128x32 tile pre-swizzled in LDS-linear order:
// element (m=col&127, k): lg=(k%32)/8, p=lg^((m>>1)&3), offset = m*32 + p*8 + (k&7).
__global__ __launch_bounds__(256)
void convw_kernel(const float* __restrict__ in, __bf16* __restrict__ out,
                  int K, int headDim) {
  __shared__ __bf16 tile[64][65];
  const int tc0 = blockIdx.x * 64;
  const int tk0 = blockIdx.y * 64;
  const int tid = threadIdx.x;
  const int cchunk = tid & 15, krow = tid >> 4;
  const int c = tc0 + cchunk * 4;
  const float* colbase = in + (size_t)(c / headDim) * (size_t)K * headDim + (c % headDim);
#pragma unroll
  for (int i = 0; i < 4; ++i) {
    const int k = tk0 + krow + i * 16;
    f32x4 v = *(const f32x4*)(colbase + (size_t)k * headDim);
#pragma unroll
    for (int j = 0; j < 4; ++j) tile[cchunk * 4 + j][krow + i * 16] = (__bf16)v[j];
  }
  __syncthreads();
  const int nks = K >> 5;
#pragma unroll
  for (int s = 0; s < 2; ++s) {
    const int ch = tid + s * 256;
    const int wc = ch >> 3, wk8 = (ch & 7) * 8;
    bfx8 v;
#pragma unroll
    for (int j = 0; j < 8; ++j) v[j] = tile[wc][wk8 + j];
    const int col = tc0 + wc;
    const int kchunk = (tk0 + wk8) >> 3;
    const int cp = col >> 7, m = col & 127;
    const int ks = kchunk >> 2, lg = kchunk & 3;
    const int p = lg ^ ((m >> 1) & 3);
    *(bfx8*)(out + ((size_t)(cp * nks + ks)) * 4096 + m * 32 + p * 8) = v;
  }
}

// ---------------- 2-phase fused GEGLU dual-GEMM (256x128 tile, 512 threads) ----------
// C = gelu(A·Wg) * (A·Wa), bf16 out. XCD-chunked block swizzle.
__global__ __launch_bounds__(512, 2)
void ffn_dual256(const __bf16* __restrict__ A, const __bf16* __restrict__ Wg,
                 const __bf16* __restrict__ Wa, __bf16* __restrict__ C,
                 int Mpb, int lda, int strideA, int Kd,
                 int ldc, int strideC, int mbPerBatch) {
  __shared__ __align__(16) __bf16 As[2 * 2 * 8192];  // [buf][half][128x64]
  __shared__ __align__(16) __bf16 Bs[2 * 2 * 8192];  // [buf][pan][128x64]
  const int tid = threadIdx.x;
  const int lane = tid & 63;
  const int wid = tid >> 6;
  const int wr = wid >> 2;
  const int wc = wid & 3;
  const int qi = lane & 15, g = lane >> 4;
  // XCD-chunked swizzle (nwg divisible by 8)
  int bid = blockIdx.y * gridDim.x + blockIdx.x;
  const int nwg = gridDim.x * gridDim.y;
  if ((nwg & 7) == 0) bid = (bid & 7) * (nwg >> 3) + (bid >> 3);
  const int bx = bid % gridDim.x, by = bid / gridDim.x;
  const int b = bx / mbPerBatch;
  const int row0 = (bx % mbPerBatch) * 256;
  const int col0 = by * 128;
  const __bf16* Ab = A + (size_t)b * strideA;
  const size_t nks = (size_t)(Kd >> 5);
  const __bf16* Bgp = Wg + ((size_t)(col0 >> 7)) * nks * 4096;
  const __bf16* Bap = Wa + ((size_t)(col0 >> 7)) * nks * 4096;
  const int NT = Kd >> 6;

  const int sm = tid >> 2, sp = tid & 3;
  const int slg = sp ^ ((sm >> 1) & 3);
  int r0 = row0 + sm;       if (r0 >= Mpb) r0 = Mpb - 1;
  int r1 = row0 + 128 + sm; if (r1 >= Mpb) r1 = Mpb - 1;
  const __bf16* asrc0 = Ab + (size_t)r0 * lda + slg * 8;
  const __bf16* asrc1 = Ab + (size_t)r1 * lda + slg * 8;

  // half order per K-tile t: 0=A0, 1=Bg, 2=A1, 3=Ba
  auto stage_half = [&](int gh) {
    if (gh >= 4 * NT) return;
    const int t = gh >> 2, which = gh & 3;
    const int bufi = t & 1;
    if ((which & 1) == 0) {
      const int h = which >> 1;
      __bf16* dst = &As[bufi * 16384 + h * 8192];
      const __bf16* src = (h ? asrc1 : asrc0) + t * 64;
      gl_lds16(src, dst + tid * 8);
      gl_lds16(src + 32, dst + 4096 + tid * 8);
    } else {
      const int pan = which >> 1;
      __bf16* dst = &Bs[bufi * 16384 + pan * 8192];
      const __bf16* src = (pan ? Bap : Bgp) + (size_t)(t * 2) * 4096 + tid * 8;
      gl_lds16(src, dst + tid * 8);
      gl_lds16(src + 4096, dst + 4096 + tid * 8);
    }
  };

  f32x4 acc[2][2][4][2];
#pragma unroll
  for (int a0 = 0; a0 < 2; ++a0)
#pragma unroll
    for (int a1 = 0; a1 < 2; ++a1)
#pragma unroll
      for (int a2 = 0; a2 < 4; ++a2)
#pragma unroll
        for (int a3 = 0; a3 < 2; ++a3) acc[a0][a1][a2][a3] = f32x4{0.f, 0.f, 0.f, 0.f};

  for (int gh = 0; gh < 6; ++gh) stage_half(gh);
  asm volatile("s_waitcnt vmcnt(4)" ::: "memory");
  __builtin_amdgcn_s_barrier();
  asm volatile("" ::: "memory");

  for (int t = 0; t < NT; ++t) {
    const int cb = (t & 1) * 16384;
    bfx8 af[4][2], bf[2][2][2];

    // ---- PHASE 0: A-half 0, both panels ----
#pragma unroll
    for (int mi = 0; mi < 4; ++mi) {
      const int m = wr * 64 + mi * 16 + qi;
      const int sl = g ^ ((m >> 1) & 3);
      const int ba = cb + m * 32 + sl * 8;
      af[mi][0] = *(const bfx8*)(&As[ba]);
      af[mi][1] = *(const bfx8*)(&As[ba + 4096]);
    }
#pragma unroll
    for (int pan = 0; pan < 2; ++pan)
#pragma unroll
      for (int ni = 0; ni < 2; ++ni) {
        const int m = wc * 32 + ni * 16 + qi;
        const int sl = g ^ ((m >> 1) & 3);
        const int bb = cb + pan * 8192 + m * 32 + sl * 8;
        bf[pan][ni][0] = *(const bfx8*)(&Bs[bb]);
        bf[pan][ni][1] = *(const bfx8*)(&Bs[bb + 4096]);
      }
    stage_half(4 * t + 6);
    stage_half(4 * t + 7);
    __builtin_amdgcn_s_barrier();
    asm volatile("s_waitcnt lgkmcnt(0)" ::: "memory");
    __builtin_amdgcn_sched_barrier(0);
    __builtin_amdgcn_s_setprio(1);
#pragma unroll
    for (int pan = 0; pan < 2; ++pan)
#pragma unroll
      for (int mi = 0; mi < 4; ++mi)
#pragma unroll
        for (int ni = 0; ni < 2; ++ni) {
          acc[0][pan][mi][ni] = MFMA16(af[mi][0], bf[pan][ni][0], acc[0][pan][mi][ni]);
          acc[0][pan][mi][ni] = MFMA16(af[mi][1], bf[pan][ni][1], acc[0][pan][mi][ni]);
        }
    __builtin_amdgcn_s_setprio(0);
    __builtin_amdgcn_s_barrier();
    asm volatile("" ::: "memory");

    // ---- PHASE 1: A-half 1, reuse bf ----
#pragma unroll
    for (int mi = 0; mi < 4; ++mi) {
      const int m = wr * 64 + mi * 16 + qi;
      const int sl = g ^ ((m >> 1) & 3);
      const int ba = cb + 8192 + m * 32 + sl * 8;
      af[mi][0] = *(const bfx8*)(&As[ba]);
      af[mi][1] = *(const bfx8*)(&As[ba + 4096]);
    }
    stage_half(4 * t + 8);
    stage_half(4 * t + 9);
    if (t + 2 < NT) asm volatile("s_waitcnt vmcnt(4)" ::: "memory");
    else            asm volatile("s_waitcnt vmcnt(0)" ::: "memory");
    __builtin_amdgcn_s_barrier();
    asm volatile("s_waitcnt lgkmcnt(0)" ::: "memory");
    __builtin_amdgcn_sched_barrier(0);
    __builtin_amdgcn_s_setprio(1);
#pragma unroll
    for (int pan = 0; pan < 2; ++pan)
#pragma unroll
      for (int mi = 0; mi < 4; ++mi)
#pragma unroll
        for (int ni = 0; ni < 2; ++ni) {
          acc[1][pan][mi][ni] = MFMA16(af[mi][0], bf[pan][ni][0], acc[1][pan][mi][ni]);
          acc[1][pan][mi][ni] = MFMA16(af[mi][1], bf[pan][ni][1], acc[1][pan][mi][ni]);
        }
    __builtin_amdgcn_s_setprio(0);
    __builtin_amdgcn_s_barrier();
    asm volatile("" ::: "memory");
  }

#pragma unroll
  for (int mh = 0; mh < 2; ++mh)
#pragma unroll
    for (int mi = 0; mi < 4; ++mi)
#pragma unroll
      for (int ni = 0; ni < 2; ++ni) {
        const int col = col0 + wc * 32 + ni * 16 + qi;
#pragma unroll
        for (int r = 0; r < 4; ++r) {
          const int row = row0 + mh * 128 + wr * 64 + mi * 16 + g * 4 + r;
          if (row >= Mpb) continue;
          C[(size_t)b * strideC + (size_t)row * ldc + col] =
              (__bf16)(gelu_tanh_f(acc[mh][0][mi][ni][r]) * acc[mh][1][mi][ni][r]);
        }
      }
}

// ---------------- 2-phase single GEMM (256x128 tile, 512 threads) ----------------
// C[b,row,col] = sum_k A[b,row,k]*W[k,col]. outMode: 0 f32, 2 f32+Extra residual,
// 5 QKV scatter (col<2304 bf16; col>=2304 V transposed into C2).
// Row-blocks with row0==768 (action segment): if BtA != nullptr use BtA weights; if
// AA != nullptr additionally switch the A-source to AA (ldaA/strideAA/KdA, local rows).
__global__ __launch_bounds__(512, 2)
void gemm256(const __bf16* __restrict__ A, const __bf16* __restrict__ Bt,
             const __bf16* __restrict__ BtA,
             void* __restrict__ C, void* __restrict__ C2, const void* __restrict__ Extra,
             int Mpb, int lda, int strideA, int Kd,
             int ldc, int strideC, int mbPerBatch, int outMode,
             const __bf16* __restrict__ AA, int ldaA, int strideAA, int KdA) {
  __shared__ __align__(16) __bf16 As[2 * 2 * 8192];  // [buf][half][128x64]
  __shared__ __align__(16) __bf16 Bs[2 * 8192];      // [buf][128x64]
  const int tid = threadIdx.x;
  const int lane = tid & 63;
  const int wid = tid >> 6;
  const int wr = wid >> 2;
  const int wc = wid & 3;
  const int qi = lane & 15, g = lane >> 4;
  int bid = blockIdx.y * gridDim.x + blockIdx.x;
  const int nwg = gridDim.x * gridDim.y;
  if ((nwg & 7) == 0) bid = (bid & 7) * (nwg >> 3) + (bid >> 3);
  const int bx = bid % gridDim.x, by = bid / gridDim.x;
  const int b = bx / mbPerBatch;
  const int row0 = (bx % mbPerBatch) * 256;
  const int col0 = by * 128;
  const bool act = (row0 == 768) && (BtA != nullptr || AA != nullptr);
  const bool actA = act && (AA != nullptr);
  const __bf16* Abase = actA ? AA : A;
  const int ldaU = actA ? ldaA : lda;
  const size_t strU = actA ? (size_t)strideAA : (size_t)strideA;
  const int KdU = actA ? KdA : Kd;
  const int rbase = actA ? 768 : 0;
  const __bf16* Ab = Abase + (size_t)b * strU;
  const size_t nks = (size_t)(KdU >> 5);
  const __bf16* Wsel = (act && BtA != nullptr) ? BtA : Bt;
  const __bf16* Bp = Wsel + ((size_t)(col0 >> 7)) * nks * 4096;
  const int NT = KdU >> 6;

  const int sm = tid >> 2, sp = tid & 3;
  const int slg = sp ^ ((sm >> 1) & 3);
  int r0 = row0 + sm;       if (r0 >= Mpb) r0 = Mpb - 1;
  int r1 = row0 + 128 + sm; if (r1 >= Mpb) r1 = Mpb - 1;
  const __bf16* asrc0 = Ab + (size_t)(r0 - rbase) * ldaU + slg * 8;
  const __bf16* asrc1 = Ab + (size_t)(r1 - rbase) * ldaU + slg * 8;

  // half order per K-tile t: 0=A0, 1=B, 2=A1
  auto stage_half = [&](int gh) {
    if (gh >= 3 * NT) return;
    const int t = gh / 3, which = gh - 3 * t;
    const int bufi = t & 1;
    if (which == 1) {
      __bf16* dst = &Bs[bufi * 8192];
      const __bf16* src = Bp + (size_t)(t * 2) * 4096 + tid * 8;
      gl_lds16(src, dst + tid * 8);
      gl_lds16(src + 4096, dst + 4096 + tid * 8);
    } else {
      const int h = which >> 1;  // 0 -> A0, 2 -> A1
      __bf16* dst = &As[bufi * 16384 + h * 8192];
      const __bf16* src = (h ? asrc1 : asrc0) + t * 64;
      gl_lds16(src, dst + tid * 8);
      gl_lds16(src + 32, dst + 4096 + tid * 8);
    }
  };

  f32x4 acc[2][4][2];  // [mh][mi][ni]
#pragma unroll
  for (int a0 = 0; a0 < 2; ++a0)
#pragma unroll
    for (int a2 = 0; a2 < 4; ++a2)
#pragma unroll
      for (int a3 = 0; a3 < 2; ++a3) acc[a0][a2][a3] = f32x4{0.f, 0.f, 0.f, 0.f};

  // prologue: tile0 full + A0,B of tile1 (halves 0..4 = 10 loads); wait tile0 (6 loads)
  for (int gh = 0; gh < 5; ++gh) stage_half(gh);
  asm volatile("s_waitcnt vmcnt(4)" ::: "memory");
  __builtin_amdgcn_s_barrier();
  asm volatile("" ::: "memory");

  for (int t = 0; t < NT; ++t) {
    const int cb = (t & 1) * 16384;
    const int cbB = (t & 1) * 8192;
    bfx8 af[4][2], bf[2][2];

    // ---- PHASE 0: A-half 0 + B (B kept for phase 1) ----
#pragma unroll
    for (int mi = 0; mi < 4; ++mi) {
      const int m = wr * 64 + mi * 16 + qi;
      const int sl = g ^ ((m >> 1) & 3);
      const int ba = cb + m * 32 + sl * 8;
      af[mi][0] = *(const bfx8*)(&As[ba]);
      af[mi][1] = *(const bfx8*)(&As[ba + 4096]);
    }
#pragma unroll
    for (int ni = 0; ni < 2; ++ni) {
      const int m = wc * 32 + ni * 16 + qi;
      const int sl = g ^ ((m >> 1) & 3);
      const int bb = cbB + m * 32 + sl * 8;
      bf[ni][0] = *(const bfx8*)(&Bs[bb]);
      bf[ni][1] = *(const bfx8*)(&Bs[bb + 4096]);
    }
    stage_half(3 * t + 5);  // A1 of tile t+1
    __builtin_amdgcn_s_barrier();
    asm volatile("s_waitcnt lgkmcnt(0)" ::: "memory");
    __builtin_amdgcn_sched_barrier(0);
    __builtin_amdgcn_s_setprio(1);
#pragma unroll
    for (int mi = 0; mi < 4; ++mi)
#pragma unroll
      for (int ni = 0; ni < 2; ++ni) {
        acc[0][mi][ni] = MFMA16(af[mi][0], bf[ni][0], acc[0][mi][ni]);
        acc[0][mi][ni] = MFMA16(af[mi][1], bf[ni][1], acc[0][mi][ni]);
      }
    __builtin_amdgcn_s_setprio(0);
    __builtin_amdgcn_s_barrier();
    asm volatile("" ::: "memory");

    // ---- PHASE 1: A-half 1, reuse bf ----
#pragma unroll
    for (int mi = 0; mi < 4; ++mi) {
      const int m = wr * 64 + mi * 16 + qi;
      const int sl = g ^ ((m >> 1) & 3);
      const int ba = cb + 8192 + m * 32 + sl * 8;
      af[mi][0] = *(const bfx8*)(&As[ba]);
      af[mi][1] = *(const bfx8*)(&As[ba + 4096]);
    }
    stage_half(3 * t + 6);  // A0 of tile t+2
    stage_half(3 * t + 7);  // B  of tile t+2
    if (t + 2 < NT) asm volatile("s_waitcnt vmcnt(4)" ::: "memory");
    else            asm volatile("s_waitcnt vmcnt(0)" ::: "memory");
    __builtin_amdgcn_s_barrier();
    asm volatile("s_waitcnt lgkmcnt(0)" ::: "memory");
    __builtin_amdgcn_sched_barrier(0);
    __builtin_amdgcn_s_setprio(1);
#pragma unroll
    for (int mi = 0; mi < 4; ++mi)
#pragma unroll
      for (int ni = 0; ni < 2; ++ni) {
        acc[1][mi][ni] = MFMA16(af[mi][0], bf[ni][0], acc[1][mi][ni]);
        acc[1][mi][ni] = MFMA16(af[mi][1], bf[ni][1], acc[1][mi][ni]);
      }
    __builtin_amdgcn_s_setprio(0);
    __builtin_amdgcn_s_barrier();
    asm volatile("" ::: "memory");
  }

#pragma unroll
  for (int mh = 0; mh < 2; ++mh)
#pragma unroll
    for (int mi = 0; mi < 4; ++mi)
#pragma unroll
      for (int ni = 0; ni < 2; ++ni) {
        const int col = col0 + wc * 32 + ni * 16 + qi;
        if (outMode == 5 && col >= 2304) {
          const int vcol = col - 2304;
          const int rowb = row0 + mh * 128 + wr * 64 + mi * 16 + g * 4;
          if (rowb < Mpb) {
            bfx4 ov;
#pragma unroll
            for (int r = 0; r < 4; ++r) ov[r] = (__bf16)acc[mh][mi][ni][r];
            *(bfx4*)((__bf16*)C2 + (size_t)b * (256 * 816) + (size_t)vcol * 816 + rowb) = ov;
          }
          continue;
        }
#pragma unroll
        for (int r = 0; r < 4; ++r) {
          const int row = row0 + mh * 128 + wr * 64 + mi * 16 + g * 4 + r;
          if (row >= Mpb) continue;
          const float v = acc[mh][mi][ni][r];
          if (outMode == 0) {
            ((float*)C)[(size_t)b * strideC + (size_t)row * ldc + col] = v;
          } else if (outMode == 5) {
            ((__bf16*)C)[(size_t)b * strideC + (size_t)row * ldc + col] = (__bf16)v;
          } else {  // mode 2
            const size_t ix = (size_t)b * strideC + (size_t)row * ldc + col;
            ((float*)C)[ix] = v + ((const float*)Extra)[ix];
          }
        }
      }
}

// ---------------- bf16 GEMM, panel weights, BK=64, counted-vmcnt (small-M path) ------
__global__ __launch_bounds__(256, 2)
void gemm_bt2(const __bf16* __restrict__ A, const __bf16* __restrict__ Bt,
              void* __restrict__ C, void* __restrict__ C2, const void* __restrict__ Extra,
              int Mpb, int lda, int strideA, int Kd,
              int ldc, int strideC, int mbPerBatch,
              int outMode, int ldct) {
  __shared__ __align__(16) __bf16 As[2][8192];
  __shared__ __align__(16) __bf16 Bs[2][8192];
  const int tid = threadIdx.x;
  const int lane = tid & 63;
  const int wid = tid >> 6;
  const int b = blockIdx.x / mbPerBatch;
  const int row0 = (blockIdx.x % mbPerBatch) * 128;
  const int col0 = blockIdx.y * 128;
  const __bf16* Ab = A + (size_t)b * strideA;
  const size_t nks = (size_t)(Kd >> 5);
  const __bf16* Bpan0 = Bt + ((size_t)(col0 >> 7)) * nks * 4096;
  const int wm = (wid >> 1) * 64, wn = (wid & 1) * 64;
  const int qi = lane & 15, g = lane >> 4;

  const int m0 = tid >> 2, p0 = tid & 3;
  const int lg0 = p0 ^ ((m0 >> 1) & 3);
  const int m1 = m0 + 64;
  const int lg1 = p0 ^ ((m1 >> 1) & 3);
  int mr0 = row0 + m0; if (mr0 >= Mpb) mr0 = Mpb - 1;
  int mr1 = row0 + m1; if (mr1 >= Mpb) mr1 = Mpb - 1;
  const __bf16* asrc0 = Ab + (size_t)mr0 * lda + lg0 * 8;
  const __bf16* asrc1 = Ab + (size_t)mr1 * lda + lg1 * 8;
  const int nt = Kd >> 6;

  auto stage = [&](int t, int bufi) {
    const int k0 = t * 64;
    gl_lds16(asrc0 + k0, &As[bufi][tid * 8]);
    gl_lds16(asrc1 + k0, &As[bufi][(tid + 256) * 8]);
    gl_lds16(asrc0 + k0 + 32, &As[bufi][4096 + tid * 8]);
    gl_lds16(asrc1 + k0 + 32, &As[bufi][4096 + (tid + 256) * 8]);
    const __bf16* pb = Bpan0 + (size_t)(k0 >> 5) * 4096;
    gl_lds16(pb + tid * 8, &Bs[bufi][tid * 8]);
    gl_lds16(pb + (tid + 256) * 8, &Bs[bufi][(tid + 256) * 8]);
    gl_lds16(pb + 4096 + tid * 8, &Bs[bufi][4096 + tid * 8]);
    gl_lds16(pb + 4096 + (tid + 256) * 8, &Bs[bufi][4096 + (tid + 256) * 8]);
  };

  f32x4 acc[4][4];
#pragma unroll
  for (int i = 0; i < 4; ++i)
#pragma unroll
    for (int j = 0; j < 4; ++j) acc[i][j] = f32x4{0.f, 0.f, 0.f, 0.f};

  stage(0, 0);
  if (nt > 1) stage(1, 1);

  for (int t = 0; t < nt; ++t) {
    const int cur = t & 1;
    if (t + 1 < nt) asm volatile("s_waitcnt vmcnt(8)" ::: "memory");
    else            asm volatile("s_waitcnt vmcnt(0)" ::: "memory");
    __builtin_amdgcn_s_barrier();
    asm volatile("" ::: "memory");
#pragma unroll
    for (int ks = 0; ks < 2; ++ks) {
      bfx8 af[4], bf[4];
#pragma unroll
      for (int mi = 0; mi < 4; ++mi) {
        const int m = wm + mi * 16 + qi;
        const int sl = g ^ ((m >> 1) & 3);
        af[mi] = *(const bfx8*)(&As[cur][ks * 4096 + m * 32 + sl * 8]);
      }
#pragma unroll
      for (int ni = 0; ni < 4; ++ni) {
        const int n = wn + ni * 16 + qi;
        const int sl = g ^ ((n >> 1) & 3);
        bf[ni] = *(const bfx8*)(&Bs[cur][ks * 4096 + n * 32 + sl * 8]);
      }
#pragma unroll
      for (int mi = 0; mi < 4; ++mi)
#pragma unroll
        for (int ni = 0; ni < 4; ++ni)
          acc[mi][ni] = MFMA16(af[mi], bf[ni], acc[mi][ni]);
    }
    asm volatile("s_waitcnt lgkmcnt(0)" ::: "memory");
    __builtin_amdgcn_s_barrier();
    asm volatile("" ::: "memory");
    if (t + 2 < nt) stage(t + 2, cur);
  }

#pragma unroll
  for (int mi = 0; mi < 4; ++mi) {
#pragma unroll
    for (int ni = 0; ni < 4; ++ni) {
      const int col = col0 + wn + ni * 16 + qi;
      if (outMode == 5 && col >= 2304) {
        const int vcol = col - 2304;
        const int rowb = row0 + wm + mi * 16 + g * 4;
        if (rowb < Mpb) {
          bfx4 ov;
#pragma unroll
          for (int r = 0; r < 4; ++r) ov[r] = (__bf16)acc[mi][ni][r];
          *(bfx4*)((__bf16*)C2 + (size_t)b * (256 * 816) + (size_t)vcol * 816 + rowb) = ov;
        }
        continue;
      }
#pragma unroll
      for (int r = 0; r < 4; ++r) {
        const int row = row0 + wm + mi * 16 + g * 4 + r;
        if (row >= Mpb) continue;
        const float v = acc[mi][ni][r];
        if (outMode == 0) {
          ((float*)C)[(size_t)b * strideC + (size_t)row * ldc + col] = v;
        } else if (outMode == 1 || outMode == 5) {
          ((__bf16*)C)[(size_t)b * strideC + (size_t)row * ldc + col] = (__bf16)v;
        } else {  // mode 2
          const size_t ix = (size_t)b * strideC + (size_t)row * ldc + col;
          ((float*)C)[ix] = v + ((const float*)Extra)[ix];
        }
      }
    }
  }
  (void)ldct;
}

// ---------------- Fused GEGLU dual-GEMM (128-tile, small-M path) ----------------
__global__ __launch_bounds__(256, 2)
void ffn_dual(const __bf16* __restrict__ A, const __bf16* __restrict__ Wg,
              const __bf16* __restrict__ Wa, __bf16* __restrict__ C,
              int Mpb, int lda, int strideA, int Kd,
              int ldc, int strideC, int mbPerBatch) {
  __shared__ __align__(16) __bf16 As[2][8192];
  __shared__ __align__(16) __bf16 Bs[2][8192];
  const int tid = threadIdx.x;
  const int lane = tid & 63;
  const int wid = tid >> 6;
  const int b = blockIdx.x / mbPerBatch;
  const int row0 = (blockIdx.x % mbPerBatch) * 128;
  const int col0 = blockIdx.y * 128;
  const __bf16* Ab = A + (size_t)b * strideA;
  const size_t nks = (size_t)(Kd >> 5);
  const int wm = (wid >> 1) * 64, wn = (wid & 1) * 64;
  const int qi = lane & 15, g = lane >> 4;

  const int m0 = tid >> 2, p0 = tid & 3;
  const int lg0 = p0 ^ ((m0 >> 1) & 3);
  const int m1 = m0 + 64;
  const int lg1 = p0 ^ ((m1 >> 1) & 3);
  int mr0 = row0 + m0; if (mr0 >= Mpb) mr0 = Mpb - 1;
  int mr1 = row0 + m1; if (mr1 >= Mpb) mr1 = Mpb - 1;
  const __bf16* asrc0 = Ab + (size_t)mr0 * lda + lg0 * 8;
  const __bf16* asrc1 = Ab + (size_t)mr1 * lda + lg1 * 8;
  const int nt = Kd >> 6;

  f32x4 gval[4][4];
  f32x4 acc[4][4];

#pragma unroll
  for (int pan = 0; pan < 2; ++pan) {
    const __bf16* Bpan0 = (pan ? Wa : Wg) + ((size_t)(col0 >> 7)) * nks * 4096;

    auto stage = [&](int t, int bufi) {
      const int k0 = t * 64;
      gl_lds16(asrc0 + k0, &As[bufi][tid * 8]);
      gl_lds16(asrc1 + k0, &As[bufi][(tid + 256) * 8]);
      gl_lds16(asrc0 + k0 + 32, &As[bufi][4096 + tid * 8]);
      gl_lds16(asrc1 + k0 + 32, &As[bufi][4096 + (tid + 256) * 8]);
      const __bf16* pb = Bpan0 + (size_t)(k0 >> 5) * 4096;
      gl_lds16(pb + tid * 8, &Bs[bufi][tid * 8]);
      gl_lds16(pb + (tid + 256) * 8, &Bs[bufi][(tid + 256) * 8]);
      gl_lds16(pb + 4096 + tid * 8, &Bs[bufi][4096 + tid * 8]);
      gl_lds16(pb + 4096 + (tid + 256) * 8, &Bs[bufi][4096 + (tid + 256) * 8]);
    };

#pragma unroll
    for (int i = 0; i < 4; ++i)
#pragma unroll
      for (int j = 0; j < 4; ++j) acc[i][j] = f32x4{0.f, 0.f, 0.f, 0.f};

    stage(0, 0);
    if (nt > 1) stage(1, 1);

    for (int t = 0; t < nt; ++t) {
      const int cur = t & 1;
      if (t + 1 < nt) asm volatile("s_waitcnt vmcnt(8)" ::: "memory");
      else            asm volatile("s_waitcnt vmcnt(0)" ::: "memory");
      __builtin_amdgcn_s_barrier();
      asm volatile("" ::: "memory");
#pragma unroll
      for (int ks = 0; ks < 2; ++ks) {
        bfx8 af[4], bf[4];
#pragma unroll
        for (int mi = 0; mi < 4; ++mi) {
          const int m = wm + mi * 16 + qi;
          const int sl = g ^ ((m >> 1) & 3);
          af[mi] = *(const bfx8*)(&As[cur][ks * 4096 + m * 32 + sl * 8]);
        }
#pragma unroll
        for (int ni = 0; ni < 4; ++ni) {
          const int n = wn + ni * 16 + qi;
          const int sl = g ^ ((n >> 1) & 3);
          bf[ni] = *(const bfx8*)(&Bs[cur][ks * 4096 + n * 32 + sl * 8]);
        }
#pragma unroll
        for (int mi = 0; mi < 4; ++mi)
#pragma unroll
          for (int ni = 0; ni < 4; ++ni)
            acc[mi][ni] = MFMA16(af[mi], bf[ni], acc[mi][ni]);
      }
      asm volatile("s_waitcnt lgkmcnt(0)" ::: "memory");
      __builtin_amdgcn_s_barrier();
      asm volatile("" ::: "memory");
      if (t + 2 < nt) stage(t + 2, cur);
    }

    if (pan == 0) {
#pragma unroll
      for (int i = 0; i < 4; ++i)
#pragma unroll
        for (int j = 0; j < 4; ++j)
#pragma unroll
          for (int r = 0; r < 4; ++r) gval[i][j][r] = gelu_tanh_f(acc[i][j][r]);
    }
  }

#pragma unroll
  for (int mi = 0; mi < 4; ++mi) {
#pragma unroll
    for (int ni = 0; ni < 4; ++ni) {
      const int col = col0 + wn + ni * 16 + qi;
#pragma unroll
      for (int r = 0; r < 4; ++r) {
        const int row = row0 + wm + mi * 16 + g * 4 + r;
        if (row >= Mpb) continue;
        C[(size_t)b * strideC + (size_t)row * ldc + col] =
            (__bf16)(gval[mi][ni][r] * acc[mi][ni][r]);
      }
    }
  }
}

// ---------------- Old GEMM (f32 weights on the fly) — legacy fallback ----------------
__global__ __launch_bounds__(256, 2)
void gemm_kernel(const __bf16* __restrict__ A, const float* __restrict__ Bw,
                 void* __restrict__ C, const void* __restrict__ Extra,
                 int Mpb, int lda, int strideA,
                 int ldb, int headDim, int Kd,
                 int ldc, int strideC, int mbPerBatch,
                 int outMode, int ldct) {
  __shared__ __align__(16) __bf16 As[128 * 32];
  __shared__ __align__(16) __bf16 Bs[128 * 32];
  const int tid = threadIdx.x;
  const int lane = tid & 63;
  const int wid = tid >> 6;
  const int b = blockIdx.x / mbPerBatch;
  const int row0 = (blockIdx.x % mbPerBatch) * 128;
  const int col0 = blockIdx.y * 128;
  const __bf16* Ab = A + (size_t)b * strideA;
  const float* Bb = (headDim > 0)
      ? (Bw + (size_t)(col0 / headDim) * (size_t)Kd * headDim + (col0 % headDim))
      : (Bw + col0);
  const int wm = (wid >> 1) * 64, wn = (wid & 1) * 64;
  const int qi = lane & 15, g = lane >> 4;

  f32x4 acc[4][4];
#pragma unroll
  for (int i = 0; i < 4; ++i)
#pragma unroll
    for (int j = 0; j < 4; ++j) acc[i][j] = f32x4{0.f, 0.f, 0.f, 0.f};

  const int am = tid >> 2, ap = tid & 3;
  const int bn = tid >> 2, bc = tid & 3;

  for (int k0 = 0; k0 < Kd; k0 += 32) {
    __syncthreads();
#pragma unroll
    for (int s = 0; s < 2; ++s) {
      const int m = am + s * 64;
      int mr = row0 + m;
      if (mr >= Mpb) mr = Mpb - 1;
      const int lg = ap ^ ((m >> 1) & 3);
      bfx8 v = *(const bfx8*)(Ab + (size_t)mr * lda + k0 + lg * 8);
      *(bfx8*)(&As[m * 32 + ap * 8]) = v;
    }
#pragma unroll
    for (int s = 0; s < 2; ++s) {
      const int n = bn + s * 64;
      const float* bp = Bb + (size_t)(k0 + bc * 8) * ldb + n;
      bfx8 v;
#pragma unroll
      for (int i = 0; i < 8; ++i) v[i] = (__bf16)bp[(size_t)i * ldb];
      const int p = bc ^ ((n >> 1) & 3);
      *(bfx8*)(&Bs[n * 32 + p * 8]) = v;
    }
    __syncthreads();
    bfx8 af[4], bf[4];
#pragma unroll
    for (int mi = 0; mi < 4; ++mi) {
      const int m = wm + mi * 16 + qi;
      const int sl = g ^ ((m >> 1) & 3);
      af[mi] = *(const bfx8*)(&As[m * 32 + sl * 8]);
    }
#pragma unroll
    for (int ni = 0; ni < 4; ++ni) {
      const int n = wn + ni * 16 + qi;
      const int sl = g ^ ((n >> 1) & 3);
      bf[ni] = *(const bfx8*)(&Bs[n * 32 + sl * 8]);
    }
#pragma unroll
    for (int mi = 0; mi < 4; ++mi)
#pragma unroll
      for (int ni = 0; ni < 4; ++ni)
        acc[mi][ni] = MFMA16(af[mi], bf[ni], acc[mi][ni]);
  }

#pragma unroll
  for (int mi = 0; mi < 4; ++mi) {
#pragma unroll
    for (int ni = 0; ni < 4; ++ni) {
      const int col = col0 + wn + ni * 16 + qi;
#pragma unroll
      for (int r = 0; r < 4; ++r) {
        const int row = row0 + wm + mi * 16 + g * 4 + r;
        if (row >= Mpb) continue;
        const float v = acc[mi][ni][r];
        if (outMode == 0) {
          ((float*)C)[(size_t)b * strideC + (size_t)row * ldc + col] = v;
        } else if (outMode == 1) {
          ((__bf16*)C)[(size_t)b * strideC + (size_t)row * ldc + col] = (__bf16)v;
        } else if (outMode == 2) {
          const size_t ix = (size_t)b * strideC + (size_t)row * ldc + col;
          ((float*)C)[ix] = v + ((const float*)Extra)[ix];
        } else if (outMode == 3) {
          ((__bf16*)C)[(size_t)b * strideC + (size_t)col * ldct + row] = (__bf16)v;
        } else {
          const size_t ix = (size_t)b * strideC + (size_t)row * ldc + col;
          const float gt = (float)((const __bf16*)Extra)[ix];
          ((__bf16*)C)[ix] = (__bf16)(gelu_tanh_f(gt) * v);
        }
      }
    }
  }
}

// ---------------- Fused attention (q/k strides parameterized) ----------------
__global__ __launch_bounds__(256, 2)
void attn_kernel(const __bf16* __restrict__ qp, const __bf16* __restrict__ kp0,
                 const __bf16* __restrict__ vt, __bf16* __restrict__ ao,
                 int qstride, int kstride) {
  __shared__ __align__(16) __bf16 Ps[4][1024];
  __shared__ float denw[4][16];
  const int tid = threadIdx.x, lane = tid & 63, wid = tid >> 6;
  const int qt = blockIdx.x, hn = blockIdx.y, b = blockIdx.z;
  const int q0 = qt * 64;
  const int qi = lane & 15, g = lane >> 4;

  int qrow = q0 + wid * 16 + qi;
  if (qrow > 815) qrow = 815;
  const int cmq = (qrow >= 768) + (qrow >= 771);
  const __bf16* qrp = qp + (size_t)(b * 816 + qrow) * qstride + hn * 256 + g * 8;
  bfx8 qf[8];
#pragma unroll
  for (int kf = 0; kf < 8; ++kf) qf[kf] = *(const bfx8*)(qrp + kf * 32);

  f32x4 oacc[16];
#pragma unroll
  for (int i = 0; i < 16; ++i) oacc[i] = f32x4{0.f, 0.f, 0.f, 0.f};
  float den = 0.f;

  const int ntiles = (q0 + 63 < 768) ? 12 : 13;
  for (int t = 0; t < ntiles; ++t) {
    const int kv0 = t * 64;
#pragma unroll
    for (int mi = 0; mi < 4; ++mi) {
      f32x4 sac = f32x4{0.f, 0.f, 0.f, 0.f};
      int srow = kv0 + mi * 16 + qi;
      if (srow > 815) srow = 815;
      const __bf16* kp = kp0 + (size_t)(b * 816 + srow) * kstride + g * 8;
#pragma unroll
      for (int kf = 0; kf < 8; ++kf) {
        bfx8 a = *(const bfx8*)(kp + kf * 32);
        sac = MFMA16(a, qf[kf], sac);
      }
      float pv[4];
#pragma unroll
      for (int r = 0; r < 4; ++r) {
        const int s = kv0 + mi * 16 + g * 4 + r;
        const float l = sac[r];
        const float e2 = __expf(l * 0.04f);
        const float capped = 50.f * (e2 - 1.f) / (e2 + 1.f);
        const int cms = (s >= 768) + (s >= 771);
        const bool ok = (s < 816) && (cms <= cmq);
        const float p = ok ? __expf(capped) : 0.f;
        den += p;
        pv[r] = p;
      }
      const unsigned lo = pack_bf2(pv[0], pv[1]);
      const unsigned hi = pack_bf2(pv[2], pv[3]);
      const int slot = 2 * mi + (g >> 1);
      const int phys = slot ^ (qi & 7);
      char* pb = (char*)&Ps[wid][0] + qi * 128 + phys * 16 + (g & 1) * 8;
      *(unsigned*)(pb) = lo;
      *(unsigned*)(pb + 4) = hi;
    }
    asm volatile("s_waitcnt lgkmcnt(0)" ::: "memory");
    bfx8 pa[2];
#pragma unroll
    for (int k2 = 0; k2 < 2; ++k2) {
      const int sl = (k2 * 4 + g) ^ (qi & 7);
      pa[k2] = *(const bfx8*)((const char*)&Ps[wid][0] + qi * 128 + sl * 16);
    }
#pragma unroll
    for (int hf = 0; hf < 16; ++hf) {
      const int h = hf * 16 + qi;
#pragma unroll
      for (int k2 = 0; k2 < 2; ++k2) {
        int s0 = kv0 + k2 * 32 + g * 8;
        if (s0 > 808) s0 = 808;
        bfx8 vb = *(const bfx8*)(vt + ((size_t)(b * 256 + h)) * 816 + s0);
        oacc[hf] = MFMA16(pa[k2], vb, oacc[hf]);
      }
    }
    asm volatile("s_waitcnt lgkmcnt(0)" ::: "memory");
  }

  den += __shfl_xor(den, 16, 64);
  den += __shfl_xor(den, 32, 64);
  if (lane < 16) denw[wid][qi] = den;
  asm volatile("s_waitcnt lgkmcnt(0)" ::: "memory");
#pragma unroll
  for (int r = 0; r < 4; ++r) {
    const int qg = q0 + wid * 16 + g * 4 + r;
    if (qg >= 816) continue;
    const float di = 1.f / denw[wid][g * 4 + r];
#pragma unroll
    for (int hf = 0; hf < 16; ++hf) {
      ao[((size_t)(b * 816 + qg)) * 2048 + hn * 256 + hf * 16 + qi] =
          (__bf16)(oacc[hf][r] * di);
    }
  }
}

// ---------------- Host orchestration ----------------
extern "C" void kernel_launch(void* const* d_in, const int* in_sizes, int n_in,
                              void* d_out, int out_size, void* d_ws, size_t ws_size,
                              hipStream_t stream) {
  (void)in_sizes; (void)n_in; (void)out_size;
  const float* x      = (const float*)d_in[0];
  const int*   pos    = (const int*)d_in[1];
  const float* s_attn = (const float*)d_in[4];
  const float* s_ffw  = (const float*)d_in[5];
  const float* gq     = (const float*)d_in[6];
  const float* gkv    = (const float*)d_in[7];
  const float* go     = (const float*)d_in[8];
  const float* aq     = (const float*)d_in[9];
  const float* akv    = (const float*)d_in[10];
  const float* aow    = (const float*)d_in[11];
  const float* gg     = (const float*)d_in[12];
  const float* gl     = (const float*)d_in[13];
  const float* ag     = (const float*)d_in[14];
  const float* al     = (const float*)d_in[15];
  float* outp = (float*)d_out;
  char* ws = (char*)d_ws;
  dim3 blk(256);

  const size_t NEED_BATCH = 577437696u;
  const size_t NEED_FAST  = 423297024u;

  if (ws_size >= NEED_FAST) {
    const bool batched = (ws_size >= NEED_BATCH);
    // weights (tile-panel bf16); QKV fused: [Q 16 panels][K 2][V 2] contiguous
    __bf16* wQKVg = (__bf16*)(ws + 0);          // 20 panels x 64ks x 4096
    __bf16* wQKVa = (__bf16*)(ws + 10485760);
    __bf16* goT = (__bf16*)(ws + 20971520);
    __bf16* aoT = (__bf16*)(ws + 29360128);
    __bf16* ggT = (__bf16*)(ws + 37748736);     // [2] x [16384 x 2048]
    __bf16* glT = (__bf16*)(ws + 171966464);    // [2048 x 16384]
    __bf16* agT = (__bf16*)(ws + 239075328);    // [2] x [4096 x 2048]
    __bf16* alT = (__bf16*)(ws + 272629760);    // [2048 x 4096]
    // activations
    __bf16* xn   = (__bf16*)(ws + 289406976);   // [3264][2048]
    __bf16* qkb  = (__bf16*)(ws + 302776320);   // [3264][2304]  Q cols 0-2047, K 2048-2303
    __bf16* vt   = (__bf16*)(ws + 317816832);   // [4][256][816]
    __bf16* aob  = (__bf16*)(ws + 319488000);   // [3264][2048]
    float*  ob   = (float*)(ws + 332857344);    // [3264][2048] f32
    __bf16* hb   = (__bf16*)(ws + 359596032);   // [3264][2048]
    __bf16* gate  = (__bf16*)(ws + 372965376);  // per-batch scratch
    __bf16* act   = (__bf16*)(ws + 398131200);  // per-batch [768][16384]
    __bf16* act4  = (__bf16*)(ws + 473628672);  // batched [4][768][16384]
    __bf16* actA4 = (__bf16*)(ws + 575864832);  // batched [4][48][4096]

    // weight conversion (f32 [K][N] -> bf16 panel)
    convw_kernel<<<dim3(32, 32), blk, 0, stream>>>(gq, wQKVg, 2048, 256);
    convw_kernel<<<dim3(4, 32), blk, 0, stream>>>(gkv, wQKVg + 16 * 64 * 4096, 2048, 256);
    convw_kernel<<<dim3(4, 32), blk, 0, stream>>>(gkv + 2048 * 256, wQKVg + 18 * 64 * 4096, 2048, 256);
    convw_kernel<<<dim3(32, 32), blk, 0, stream>>>(aq, wQKVa, 2048, 256);
    convw_kernel<<<dim3(4, 32), blk, 0, stream>>>(akv, wQKVa + 16 * 64 * 4096, 2048, 256);
    convw_kernel<<<dim3(4, 32), blk, 0, stream>>>(akv + 2048 * 256, wQKVa + 18 * 64 * 4096, 2048, 256);
    convw_kernel<<<dim3(32, 32), blk, 0, stream>>>(go, goT, 2048, 2048);
    convw_kernel<<<dim3(32, 32), blk, 0, stream>>>(aow, aoT, 2048, 2048);
    convw_kernel<<<dim3(256, 32), blk, 0, stream>>>(gg, ggT, 2048, 16384);
    convw_kernel<<<dim3(256, 32), blk, 0, stream>>>(gg + (size_t)2048 * 16384, ggT + (size_t)16384 * 2048, 2048, 16384);
    convw_kernel<<<dim3(32, 256), blk, 0, stream>>>(gl, glT, 16384, 2048);
    convw_kernel<<<dim3(64, 32), blk, 0, stream>>>(ag, agT, 2048, 4096);
    convw_kernel<<<dim3(64, 32), blk, 0, stream>>>(ag + (size_t)2048 * 4096, agT + (size_t)4096 * 2048, 2048, 4096);
    convw_kernel<<<dim3(32, 64), blk, 0, stream>>>(al, alT, 4096, 2048);

    // 1. pre-attention rmsnorm
    rmsnorm_kernel<<<3264, blk, 0, stream>>>(x, nullptr, s_attn, xn);

    // 2. fused QKV projection, gemma+action merged (row-block 3 = action weights)
    gemm256<<<dim3(16, 20), dim3(512), 0, stream>>>(xn, wQKVg, wQKVa, qkb, vt, nullptr,
        816, 2048, 816 * 2048, 2048, 2304, 816 * 2304, 4, 5, nullptr, 0, 0, 0);

    // 3. RoPE in place, Q+K in one launch (heads 0-7 scaled by H^-0.5, head 8 = K unscaled)
    rope_bf_kernel<<<3264, blk, 0, stream>>>(qkb, pos, 9, 2304, 8, 0.0625f);

    // 4. attention
    attn_kernel<<<dim3(13, 8, 4), blk, 0, stream>>>(qkb, qkb + 2048, vt, aob, 2304, 2304);

    // 5. output projection, gemma+action merged
    gemm256<<<dim3(16, 16), dim3(512), 0, stream>>>(aob, goT, aoT, ob, nullptr, nullptr,
        816, 2048, 816 * 2048, 2048, 2048, 816 * 2048, 4, 0, nullptr, 0, 0, 0);

    // 6. pre-FFW rmsnorm of (o + x)
    rmsnorm_kernel<<<3264, blk, 0, stream>>>(ob, x, s_ffw, hb);

    // 7. FFN: gemma gate+act dual GEMM; action gate (small); down-proj merged g+a
    if (batched) {
      ffn_dual256<<<dim3(12, 128), dim3(512), 0, stream>>>(hb, ggT, ggT + (size_t)16384 * 2048, act4,
          768, 2048, 816 * 2048, 2048, 16384, 768 * 16384, 3);
      ffn_dual<<<dim3(4, 32), blk, 0, stream>>>(hb + 768 * 2048, agT, agT + (size_t)4096 * 2048, actA4,
          48, 2048, 816 * 2048, 2048, 4096, 48 * 4096, 1);
      // merged down-proj: row-blocks 0-2 = gemma (act4, glT, K=16384),
      // row-block 3 = action (actA4, alT, K=4096); epilogue residual indexing identical.
      gemm256<<<dim3(16, 16), dim3(512), 0, stream>>>(act4, glT, alT, outp, nullptr, x,
          816, 16384, 768 * 16384, 16384, 2048, 816 * 2048, 4, 2,
          actA4, 4096, 48 * 4096, 4096);
    } else {
      for (int bb = 0; bb < 4; ++bb) {
        const __bf16* hg = hb + (size_t)bb * 816 * 2048;
        float* og = outp + (size_t)bb * 816 * 2048;
        const float* xg = x + (size_t)bb * 816 * 2048;
        ffn_dual<<<dim3(6, 128), blk, 0, stream>>>(hg, ggT, ggT + (size_t)16384 * 2048, act,
            768, 2048, 0, 2048, 16384, 0, 6);
        gemm_bt2<<<dim3(6, 16), blk, 0, stream>>>(act, glT, og, nullptr, xg,
            768, 16384, 0, 16384, 2048, 0, 6, 2, 0);
        const __bf16* ha = hg + 768 * 2048;
        ffn_dual<<<dim3(1, 32), blk, 0, stream>>>(ha, agT, agT + (size_t)4096 * 2048, gate,
            48, 2048, 0, 2048, 4096, 0, 1);
        gemm_bt2<<<dim3(1, 16), blk, 0, stream>>>(gate, alT, og + 768 * 2048, nullptr, xg + 768 * 2048,
            48, 4096, 0, 4096, 2048, 0, 1, 2, 0);
      }
    }
    return;
  }

  // ---- legacy fallback path (round-0, on-the-fly f32 weights) ----
  if (ws_size < 164000000u) return;
  __bf16* xn   = (__bf16*)(ws + 0);
  float*  qf   = (float*)(ws + 13369344);
  __bf16* qbb  = (__bf16*)(ws + 40108032);
  float*  kf   = (float*)(ws + 53477376);
  __bf16* kbb  = (__bf16*)(ws + 56819712);
  __bf16* vt   = (__bf16*)(ws + 58490880);
  __bf16* aob  = (__bf16*)(ws + 60162048);
  float*  ob   = (float*)(ws + 73531392);
  __bf16* hb   = (__bf16*)(ws + 100270080);
  __bf16* gate = (__bf16*)(ws + 113639424);
  __bf16* act  = (__bf16*)(ws + 138805248);

  rmsnorm_kernel<<<3264, blk, 0, stream>>>(x, nullptr, s_attn, xn);
  gemm_kernel<<<dim3(24, 16), blk, 0, stream>>>(xn, gq, qf, nullptr,
      768, 2048, 816 * 2048, 256, 256, 2048, 2048, 816 * 2048, 6, 0, 0);
  gemm_kernel<<<dim3(4, 16), blk, 0, stream>>>(xn + 768 * 2048, aq, qf + 768 * 2048, nullptr,
      48, 2048, 816 * 2048, 256, 256, 2048, 2048, 816 * 2048, 1, 0, 0);
  gemm_kernel<<<dim3(24, 2), blk, 0, stream>>>(xn, gkv, kf, nullptr,
      768, 2048, 816 * 2048, 256, 256, 2048, 256, 816 * 256, 6, 0, 0);
  gemm_kernel<<<dim3(4, 2), blk, 0, stream>>>(xn + 768 * 2048, akv, kf + 768 * 256, nullptr,
      48, 2048, 816 * 2048, 256, 256, 2048, 256, 816 * 256, 1, 0, 0);
  gemm_kernel<<<dim3(24, 2), blk, 0, stream>>>(xn, gkv + 2048 * 256, vt, nullptr,
      768, 2048, 816 * 2048, 256, 256, 2048, 0, 256 * 816, 6, 3, 816);
  gemm_kernel<<<dim3(4, 2), blk, 0, stream>>>(xn + 768 * 2048, akv + 2048 * 256, vt + 768, nullptr,
      48, 2048, 816 * 2048, 256, 256, 2048, 0, 256 * 816, 1, 3, 816);
  rope_kernel<<<3264, blk, 0, stream>>>(qf, pos, qbb, 8, 0.0625f);
  rope_kernel<<<3264, blk, 0, stream>>>(kf, pos, kbb, 1, 1.0f);
  attn_kernel<<<dim3(13, 8, 4), blk, 0, stream>>>(qbb, kbb, vt, aob, 2048, 256);
  gemm_kernel<<<dim3(24, 16), blk, 0, stream>>>(aob, go, ob, nullptr,
      768, 2048, 816 * 2048, 2048, 0, 2048, 2048, 816 * 2048, 6, 0, 0);
  gemm_kernel<<<dim3(4, 16), blk, 0, stream>>>(aob + 768 * 2048, aow, ob + 768 * 2048, nullptr,
      48, 2048, 816 * 2048, 2048, 0, 2048, 2048, 816 * 2048, 1, 0, 0);
  rmsnorm_kernel<<<3264, blk, 0, stream>>>(ob, x, s_ffw, hb);
  for (int bb = 0; bb < 4; ++bb) {
    const __bf16* hg = hb + (size_t)bb * 816 * 2048;
    float* og = outp + (size_t)bb * 816 * 2048;
    const float* xg = x + (size_t)bb * 816 * 2048;
    gemm_kernel<<<dim3(6, 128), blk, 0, stream>>>(hg, gg, gate, nullptr,
        768, 2048, 0, 16384, 0, 2048, 16384, 0, 6, 1, 0);
    gemm_kernel<<<dim3(6, 128), blk, 0, stream>>>(hg, gg + 2048 * 16384, act, gate,
        768, 2048, 0, 16384, 0, 2048, 16384, 0, 6, 4, 0);
    gemm_kernel<<<dim3(6, 16), blk, 0, stream>>>(act, gl, og, xg,
        768, 16384, 0, 2048, 0, 16384, 2048, 0, 6, 2, 0);
    const __bf16* ha = hg + 768 * 2048;
    gemm_kernel<<<dim3(1, 32), blk, 0, stream>>>(ha, ag, gate, nullptr,
        48, 2048, 0, 4096, 0, 2048, 4096, 0, 1, 1, 0);
    gemm_kernel<<<dim3(1, 32), blk, 0, stream>>>(ha, ag + 2048 * 4096, act, gate,
        48, 2048, 0, 4096, 0, 2048, 4096, 0, 1, 4, 0);
    gemm_kernel<<<dim3(1, 16), blk, 0, stream>>>(act, al, og + 768 * 2048, xg + 768 * 2048,
        48, 4096, 0, 2048, 0, 4096, 2048, 0, 1, 2, 0);
  }
}